// Round 15
// baseline (1771.806 us; speedup 1.0000x reference)
//
#include <hip/hip_runtime.h>
#include <math.h>

#define NTOK 197
#define NIMG 196
#define CDIM 768
#define NHEAD 12
#define HD 64
#define BATCH 64
#define NSEL 118
#define ROWS_FULL (BATCH*NTOK)     // 12608
#define ROWS_SEL  (BATCH*(NSEL+1)) // 7616

typedef short bf16x8 __attribute__((ext_vector_type(8)));
typedef float f32x4  __attribute__((ext_vector_type(4)));

#define GLDS(g, l) __builtin_amdgcn_global_load_lds( \
    (const __attribute__((address_space(1))) void*)(g), \
    (__attribute__((address_space(3))) void*)(l), 16, 0, 0)

__device__ __forceinline__ unsigned short f2bf(float f){
  union { float f; unsigned u; } v; v.f = f;
  unsigned r = v.u + 0x7FFF + ((v.u >> 16) & 1);
  return (unsigned short)(r >> 16);
}
__device__ __forceinline__ float bf2f(unsigned short h){
  union { unsigned u; float f; } v; v.u = ((unsigned)h) << 16; return v.f;
}

// ---------------- LayerNorm (one block per row, C=768). OUT: 0=f32 1=bf16 --
template<int OUT>
__global__ __launch_bounds__(256) void ln_kernel(
    const float* __restrict__ x, const float* __restrict__ w,
    const float* __restrict__ b, void* __restrict__ outv)
{
  const int row = blockIdx.x;
  const int t = threadIdx.x;
  const float* xr = x + (size_t)row * CDIM;
  float v0 = xr[t], v1 = xr[t+256], v2 = xr[t+512];
  float s = v0 + v1 + v2;
  __shared__ float red[4], red2[4];
  #pragma unroll
  for (int o=32;o>0;o>>=1) s += __shfl_down(s,o);
  if ((t&63)==0) red[t>>6] = s;
  __syncthreads();
  const float mean = (red[0]+red[1]+red[2]+red[3]) / 768.0f;
  const float d0=v0-mean, d1=v1-mean, d2=v2-mean;
  float vs = d0*d0 + d1*d1 + d2*d2;
  #pragma unroll
  for (int o=32;o>0;o>>=1) vs += __shfl_down(vs,o);
  if ((t&63)==0) red2[t>>6] = vs;
  __syncthreads();
  const float var = (red2[0]+red2[1]+red2[2]+red2[3]) / 768.0f;
  const float rstd = 1.0f / sqrtf(var + 1e-5f);
  const float o0 = d0*rstd*w[t]     + b[t];
  const float o1 = d1*rstd*w[t+256] + b[t+256];
  const float o2 = d2*rstd*w[t+512] + b[t+512];
  if (OUT == 0){
    float* orow = (float*)outv + (size_t)row * CDIM;
    orow[t] = o0; orow[t+256] = o1; orow[t+512] = o2;
  } else {
    unsigned short* orow = (unsigned short*)outv + (size_t)row * CDIM;
    orow[t] = f2bf(o0); orow[t+256] = f2bf(o1); orow[t+512] = f2bf(o2);
  }
}

// -------- LN1 fused with 3-plane bf16 split (big-ws path) -----------------
__global__ __launch_bounds__(256) void ln_split3_kernel(
    const float* __restrict__ x, const float* __restrict__ w,
    const float* __restrict__ b, unsigned short* __restrict__ dst, size_t plane)
{
  const int row = blockIdx.x;
  const int t = threadIdx.x;
  const float* xr = x + (size_t)row * CDIM;
  float v0 = xr[t], v1 = xr[t+256], v2 = xr[t+512];
  float s = v0 + v1 + v2;
  __shared__ float red[4], red2[4];
  #pragma unroll
  for (int o=32;o>0;o>>=1) s += __shfl_down(s,o);
  if ((t&63)==0) red[t>>6] = s;
  __syncthreads();
  const float mean = (red[0]+red[1]+red[2]+red[3]) / 768.0f;
  const float d0=v0-mean, d1=v1-mean, d2=v2-mean;
  float vs = d0*d0 + d1*d1 + d2*d2;
  #pragma unroll
  for (int o=32;o>0;o>>=1) vs += __shfl_down(vs,o);
  if ((t&63)==0) red2[t>>6] = vs;
  __syncthreads();
  const float var = (red2[0]+red2[1]+red2[2]+red2[3]) / 768.0f;
  const float rstd = 1.0f / sqrtf(var + 1e-5f);
  const float ov[3] = { d0*rstd*w[t]     + b[t],
                        d1*rstd*w[t+256] + b[t+256],
                        d2*rstd*w[t+512] + b[t+512] };
  #pragma unroll
  for (int e=0;e<3;e++){
    const int col = t + e*256;
    const float f = ov[e];
    const unsigned short p0 = f2bf(f);
    const float r1 = f - bf2f(p0);
    const unsigned short p1 = f2bf(r1);
    const unsigned short p2 = f2bf(r1 - bf2f(p1));
    dst[(size_t)row*CDIM + col]             = p0;
    dst[plane + (size_t)row*CDIM + col]     = p1;
    dst[2*plane + (size_t)row*CDIM + col]   = p2;
  }
}

// ---------------- f32 -> bf16 conversion (4 elems/thread) ----------------
__global__ __launch_bounds__(256) void cvt_bf16_kernel(
    const float* __restrict__ src, unsigned short* __restrict__ dst, int n4)
{
  const int i = blockIdx.x*256 + threadIdx.x;
  if (i < n4){
    const float4 v = *(const float4*)(src + (size_t)i*4);
    dst[(size_t)i*4+0] = f2bf(v.x); dst[(size_t)i*4+1] = f2bf(v.y);
    dst[(size_t)i*4+2] = f2bf(v.z); dst[(size_t)i*4+3] = f2bf(v.w);
  }
}

// ---------------- f32 -> hi/lo bf16 split, row layout [n][2K] -------------
__global__ __launch_bounds__(192) void cvt3_kernel(
    const float* __restrict__ w, unsigned short* __restrict__ W3, int K)
{
  const int n = blockIdx.x, t = threadIdx.x;
  const float4 v = *(const float4*)(w + (size_t)n*K + t*4);
  ushort4 hi, lo;
  hi.x = f2bf(v.x); lo.x = f2bf(v.x - bf2f(hi.x));
  hi.y = f2bf(v.y); lo.y = f2bf(v.y - bf2f(hi.y));
  hi.z = f2bf(v.z); lo.z = f2bf(v.z - bf2f(hi.z));
  hi.w = f2bf(v.w); lo.w = f2bf(v.w - bf2f(hi.w));
  *(ushort4*)(W3 + (size_t)n*2*K + t*4)     = hi;
  *(ushort4*)(W3 + (size_t)n*2*K + K + t*4) = lo;
}

// ------- f32 -> 3 bf16 planes (a = p0 + p1 + p2, 24 mantissa bits) --------
__global__ __launch_bounds__(256) void cvt_split3_kernel(
    const float* __restrict__ src, unsigned short* __restrict__ dst,
    int n4, size_t plane)
{
  const int i = blockIdx.x*256 + threadIdx.x;
  if (i >= n4) return;
  const float4 v = *(const float4*)(src + (size_t)i*4);
  const float f[4] = {v.x, v.y, v.z, v.w};
  unsigned short p0[4], p1[4], p2[4];
  #pragma unroll
  for (int q=0;q<4;q++){
    p0[q] = f2bf(f[q]);
    const float r1 = f[q] - bf2f(p0[q]);
    p1[q] = f2bf(r1);
    const float r2 = r1 - bf2f(p1[q]);
    p2[q] = f2bf(r2);
  }
  *(ushort4*)(dst + (size_t)i*4)           = make_ushort4(p0[0],p0[1],p0[2],p0[3]);
  *(ushort4*)(dst + plane + (size_t)i*4)   = make_ushort4(p1[0],p1[1],p1[2],p1[3]);
  *(ushort4*)(dst + 2*plane + (size_t)i*4) = make_ushort4(p2[0],p2[1],p2[2],p2[3]);
}

// -------- f32 GEMM fallback (round-3 proven): out = A[M,K] @ W[N,K]^T -----
__global__ __launch_bounds__(256) void gemm_f32_kernel(
    const float* __restrict__ A, const float* __restrict__ W,
    float* __restrict__ out, int M, int N, int K)
{
  __shared__ float As[16][132];
  __shared__ float Bs[16][132];
  const int t  = threadIdx.x;
  const int tx = t & 15, ty = t >> 4;
  const int m0 = blockIdx.x * 128, n0 = blockIdx.y * 128;
  const int lr = t >> 2, lc = (t & 3) << 2;
  float acc[2][2][4][4] = {{{{0.f}}}};
  const float4 z4 = make_float4(0.f,0.f,0.f,0.f);
  const int rowA0 = m0 + lr, rowA1 = m0 + 64 + lr;
  const size_t strA0 = (size_t)rowA0 * K, strA1 = (size_t)rowA1 * K;
  const size_t strW0 = (size_t)(n0+lr) * K, strW1 = (size_t)(n0+64+lr) * K;
  for (int k0=0; k0<K; k0+=16){
    float4 a0 = (rowA0 < M) ? *(const float4*)(A + strA0 + k0 + lc) : z4;
    float4 a1 = (rowA1 < M) ? *(const float4*)(A + strA1 + k0 + lc) : z4;
    float4 w0 = *(const float4*)(W + strW0 + k0 + lc);
    float4 w1 = *(const float4*)(W + strW1 + k0 + lc);
    __syncthreads();
    As[lc+0][lr]=a0.x; As[lc+1][lr]=a0.y; As[lc+2][lr]=a0.z; As[lc+3][lr]=a0.w;
    As[lc+0][64+lr]=a1.x; As[lc+1][64+lr]=a1.y; As[lc+2][64+lr]=a1.z; As[lc+3][64+lr]=a1.w;
    Bs[lc+0][lr]=w0.x; Bs[lc+1][lr]=w0.y; Bs[lc+2][lr]=w0.z; Bs[lc+3][lr]=w0.w;
    Bs[lc+0][64+lr]=w1.x; Bs[lc+1][64+lr]=w1.y; Bs[lc+2][64+lr]=w1.z; Bs[lc+3][64+lr]=w1.w;
    __syncthreads();
    #pragma unroll
    for (int k=0;k<16;k++){
      const float4 av0 = *(const float4*)&As[k][ty*4];
      const float4 av1 = *(const float4*)&As[k][64+ty*4];
      const float4 bv0 = *(const float4*)&Bs[k][tx*4];
      const float4 bv1 = *(const float4*)&Bs[k][64+tx*4];
      const float ar[2][4] = {{av0.x,av0.y,av0.z,av0.w},{av1.x,av1.y,av1.z,av1.w}};
      const float br[2][4] = {{bv0.x,bv0.y,bv0.z,bv0.w},{bv1.x,bv1.y,bv1.z,bv1.w}};
      #pragma unroll
      for (int ri=0;ri<2;ri++)
        #pragma unroll
        for (int i=0;i<4;i++)
          #pragma unroll
          for (int ci=0;ci<2;ci++)
            #pragma unroll
            for (int j=0;j<4;j++)
              acc[ri][ci][i][j] = fmaf(ar[ri][i], br[ci][j], acc[ri][ci][i][j]);
    }
  }
  #pragma unroll
  for (int ri=0;ri<2;ri++){
    #pragma unroll
    for (int i=0;i<4;i++){
      const int row = m0 + ri*64 + ty*4 + i;
      if (row >= M) continue;
      #pragma unroll
      for (int ci=0;ci<2;ci++){
        const int col = n0 + ci*64 + tx*4;
        *(float4*)(out + (size_t)row*N + col) =
          make_float4(acc[ri][ci][i][0],acc[ri][ci][i][1],acc[ri][ci][i][2],acc[ri][ci][i][3]);
      }
    }
  }
}

// ==== 6-term qkv GEMM v5: M64 x N256, 8 waves (2Mx4N), 56 KB LDS ==========
__global__ __launch_bounds__(512) void mfma_gemm6w_kernel(
    const unsigned short* __restrict__ A3, const unsigned short* __restrict__ W3,
    float* __restrict__ out, int M, int N, int K, size_t planeA, size_t planeW,
    int gx)
{
  __shared__ __align__(16) unsigned short As[3][64*64];   // 24 KB
  __shared__ __align__(16) unsigned short Ws[256*64];     // 32 KB
  const int nwg = gridDim.x;
  const int q8 = nwg >> 3, r8 = nwg & 7;
  const int xcd = blockIdx.x & 7, lid = blockIdx.x >> 3;
  const int swz = (xcd < r8) ? (xcd*(q8+1) + lid) : (r8*(q8+1) + (xcd-r8)*q8 + lid);
  const int bx = swz % gx, by = swz / gx;

  const int t = threadIdx.x;
  const int w = t >> 6, lane = t & 63;
  const int m0 = bx * 64, n0 = by * 256;
  const int wr = w >> 2, wc = w & 3;
  f32x4 acc[2][4];
  #pragma unroll
  for (int i=0;i<2;i++)
    #pragma unroll
    for (int j=0;j<4;j++){ acc[i][j][0]=0.f; acc[i][j][1]=0.f; acc[i][j][2]=0.f; acc[i][j][3]=0.f; }

  const int srow = lane >> 3;
  const int slot = lane & 7;
  const int scol = (slot ^ srow) * 8;
  const int aloc = w*8;
  const int wloc = w*32;
  const int fr = lane & 15;
  const int kg = lane >> 4;

  #define SEGW(NA)                                                            \
    _Pragma("unroll")                                                         \
    for (int ksub = 0; ksub < 2; ksub++){                                     \
      const int kbyte = ksub*64 + kg*16;                                      \
      bf16x8 b[4];                                                            \
      _Pragma("unroll")                                                       \
      for (int ni=0; ni<4; ni++){                                             \
        const int br = wc*64 + ni*16 + fr;                                    \
        b[ni] = *(const bf16x8*)(Ws + br*64 + ((kbyte ^ ((br&7)<<4)) >> 1));  \
      }                                                                       \
      _Pragma("unroll")                                                       \
      for (int p=0; p<NA; p++){                                               \
        bf16x8 a[2];                                                          \
        _Pragma("unroll")                                                     \
        for (int mi=0; mi<2; mi++){                                           \
          const int ar = wr*32 + mi*16 + fr;                                  \
          a[mi] = *(const bf16x8*)(As[p] + ar*64 + ((kbyte ^ ((ar&7)<<4)) >> 1)); \
        }                                                                     \
        _Pragma("unroll")                                                     \
        for (int mi=0; mi<2; mi++)                                            \
          _Pragma("unroll")                                                   \
          for (int ni=0; ni<4; ni++)                                          \
            acc[mi][ni] = __builtin_amdgcn_mfma_f32_16x16x32_bf16(a[mi], b[ni], acc[mi][ni], 0, 0, 0); \
      }                                                                       \
    }

  #define STAGE_W(P)                                                          \
    _Pragma("unroll")                                                         \
    for (int tt=0; tt<4; tt++){                                               \
      const int rl = wloc + tt*8;                                             \
      GLDS(W3 + (size_t)(P)*planeW + (size_t)(n0+rl+srow)*K + k0 + scol, Ws + rl*64); \
    }

  for (int k0 = 0; k0 < K; k0 += 64){
    __syncthreads();
    #pragma unroll
    for (int p=0; p<3; p++)
      GLDS(A3 + (size_t)p*planeA + (size_t)(m0+aloc+srow)*K + k0 + scol, As[p] + aloc*64);
    STAGE_W(0)
    __syncthreads();
    SEGW(3)
    __syncthreads();
    STAGE_W(1)
    __syncthreads();
    SEGW(2)
    __syncthreads();
    STAGE_W(2)
    __syncthreads();
    SEGW(1)
  }
  #undef SEGW
  #undef STAGE_W

  const int cL = lane & 15, rL = lane >> 4;
  #pragma unroll
  for (int mi=0; mi<2; mi++){
    #pragma unroll
    for (int ni=0; ni<4; ni++){
      const int col = n0 + wc*64 + ni*16 + cL;
      const int rowb = m0 + wr*32 + mi*16 + rL*4;
      #pragma unroll
      for (int r=0; r<4; r++){
        const int row = rowb + r;
        if (row >= M) continue;
        out[(size_t)row*N + col] = acc[mi][ni][r];
      }
    }
  }
}

// ==== plain bf16 GEMM v5: M64 x N256, 8 waves, 40 KB LDS (4 blocks/CU) ====
template<int EPI>
__global__ __launch_bounds__(512) void mfma_gemm1w_kernel(
    const unsigned short* __restrict__ A, const unsigned short* __restrict__ W,
    const float* __restrict__ bias, const float* __restrict__ gamma,
    const float* __restrict__ resid, void* __restrict__ outv,
    int M, int N, int K, int gx)
{
  __shared__ __align__(16) unsigned short As[64*64];      // 8 KB
  __shared__ __align__(16) unsigned short Ws[256*64];     // 32 KB
  const int nwg = gridDim.x;
  const int q8 = nwg >> 3, r8 = nwg & 7;
  const int xcd = blockIdx.x & 7, lid = blockIdx.x >> 3;
  const int swz = (xcd < r8) ? (xcd*(q8+1) + lid) : (r8*(q8+1) + (xcd-r8)*q8 + lid);
  const int bx = swz % gx, by = swz / gx;

  const int t = threadIdx.x;
  const int w = t >> 6, lane = t & 63;
  const int m0 = bx * 64, n0 = by * 256;
  const int wr = w >> 2, wc = w & 3;
  f32x4 acc[2][4];
  #pragma unroll
  for (int i=0;i<2;i++)
    #pragma unroll
    for (int j=0;j<4;j++){ acc[i][j][0]=0.f; acc[i][j][1]=0.f; acc[i][j][2]=0.f; acc[i][j][3]=0.f; }

  const int srow = lane >> 3;
  const int slot = lane & 7;
  const int scol = (slot ^ srow) * 8;
  const int aloc = w*8;
  const int wloc = w*32;
  const int fr = lane & 15;
  const int kg = lane >> 4;

  for (int k0 = 0; k0 < K; k0 += 64){
    __syncthreads();
    GLDS(A + (size_t)(m0+aloc+srow)*K + k0 + scol, As + aloc*64);
    #pragma unroll
    for (int tt=0; tt<4; tt++){
      const int rl = wloc + tt*8;
      GLDS(W + (size_t)(n0+rl+srow)*K + k0 + scol, Ws + rl*64);
    }
    __syncthreads();
    #pragma unroll
    for (int ksub = 0; ksub < 2; ksub++){
      const int kbyte = ksub*64 + kg*16;
      bf16x8 b[4];
      #pragma unroll
      for (int ni=0; ni<4; ni++){
        const int br = wc*64 + ni*16 + fr;
        b[ni] = *(const bf16x8*)(Ws + br*64 + ((kbyte ^ ((br&7)<<4)) >> 1));
      }
      bf16x8 a[2];
      #pragma unroll
      for (int mi=0; mi<2; mi++){
        const int ar = wr*32 + mi*16 + fr;
        a[mi] = *(const bf16x8*)(As + ar*64 + ((kbyte ^ ((ar&7)<<4)) >> 1));
      }
      #pragma unroll
      for (int mi=0; mi<2; mi++)
        #pragma unroll
        for (int ni=0; ni<4; ni++)
          acc[mi][ni] = __builtin_amdgcn_mfma_f32_16x16x32_bf16(a[mi], b[ni], acc[mi][ni], 0, 0, 0);
    }
  }

  const int cL = lane & 15, rL = lane >> 4;
  #pragma unroll
  for (int mi=0; mi<2; mi++){
    #pragma unroll
    for (int ni=0; ni<4; ni++){
      const int col = n0 + wc*64 + ni*16 + cL;
      const int rowb = m0 + wr*32 + mi*16 + rL*4;
      const float bb = bias[col];
      #pragma unroll
      for (int r=0; r<4; r++){
        const int row = rowb + r;
        if (row >= M) continue;
        float v = acc[mi][ni][r] + bb;
        if (EPI == 2){
          v = 0.5f*v*(1.0f + erff(v*0.7071067811865475f));
          ((unsigned short*)outv)[(size_t)row*N + col] = f2bf(v);
        } else {
          v = gamma[col]*v + resid[(size_t)row*N + col];
          ((float*)outv)[(size_t)row*N + col] = v;
        }
      }
    }
  }
}

// ==== proj v2: 3-term split, M64 x N256, 8 waves, 48 KB LDS (3 blocks/CU) ==
__global__ __launch_bounds__(512) void mfma_proj3_kernel(
    const unsigned short* __restrict__ A, const unsigned short* __restrict__ W,
    const float* __restrict__ bias, const float* __restrict__ gamma,
    const float* __restrict__ resid, float* __restrict__ out,
    int M, int N, int K, int gx)
{
  __shared__ __align__(16) unsigned short Ah[64*64], Al[64*64];  // 16 KB
  __shared__ __align__(16) unsigned short Ws[256*64];            // 32 KB
  const int nwg = gridDim.x;
  const int q8 = nwg >> 3, r8 = nwg & 7;
  const int xcd = blockIdx.x & 7, lid = blockIdx.x >> 3;
  const int swz = (xcd < r8) ? (xcd*(q8+1) + lid) : (r8*(q8+1) + (xcd-r8)*q8 + lid);
  const int bx = swz % gx, by = swz / gx;

  const int t = threadIdx.x;
  const int w = t >> 6, lane = t & 63;
  const int m0 = bx * 64, n0 = by * 256;
  const int wr = w >> 2, wc = w & 3;
  const int lda = 2*K;
  f32x4 acc[2][4];
  #pragma unroll
  for (int i=0;i<2;i++)
    #pragma unroll
    for (int j=0;j<4;j++){ acc[i][j][0]=0.f; acc[i][j][1]=0.f; acc[i][j][2]=0.f; acc[i][j][3]=0.f; }

  const int srow = lane >> 3;
  const int slot = lane & 7;
  const int scol = (slot ^ srow) * 8;
  const int aloc = w*8;
  const int wloc = w*32;
  const int fr = lane & 15;
  const int kg = lane >> 4;

  #define PSEG(NA)                                                            \
    _Pragma("unroll")                                                         \
    for (int ksub = 0; ksub < 2; ksub++){                                     \
      const int kbyte = ksub*64 + kg*16;                                      \
      bf16x8 b[4];                                                            \
      _Pragma("unroll")                                                       \
      for (int ni=0; ni<4; ni++){                                             \
        const int br = wc*64 + ni*16 + fr;                                    \
        b[ni] = *(const bf16x8*)(Ws + br*64 + ((kbyte ^ ((br&7)<<4)) >> 1));  \
      }                                                                       \
      _Pragma("unroll")                                                       \
      for (int mi=0; mi<2; mi++){                                             \
        const int ar = wr*32 + mi*16 + fr;                                    \
        const int ao = ar*64 + ((kbyte ^ ((ar&7)<<4)) >> 1);                  \
        bf16x8 ah = *(const bf16x8*)(Ah + ao);                                \
        _Pragma("unroll")                                                     \
        for (int ni=0; ni<4; ni++)                                            \
          acc[mi][ni] = __builtin_amdgcn_mfma_f32_16x16x32_bf16(ah, b[ni], acc[mi][ni], 0, 0, 0); \
        if (NA > 1){                                                          \
          bf16x8 al = *(const bf16x8*)(Al + ao);                              \
          _Pragma("unroll")                                                   \
          for (int ni=0; ni<4; ni++)                                          \
            acc[mi][ni] = __builtin_amdgcn_mfma_f32_16x16x32_bf16(al, b[ni], acc[mi][ni], 0, 0, 0); \
        }                                                                     \
      }                                                                       \
    }

  for (int k0 = 0; k0 < K; k0 += 64){
    __syncthreads();
    {
      const size_t abase = (size_t)(m0+aloc+srow)*lda + k0 + scol;
      GLDS(A + abase,     Ah + aloc*64);
      GLDS(A + abase + K, Al + aloc*64);
    }
    #pragma unroll
    for (int tt=0; tt<4; tt++){
      const int rl = wloc + tt*8;
      GLDS(W + (size_t)(n0+rl+srow)*lda + k0 + scol, Ws + rl*64);
    }
    __syncthreads();
    PSEG(2)
    __syncthreads();
    #pragma unroll
    for (int tt=0; tt<4; tt++){
      const int rl = wloc + tt*8;
      GLDS(W + (size_t)(n0+rl+srow)*lda + K + k0 + scol, Ws + rl*64);
    }
    __syncthreads();
    PSEG(1)
  }
  #undef PSEG

  const int cL = lane & 15, rL = lane >> 4;
  #pragma unroll
  for (int mi=0; mi<2; mi++){
    #pragma unroll
    for (int ni=0; ni<4; ni++){
      const int col = n0 + wc*64 + ni*16 + cL;
      const int rowb = m0 + wr*32 + mi*16 + rL*4;
      const float bb = bias[col];
      const float gg = gamma[col];
      #pragma unroll
      for (int r=0; r<4; r++){
        const int row = rowb + r;
        if (row >= M) continue;
        out[(size_t)row*N + col] = gg*(acc[mi][ni][r] + bb) + resid[(size_t)row*N + col];
      }
    }
  }
}

// ---- flash attention: zero-LDS; K/V rows broadcast from global -----------
// Writes mbuf (all rows) and lbuf (all rows, f32 1/l). Row-0 f64 normalizer
// moved to attn_sel (it computes the same logits per-column).
__global__ __launch_bounds__(256) void attn_flash_kernel(
    const float* __restrict__ qkv, double* __restrict__ mbuf,
    double* __restrict__ lbuf, unsigned short* __restrict__ msa3)
{
  const int bh = blockIdx.x;
  const int b = bh / NHEAD, h = bh % NHEAD;
  const float* basep = qkv + (size_t)b*NTOK*2304 + h*HD;
  const int i = threadIdx.x;
  if (i >= NTOK) return;
  float4 q[16], o[16];
  #pragma unroll
  for (int dd=0; dd<16; dd++){
    float4 tq = *(const float4*)(basep + (size_t)i*2304 + dd*4);
    q[dd] = make_float4(tq.x*0.125f, tq.y*0.125f, tq.z*0.125f, tq.w*0.125f);
    o[dd] = make_float4(0.f,0.f,0.f,0.f);
  }
  float m = -INFINITY, l = 0.f;
  for (int j=0;j<NTOK;j++){
    const float* krow = basep + (size_t)j*2304 + 768;   // uniform: broadcast
    float s0=0.f, s1=0.f, s2=0.f, s3=0.f;
    #pragma unroll
    for (int dd=0;dd<16;dd++){
      const float4 kk = *(const float4*)(krow + dd*4);
      s0 = fmaf(q[dd].x,kk.x,s0); s1 = fmaf(q[dd].y,kk.y,s1);
      s2 = fmaf(q[dd].z,kk.z,s2); s3 = fmaf(q[dd].w,kk.w,s3);
    }
    const float s = (s0+s1)+(s2+s3);
    const float mn = fmaxf(m, s);
    const float sc = expf(m - mn);
    const float p  = expf(s - mn);
    l = l*sc + p;
    if (sc != 1.0f){
      #pragma unroll
      for (int dd=0;dd<16;dd++){
        o[dd].x *= sc; o[dd].y *= sc; o[dd].z *= sc; o[dd].w *= sc;
      }
    }
    m = mn;
    const float* vrow = basep + (size_t)j*2304 + 1536;  // uniform: broadcast
    #pragma unroll
    for (int dd=0;dd<16;dd++){
      const float4 vv = *(const float4*)(vrow + dd*4);
      o[dd].x = fmaf(p,vv.x,o[dd].x); o[dd].y = fmaf(p,vv.y,o[dd].y);
      o[dd].z = fmaf(p,vv.z,o[dd].z); o[dd].w = fmaf(p,vv.w,o[dd].w);
    }
  }
  const float linv = 1.0f/l;
  mbuf[bh*NTOK+i] = (double)m;
  lbuf[bh*NTOK+i] = (double)linv;
  unsigned short* orow = msa3 + ((size_t)b*NTOK + i)*1536 + h*HD;
  #pragma unroll
  for (int dd=0;dd<16;dd++){
    const float4 v = make_float4(o[dd].x*linv, o[dd].y*linv, o[dd].z*linv, o[dd].w*linv);
    ushort4 hi, lo;
    hi.x = f2bf(v.x); lo.x = f2bf(v.x - bf2f(hi.x));
    hi.y = f2bf(v.y); lo.y = f2bf(v.y - bf2f(hi.y));
    hi.z = f2bf(v.z); lo.z = f2bf(v.z - bf2f(hi.z));
    hi.w = f2bf(v.w); lo.w = f2bf(v.w - bf2f(hi.w));
    *(ushort4*)(orow + dd*4)       = hi;
    *(ushort4*)(orow + 768 + dd*4) = lo;
  }
}

// ---- selector stats: Q rows broadcast from global; f64 l0 computed here --
// thread = column j; kreg raw; Q scaled per-use by exact 0.125f.
__global__ __launch_bounds__(256) void attn_sel_kernel(
    const float* __restrict__ qkv, const double* __restrict__ mbuf,
    const double* __restrict__ lbuf, double* __restrict__ ta_part)
{
  __shared__ double q0s[HD];
  __shared__ float msf[NTOK], lsf[NTOK];
  __shared__ double m0d;
  __shared__ double red[4];
  __shared__ double sh_cs0, sh_e00, sh_l0inv;
  const int bh = blockIdx.x;
  const int b = bh / NHEAD, h = bh % NHEAD;
  const float* basep = qkv + (size_t)b*NTOK*2304 + h*HD;
  if (threadIdx.x < 16){
    const float4 t4 = *(const float4*)(basep + threadIdx.x*4);
    q0s[threadIdx.x*4+0] = (double)t4.x*0.125; q0s[threadIdx.x*4+1] = (double)t4.y*0.125;
    q0s[threadIdx.x*4+2] = (double)t4.z*0.125; q0s[threadIdx.x*4+3] = (double)t4.w*0.125;
  }
  for (int li=threadIdx.x; li<NTOK; li+=256){
    msf[li] = (float)mbuf[bh*NTOK+li];
    lsf[li] = (float)lbuf[bh*NTOK+li];
  }
  if (threadIdx.x == 0) m0d = mbuf[bh*NTOK];
  __syncthreads();
  const int j = threadIdx.x;
  double colsum = 0.0, e0 = 0.0;
  if (j < NTOK){
    float4 kreg[16];
    #pragma unroll
    for (int dd=0;dd<16;dd++) kreg[dd] = *(const float4*)(basep + (size_t)j*2304 + 768 + dd*4);
    // exact f64 row-0 logit -> e0_j = exp(s64 - m0)
    {
      double s64 = 0.0;
      #pragma unroll
      for (int dd=0;dd<16;dd++){
        s64 = fma(q0s[dd*4+0], (double)kreg[dd].x, s64);
        s64 = fma(q0s[dd*4+1], (double)kreg[dd].y, s64);
        s64 = fma(q0s[dd*4+2], (double)kreg[dd].z, s64);
        s64 = fma(q0s[dd*4+3], (double)kreg[dd].w, s64);
      }
      e0 = exp(s64 - m0d);
    }
    // colsum over rows 1..196; Q row broadcast from global, scaled 0.125 (exact)
    for (int i2=1;i2<NTOK;i2++){
      const float* qrow = basep + (size_t)i2*2304;   // uniform: broadcast
      float s0=0.f, s1=0.f, s2=0.f, s3=0.f;
      #pragma unroll
      for (int dd=0;dd<16;dd++){
        const float4 qq = *(const float4*)(qrow + dd*4);
        s0 = fmaf(qq.x*0.125f,kreg[dd].x,s0); s1 = fmaf(qq.y*0.125f,kreg[dd].y,s1);
        s2 = fmaf(qq.z*0.125f,kreg[dd].z,s2); s3 = fmaf(qq.w*0.125f,kreg[dd].w,s3);
      }
      const float s = (s0+s1)+(s2+s3);
      colsum += (double)(expf(s - msf[i2]) * lsf[i2]);
    }
  }
  // deterministic f64 block-reduce of e0 -> l0
  double e = e0;
  #pragma unroll
  for (int o=32;o>0;o>>=1) e += __shfl_down(e,o);
  if ((threadIdx.x&63)==0) red[threadIdx.x>>6] = e;
  __syncthreads();
  if (threadIdx.x == 0){
    sh_l0inv = 1.0/(red[0]+red[1]+red[2]+red[3]);
    sh_cs0 = colsum;
    sh_e00 = e0;
  }
  __syncthreads();
  if (j >= 1 && j < NTOK){
    const double row0 = e0 * sh_l0inv;
    const double r00  = sh_e00 * sh_l0inv;
    ta_part[(size_t)bh*NIMG + (j-1)] = row0 * (sh_cs0 / 196.0) + (colsum / 196.0) * r00;
  }
}

// -------- circulant coefficients, parallel: one block per d ---------------
__global__ __launch_bounds__(256) void circ_kernel(float* __restrict__ circ)
{
  const int d = blockIdx.x;
  const int g = threadIdx.x;
  __shared__ double rs[4], is[4];
  double re = 0.0, im = 0.0;
  if (g < NIMG){
    const double d0   = (196.0 * 0.15 / 2.0);
    const double twod = 2.0 * d0 * d0;
    const double gg = (double)g - 97.5;
    const double kg = 1.0 - exp(-(gg*gg)/twod);
    const int gd = (g*d) % NIMG;
    const double ang = 6.283185307179586476925286766559 * ((double)gd / 196.0);
    re = kg * cos(ang);
    im = kg * sin(ang);
  }
  #pragma unroll
  for (int o=32;o>0;o>>=1){ re += __shfl_down(re,o); im += __shfl_down(im,o); }
  if ((g&63)==0){ rs[g>>6] = re; is[g>>6] = im; }
  __syncthreads();
  if (g == 0){
    circ[d]        = (float)((rs[0]+rs[1]+rs[2]+rs[3]) / 196.0);
    circ[NIMG + d] = (float)((is[0]+is[1]+is[2]+is[3]) / 196.0);
  }
}

// -------- low-frequency-energy: f32 conv, f64 accumulation ----------------
__global__ __launch_bounds__(256) void lfe_kernel(
    const float* __restrict__ x1, const float* __restrict__ circ,
    double* __restrict__ lfe_part, double* __restrict__ den_part)
{
  __shared__ float xs[NIMG][36];
  __shared__ float2 c2[NIMG];
  __shared__ double red[4];
  const int cg = blockIdx.x, b = blockIdx.y;
  const int c0 = cg * 32;
  for (int li=threadIdx.x; li<NIMG*32; li+=256){
    const int m = li >> 5, ch = li & 31;
    xs[m][ch] = x1[((size_t)b*NTOK + 1 + m)*CDIM + c0 + ch];
  }
  for (int li=threadIdx.x; li<NIMG; li+=256) c2[li] = make_float2(circ[li], circ[NIMG+li]);
  __syncthreads();
  const int n = threadIdx.x;
  double lfe_sum = 0.0, den_sum = 0.0;
  if (n < NIMG){
    #pragma unroll 1
    for (int g=0; g<4; g++){
      const int cc0 = g*8;
      float re[8] = {0,0,0,0,0,0,0,0};
      float im[8] = {0,0,0,0,0,0,0,0};
      int d = n;
      for (int mm=0; mm<NIMG; mm++){
        const float2 cc = c2[d];
        const float4 xa = *(const float4*)&xs[mm][cc0];
        const float4 xb = *(const float4*)&xs[mm][cc0+4];
        const float xv[8] = {xa.x,xa.y,xa.z,xa.w,xb.x,xb.y,xb.z,xb.w};
        #pragma unroll
        for (int q=0;q<8;q++){
          re[q] = fmaf(cc.x, xv[q], re[q]);
          im[q] = fmaf(cc.y, xv[q], im[q]);
        }
        d = (d==0) ? (NIMG-1) : (d-1);
      }
      #pragma unroll
      for (int q=0;q<8;q++) lfe_sum += (double)sqrtf(re[q]*re[q] + im[q]*im[q]);
    }
    #pragma unroll
    for (int q=0;q<8;q++){
      const float4 xv = *(const float4*)&xs[n][q*4];
      den_sum += (double)fabsf(xv.x)+(double)fabsf(xv.y)+(double)fabsf(xv.z)+(double)fabsf(xv.w);
    }
    lfe_part[((size_t)b*24 + cg)*NIMG + n] = lfe_sum;
  }
  double s = (n < NIMG) ? den_sum : 0.0;
  #pragma unroll
  for (int o=32;o>0;o>>=1) s += __shfl_down(s,o);
  if ((threadIdx.x & 63) == 0) red[threadIdx.x >> 6] = s;
  __syncthreads();
  if (threadIdx.x == 0) den_part[b*24 + cg] = red[0]+red[1]+red[2]+red[3];
}

// -------- merged head-reduce + scores (per b, bit-identical math) ---------
__global__ __launch_bounds__(256) void reduce_scores_kernel(
    const double* __restrict__ ta_part, const double* __restrict__ lfe_part,
    const double* __restrict__ den_part, double* __restrict__ scores)
{
  const int b = blockIdx.x, j = threadIdx.x;
  if (j < NIMG){
    double s = 0.0;
    for (int h=0; h<NHEAD; h++) s += ta_part[((size_t)b*NHEAD + h)*NIMG + j];
    const double ta = s / 12.0;
    double num = 0.0;
    for (int cg=0; cg<24; cg++) num += lfe_part[((size_t)b*24 + cg)*NIMG + j];
    double den = 0.0;
    for (int cg=0; cg<24; cg++) den += den_part[b*24 + cg];
    const double tl = num / (den / 196.0);
    scores[b*NIMG + j] = tl * ta;
  }
}

// -------- top-118 + gather fused: 1 wave per batch ------------------------
__global__ void topk_gather_kernel(const double* __restrict__ scores,
                                   const float* __restrict__ x1,
                                   float* __restrict__ xsel)
{
  __shared__ double w[NIMG];
  __shared__ int bi_sh;
  const int b = blockIdx.x, lane = threadIdx.x;   // blockDim = 64
  for (int i=lane; i<NIMG; i+=64) w[i] = scores[b*NIMG + i];
  {
    const float4* s0 = (const float4*)(x1 + ((size_t)b*NTOK)*CDIM);
    float4* d0 = (float4*)(xsel + ((size_t)b*(NSEL+1))*CDIM);
    #pragma unroll
    for (int c=0;c<3;c++) d0[lane + c*64] = s0[lane + c*64];
  }
  __syncthreads();
  for (int r=0; r<NSEL; r++){
    double bv = -INFINITY; int bi = NIMG;
    for (int i=lane; i<NIMG; i+=64){
      const double v = w[i];
      if (v > bv){ bv = v; bi = i; }
    }
    #pragma unroll
    for (int o=32;o>0;o>>=1){
      const double ov = __shfl_down(bv,o);
      const int    oi = __shfl_down(bi,o);
      if (ov > bv || (ov == bv && oi < bi)){ bv = ov; bi = oi; }
    }
    if (lane == 0){
      w[bi] = -INFINITY;
      bi_sh = bi;
    }
    __syncthreads();
    const int src = 1 + bi_sh;
    const float4* s = (const float4*)(x1 + ((size_t)b*NTOK + src)*CDIM);
    float4* d = (float4*)(xsel + ((size_t)b*(NSEL+1) + 1 + r)*CDIM);
    #pragma unroll
    for (int c=0;c<3;c++) d[lane + c*64] = s[lane + c*64];
    __syncthreads();
  }
}

// ===========================================================================
extern "C" void kernel_launch(void* const* d_in, const int* in_sizes, int n_in,
                              void* d_out, int out_size, void* d_ws, size_t ws_size,
                              hipStream_t stream)
{
  const float* x      = (const float*)d_in[0];
  const float* ln1_w  = (const float*)d_in[1];
  const float* ln1_b  = (const float*)d_in[2];
  const float* qkv_w  = (const float*)d_in[3];
  const float* proj_w = (const float*)d_in[4];
  const float* proj_b = (const float*)d_in[5];
  const float* gamma1 = (const float*)d_in[6];
  const float* ln2_w  = (const float*)d_in[7];
  const float* ln2_b  = (const float*)d_in[8];
  const float* fc1_w  = (const float*)d_in[9];
  const float* fc1_b  = (const float*)d_in[10];
  const float* fc2_w  = (const float*)d_in[11];
  const float* fc2_b  = (const float*)d_in[12];
  const float* gamma2 = (const float*)d_in[13];
  float* out = (float*)d_out;
  float* ws  = (float*)d_ws;

  float* R1 = ws;                                   // 9,732,096 f
  float* R2 = ws + 9732096;                         // 29,048,832 f
  double* D = (double*)(ws + 9732096 + 29048832);   // f-off 38,780,928
  double* mbuf = D;                   // 151296
  double* lbuf = mbuf + 151296;       // 151296
  double* tap  = lbuf + 151296;       // 150528
  double* ta   = tap  + 150528;       // 12544 (unused)
  double* lfep = ta   + 12544;        // 301056
  double* denp = lfep + 301056;       // 1536
  double* sc   = denp + 1536;         // 12544
  float* circ  = (float*)(sc + 12544);        // 392 f
  unsigned short* W3p = (unsigned short*)(ws + 40350472);   // 768x1536 us
  unsigned short* WQ3 = (unsigned short*)(ws + 40940296);   // 3 x 2304x768 us
  unsigned short* XQ3 = (unsigned short*)(ws + 43594504);   // 3 x 12672x768 us
  const size_t NEED_BYTES = (size_t)58192648 * 4;           // ~233 MB

  float* xln  = R1;
  unsigned short* msa3 = (unsigned short*)R1;
  float* xsel = R1;
  float* qkv  = R2;
  float* x1   = R2;
  unsigned short* ln2o_bf = (unsigned short*)(R2 + 9682944);   // 7680*768
  unsigned short* fc1w_bf = (unsigned short*)(R2 + 12632064);  // 3072*768
  unsigned short* fc2w_bf = (unsigned short*)(R2 + 13811712);  // 768*3072
  unsigned short* h1_bf   = (unsigned short*)(R2 + 14991360);  // 7680*3072

  // 1-2) LN1 + qkv = ln(x) @ qkv_w^T  [12608,2304]
  if (ws_size >= NEED_BYTES){
    ln_split3_kernel<<<ROWS_FULL, 256, 0, stream>>>(x, ln1_w, ln1_b, XQ3, (size_t)9732096);
    cvt_split3_kernel<<<(442368+255)/256, 256, 0, stream>>>(qkv_w, WQ3, 442368, (size_t)1769472);
    mfma_gemm6w_kernel<<<197*9, 512, 0, stream>>>(XQ3, WQ3, qkv, ROWS_FULL, 2304, 768,
                                                  (size_t)9732096, (size_t)1769472, 197);
  } else {
    ln_kernel<0><<<ROWS_FULL, 256, 0, stream>>>(x, ln1_w, ln1_b, xln);
    gemm_f32_kernel<<<dim3(99,18), 256, 0, stream>>>(xln, qkv_w, qkv, ROWS_FULL, 2304, 768);
  }
  // 3-4) flash attention (zero-LDS, K/V broadcast): stats + PV -> msa
  attn_flash_kernel<<<BATCH*NHEAD, 256, 0, stream>>>(qkv, mbuf, lbuf, msa3);
  // 5) selector stats (Q broadcast, f64 l0 in-kernel)
  attn_sel_kernel<<<BATCH*NHEAD, 256, 0, stream>>>(qkv, mbuf, lbuf, tap);
  // 6) proj via 3-term split MFMA v2: x1 = gamma1*(msa@proj_w^T + b) + x
  cvt3_kernel<<<CDIM, 192, 0, stream>>>(proj_w, W3p, CDIM);
  mfma_proj3_kernel<<<197*3, 512, 0, stream>>>(msa3, W3p, proj_b, gamma1, x,
                                               x1, ROWS_FULL, CDIM, CDIM, 197);
  // 6b) fc weights -> bf16
  cvt_bf16_kernel<<<2304, 256, 0, stream>>>(fc1_w, fc1w_bf, 589824);
  cvt_bf16_kernel<<<2304, 256, 0, stream>>>(fc2_w, fc2w_bf, 589824);
  // 7) selector scores (head-reduce + scores merged)
  circ_kernel<<<NIMG, 256, 0, stream>>>(circ);
  lfe_kernel<<<dim3(24, BATCH), 256, 0, stream>>>(x1, circ, lfep, denp);
  reduce_scores_kernel<<<BATCH, 256, 0, stream>>>(tap, lfep, denp, sc);
  // 8) top-118 + gather fused (xsel over dead msa3)
  topk_gather_kernel<<<BATCH, 64, 0, stream>>>(sc, x1, xsel);
  // 9) MLP: LN2 -> bf16, fc1/fc2 via v5-style M64xN256 MFMA
  ln_kernel<1><<<ROWS_SEL, 256, 0, stream>>>(xsel, ln2_w, ln2_b, ln2o_bf);
  mfma_gemm1w_kernel<2><<<119*12, 512, 0, stream>>>(ln2o_bf, fc1w_bf, fc1_b, nullptr,
                                                    nullptr, h1_bf, ROWS_SEL, 3072, 768, 119);
  mfma_gemm1w_kernel<3><<<119*3, 512, 0, stream>>>(h1_bf, fc2w_bf, fc2_b, gamma2,
                                                   xsel, out, ROWS_SEL, 768, 3072, 119);
}

// Round 16
// 1291.366 us; speedup vs baseline: 1.3720x; 1.3720x over previous
//
#include <hip/hip_runtime.h>
#include <math.h>

#define NTOK 197
#define NIMG 196
#define CDIM 768
#define NHEAD 12
#define HD 64
#define BATCH 64
#define NSEL 118
#define ROWS_FULL (BATCH*NTOK)     // 12608
#define ROWS_SEL  (BATCH*(NSEL+1)) // 7616

typedef short bf16x8 __attribute__((ext_vector_type(8)));
typedef float f32x4  __attribute__((ext_vector_type(4)));

#define GLDS(g, l) __builtin_amdgcn_global_load_lds( \
    (const __attribute__((address_space(1))) void*)(g), \
    (__attribute__((address_space(3))) void*)(l), 16, 0, 0)

__device__ __forceinline__ unsigned short f2bf(float f){
  union { float f; unsigned u; } v; v.f = f;
  unsigned r = v.u + 0x7FFF + ((v.u >> 16) & 1);
  return (unsigned short)(r >> 16);
}
__device__ __forceinline__ float bf2f(unsigned short h){
  union { unsigned u; float f; } v; v.u = ((unsigned)h) << 16; return v.f;
}

// ---------------- LayerNorm (one block per row, C=768). OUT: 0=f32 1=bf16 --
template<int OUT>
__global__ __launch_bounds__(256) void ln_kernel(
    const float* __restrict__ x, const float* __restrict__ w,
    const float* __restrict__ b, void* __restrict__ outv)
{
  const int row = blockIdx.x;
  const int t = threadIdx.x;
  const float* xr = x + (size_t)row * CDIM;
  float v0 = xr[t], v1 = xr[t+256], v2 = xr[t+512];
  float s = v0 + v1 + v2;
  __shared__ float red[4], red2[4];
  #pragma unroll
  for (int o=32;o>0;o>>=1) s += __shfl_down(s,o);
  if ((t&63)==0) red[t>>6] = s;
  __syncthreads();
  const float mean = (red[0]+red[1]+red[2]+red[3]) / 768.0f;
  const float d0=v0-mean, d1=v1-mean, d2=v2-mean;
  float vs = d0*d0 + d1*d1 + d2*d2;
  #pragma unroll
  for (int o=32;o>0;o>>=1) vs += __shfl_down(vs,o);
  if ((t&63)==0) red2[t>>6] = vs;
  __syncthreads();
  const float var = (red2[0]+red2[1]+red2[2]+red2[3]) / 768.0f;
  const float rstd = 1.0f / sqrtf(var + 1e-5f);
  const float o0 = d0*rstd*w[t]     + b[t];
  const float o1 = d1*rstd*w[t+256] + b[t+256];
  const float o2 = d2*rstd*w[t+512] + b[t+512];
  if (OUT == 0){
    float* orow = (float*)outv + (size_t)row * CDIM;
    orow[t] = o0; orow[t+256] = o1; orow[t+512] = o2;
  } else {
    unsigned short* orow = (unsigned short*)outv + (size_t)row * CDIM;
    orow[t] = f2bf(o0); orow[t+256] = f2bf(o1); orow[t+512] = f2bf(o2);
  }
}

// -------- LN1 fused with 3-plane bf16 split (big-ws path) -----------------
__global__ __launch_bounds__(256) void ln_split3_kernel(
    const float* __restrict__ x, const float* __restrict__ w,
    const float* __restrict__ b, unsigned short* __restrict__ dst, size_t plane)
{
  const int row = blockIdx.x;
  const int t = threadIdx.x;
  const float* xr = x + (size_t)row * CDIM;
  float v0 = xr[t], v1 = xr[t+256], v2 = xr[t+512];
  float s = v0 + v1 + v2;
  __shared__ float red[4], red2[4];
  #pragma unroll
  for (int o=32;o>0;o>>=1) s += __shfl_down(s,o);
  if ((t&63)==0) red[t>>6] = s;
  __syncthreads();
  const float mean = (red[0]+red[1]+red[2]+red[3]) / 768.0f;
  const float d0=v0-mean, d1=v1-mean, d2=v2-mean;
  float vs = d0*d0 + d1*d1 + d2*d2;
  #pragma unroll
  for (int o=32;o>0;o>>=1) vs += __shfl_down(vs,o);
  if ((t&63)==0) red2[t>>6] = vs;
  __syncthreads();
  const float var = (red2[0]+red2[1]+red2[2]+red2[3]) / 768.0f;
  const float rstd = 1.0f / sqrtf(var + 1e-5f);
  const float ov[3] = { d0*rstd*w[t]     + b[t],
                        d1*rstd*w[t+256] + b[t+256],
                        d2*rstd*w[t+512] + b[t+512] };
  #pragma unroll
  for (int e=0;e<3;e++){
    const int col = t + e*256;
    const float f = ov[e];
    const unsigned short p0 = f2bf(f);
    const float r1 = f - bf2f(p0);
    const unsigned short p1 = f2bf(r1);
    const unsigned short p2 = f2bf(r1 - bf2f(p1));
    dst[(size_t)row*CDIM + col]             = p0;
    dst[plane + (size_t)row*CDIM + col]     = p1;
    dst[2*plane + (size_t)row*CDIM + col]   = p2;
  }
}

// ---------------- f32 -> bf16 conversion (4 elems/thread) ----------------
__global__ __launch_bounds__(256) void cvt_bf16_kernel(
    const float* __restrict__ src, unsigned short* __restrict__ dst, int n4)
{
  const int i = blockIdx.x*256 + threadIdx.x;
  if (i < n4){
    const float4 v = *(const float4*)(src + (size_t)i*4);
    dst[(size_t)i*4+0] = f2bf(v.x); dst[(size_t)i*4+1] = f2bf(v.y);
    dst[(size_t)i*4+2] = f2bf(v.z); dst[(size_t)i*4+3] = f2bf(v.w);
  }
}

// ---------------- f32 -> hi/lo bf16 split, row layout [n][2K] -------------
__global__ __launch_bounds__(192) void cvt3_kernel(
    const float* __restrict__ w, unsigned short* __restrict__ W3, int K)
{
  const int n = blockIdx.x, t = threadIdx.x;
  const float4 v = *(const float4*)(w + (size_t)n*K + t*4);
  ushort4 hi, lo;
  hi.x = f2bf(v.x); lo.x = f2bf(v.x - bf2f(hi.x));
  hi.y = f2bf(v.y); lo.y = f2bf(v.y - bf2f(hi.y));
  hi.z = f2bf(v.z); lo.z = f2bf(v.z - bf2f(hi.z));
  hi.w = f2bf(v.w); lo.w = f2bf(v.w - bf2f(hi.w));
  *(ushort4*)(W3 + (size_t)n*2*K + t*4)     = hi;
  *(ushort4*)(W3 + (size_t)n*2*K + K + t*4) = lo;
}

// ------- f32 -> 3 bf16 planes (a = p0 + p1 + p2, 24 mantissa bits) --------
__global__ __launch_bounds__(256) void cvt_split3_kernel(
    const float* __restrict__ src, unsigned short* __restrict__ dst,
    int n4, size_t plane)
{
  const int i = blockIdx.x*256 + threadIdx.x;
  if (i >= n4) return;
  const float4 v = *(const float4*)(src + (size_t)i*4);
  const float f[4] = {v.x, v.y, v.z, v.w};
  unsigned short p0[4], p1[4], p2[4];
  #pragma unroll
  for (int q=0;q<4;q++){
    p0[q] = f2bf(f[q]);
    const float r1 = f[q] - bf2f(p0[q]);
    p1[q] = f2bf(r1);
    const float r2 = r1 - bf2f(p1[q]);
    p2[q] = f2bf(r2);
  }
  *(ushort4*)(dst + (size_t)i*4)           = make_ushort4(p0[0],p0[1],p0[2],p0[3]);
  *(ushort4*)(dst + plane + (size_t)i*4)   = make_ushort4(p1[0],p1[1],p1[2],p1[3]);
  *(ushort4*)(dst + 2*plane + (size_t)i*4) = make_ushort4(p2[0],p2[1],p2[2],p2[3]);
}

// -------- f32 GEMM fallback (round-3 proven): out = A[M,K] @ W[N,K]^T -----
__global__ __launch_bounds__(256) void gemm_f32_kernel(
    const float* __restrict__ A, const float* __restrict__ W,
    float* __restrict__ out, int M, int N, int K)
{
  __shared__ float As[16][132];
  __shared__ float Bs[16][132];
  const int t  = threadIdx.x;
  const int tx = t & 15, ty = t >> 4;
  const int m0 = blockIdx.x * 128, n0 = blockIdx.y * 128;
  const int lr = t >> 2, lc = (t & 3) << 2;
  float acc[2][2][4][4] = {{{{0.f}}}};
  const float4 z4 = make_float4(0.f,0.f,0.f,0.f);
  const int rowA0 = m0 + lr, rowA1 = m0 + 64 + lr;
  const size_t strA0 = (size_t)rowA0 * K, strA1 = (size_t)rowA1 * K;
  const size_t strW0 = (size_t)(n0+lr) * K, strW1 = (size_t)(n0+64+lr) * K;
  for (int k0=0; k0<K; k0+=16){
    float4 a0 = (rowA0 < M) ? *(const float4*)(A + strA0 + k0 + lc) : z4;
    float4 a1 = (rowA1 < M) ? *(const float4*)(A + strA1 + k0 + lc) : z4;
    float4 w0 = *(const float4*)(W + strW0 + k0 + lc);
    float4 w1 = *(const float4*)(W + strW1 + k0 + lc);
    __syncthreads();
    As[lc+0][lr]=a0.x; As[lc+1][lr]=a0.y; As[lc+2][lr]=a0.z; As[lc+3][lr]=a0.w;
    As[lc+0][64+lr]=a1.x; As[lc+1][64+lr]=a1.y; As[lc+2][64+lr]=a1.z; As[lc+3][64+lr]=a1.w;
    Bs[lc+0][lr]=w0.x; Bs[lc+1][lr]=w0.y; Bs[lc+2][lr]=w0.z; Bs[lc+3][lr]=w0.w;
    Bs[lc+0][64+lr]=w1.x; Bs[lc+1][64+lr]=w1.y; Bs[lc+2][64+lr]=w1.z; Bs[lc+3][64+lr]=w1.w;
    __syncthreads();
    #pragma unroll
    for (int k=0;k<16;k++){
      const float4 av0 = *(const float4*)&As[k][ty*4];
      const float4 av1 = *(const float4*)&As[k][64+ty*4];
      const float4 bv0 = *(const float4*)&Bs[k][tx*4];
      const float4 bv1 = *(const float4*)&Bs[k][64+tx*4];
      const float ar[2][4] = {{av0.x,av0.y,av0.z,av0.w},{av1.x,av1.y,av1.z,av1.w}};
      const float br[2][4] = {{bv0.x,bv0.y,bv0.z,bv0.w},{bv1.x,bv1.y,bv1.z,bv1.w}};
      #pragma unroll
      for (int ri=0;ri<2;ri++)
        #pragma unroll
        for (int i=0;i<4;i++)
          #pragma unroll
          for (int ci=0;ci<2;ci++)
            #pragma unroll
            for (int j=0;j<4;j++)
              acc[ri][ci][i][j] = fmaf(ar[ri][i], br[ci][j], acc[ri][ci][i][j]);
    }
  }
  #pragma unroll
  for (int ri=0;ri<2;ri++){
    #pragma unroll
    for (int i=0;i<4;i++){
      const int row = m0 + ri*64 + ty*4 + i;
      if (row >= M) continue;
      #pragma unroll
      for (int ci=0;ci<2;ci++){
        const int col = n0 + ci*64 + tx*4;
        *(float4*)(out + (size_t)row*N + col) =
          make_float4(acc[ri][ci][i][0],acc[ri][ci][i][1],acc[ri][ci][i][2],acc[ri][ci][i][3]);
      }
    }
  }
}

// ==== 6-term qkv GEMM v5: M64 x N256, 8 waves (2Mx4N), 56 KB LDS ==========
__global__ __launch_bounds__(512) void mfma_gemm6w_kernel(
    const unsigned short* __restrict__ A3, const unsigned short* __restrict__ W3,
    float* __restrict__ out, int M, int N, int K, size_t planeA, size_t planeW,
    int gx)
{
  __shared__ __align__(16) unsigned short As[3][64*64];   // 24 KB
  __shared__ __align__(16) unsigned short Ws[256*64];     // 32 KB
  const int nwg = gridDim.x;
  const int q8 = nwg >> 3, r8 = nwg & 7;
  const int xcd = blockIdx.x & 7, lid = blockIdx.x >> 3;
  const int swz = (xcd < r8) ? (xcd*(q8+1) + lid) : (r8*(q8+1) + (xcd-r8)*q8 + lid);
  const int bx = swz % gx, by = swz / gx;

  const int t = threadIdx.x;
  const int w = t >> 6, lane = t & 63;
  const int m0 = bx * 64, n0 = by * 256;
  const int wr = w >> 2, wc = w & 3;
  f32x4 acc[2][4];
  #pragma unroll
  for (int i=0;i<2;i++)
    #pragma unroll
    for (int j=0;j<4;j++){ acc[i][j][0]=0.f; acc[i][j][1]=0.f; acc[i][j][2]=0.f; acc[i][j][3]=0.f; }

  const int srow = lane >> 3;
  const int slot = lane & 7;
  const int scol = (slot ^ srow) * 8;
  const int aloc = w*8;
  const int wloc = w*32;
  const int fr = lane & 15;
  const int kg = lane >> 4;

  #define SEGW(NA)                                                            \
    _Pragma("unroll")                                                         \
    for (int ksub = 0; ksub < 2; ksub++){                                     \
      const int kbyte = ksub*64 + kg*16;                                      \
      bf16x8 b[4];                                                            \
      _Pragma("unroll")                                                       \
      for (int ni=0; ni<4; ni++){                                             \
        const int br = wc*64 + ni*16 + fr;                                    \
        b[ni] = *(const bf16x8*)(Ws + br*64 + ((kbyte ^ ((br&7)<<4)) >> 1));  \
      }                                                                       \
      _Pragma("unroll")                                                       \
      for (int p=0; p<NA; p++){                                               \
        bf16x8 a[2];                                                          \
        _Pragma("unroll")                                                     \
        for (int mi=0; mi<2; mi++){                                           \
          const int ar = wr*32 + mi*16 + fr;                                  \
          a[mi] = *(const bf16x8*)(As[p] + ar*64 + ((kbyte ^ ((ar&7)<<4)) >> 1)); \
        }                                                                     \
        _Pragma("unroll")                                                     \
        for (int mi=0; mi<2; mi++)                                            \
          _Pragma("unroll")                                                   \
          for (int ni=0; ni<4; ni++)                                          \
            acc[mi][ni] = __builtin_amdgcn_mfma_f32_16x16x32_bf16(a[mi], b[ni], acc[mi][ni], 0, 0, 0); \
      }                                                                       \
    }

  #define STAGE_W(P)                                                          \
    _Pragma("unroll")                                                         \
    for (int tt=0; tt<4; tt++){                                               \
      const int rl = wloc + tt*8;                                             \
      GLDS(W3 + (size_t)(P)*planeW + (size_t)(n0+rl+srow)*K + k0 + scol, Ws + rl*64); \
    }

  for (int k0 = 0; k0 < K; k0 += 64){
    __syncthreads();
    #pragma unroll
    for (int p=0; p<3; p++)
      GLDS(A3 + (size_t)p*planeA + (size_t)(m0+aloc+srow)*K + k0 + scol, As[p] + aloc*64);
    STAGE_W(0)
    __syncthreads();
    SEGW(3)
    __syncthreads();
    STAGE_W(1)
    __syncthreads();
    SEGW(2)
    __syncthreads();
    STAGE_W(2)
    __syncthreads();
    SEGW(1)
  }
  #undef SEGW
  #undef STAGE_W

  const int cL = lane & 15, rL = lane >> 4;
  #pragma unroll
  for (int mi=0; mi<2; mi++){
    #pragma unroll
    for (int ni=0; ni<4; ni++){
      const int col = n0 + wc*64 + ni*16 + cL;
      const int rowb = m0 + wr*32 + mi*16 + rL*4;
      #pragma unroll
      for (int r=0; r<4; r++){
        const int row = rowb + r;
        if (row >= M) continue;
        out[(size_t)row*N + col] = acc[mi][ni][r];
      }
    }
  }
}

// ==== plain bf16 GEMM v5: M64 x N256, 8 waves, 40 KB LDS (4 blocks/CU) ====
template<int EPI>
__global__ __launch_bounds__(512) void mfma_gemm1w_kernel(
    const unsigned short* __restrict__ A, const unsigned short* __restrict__ W,
    const float* __restrict__ bias, const float* __restrict__ gamma,
    const float* __restrict__ resid, void* __restrict__ outv,
    int M, int N, int K, int gx)
{
  __shared__ __align__(16) unsigned short As[64*64];      // 8 KB
  __shared__ __align__(16) unsigned short Ws[256*64];     // 32 KB
  const int nwg = gridDim.x;
  const int q8 = nwg >> 3, r8 = nwg & 7;
  const int xcd = blockIdx.x & 7, lid = blockIdx.x >> 3;
  const int swz = (xcd < r8) ? (xcd*(q8+1) + lid) : (r8*(q8+1) + (xcd-r8)*q8 + lid);
  const int bx = swz % gx, by = swz / gx;

  const int t = threadIdx.x;
  const int w = t >> 6, lane = t & 63;
  const int m0 = bx * 64, n0 = by * 256;
  const int wr = w >> 2, wc = w & 3;
  f32x4 acc[2][4];
  #pragma unroll
  for (int i=0;i<2;i++)
    #pragma unroll
    for (int j=0;j<4;j++){ acc[i][j][0]=0.f; acc[i][j][1]=0.f; acc[i][j][2]=0.f; acc[i][j][3]=0.f; }

  const int srow = lane >> 3;
  const int slot = lane & 7;
  const int scol = (slot ^ srow) * 8;
  const int aloc = w*8;
  const int wloc = w*32;
  const int fr = lane & 15;
  const int kg = lane >> 4;

  for (int k0 = 0; k0 < K; k0 += 64){
    __syncthreads();
    GLDS(A + (size_t)(m0+aloc+srow)*K + k0 + scol, As + aloc*64);
    #pragma unroll
    for (int tt=0; tt<4; tt++){
      const int rl = wloc + tt*8;
      GLDS(W + (size_t)(n0+rl+srow)*K + k0 + scol, Ws + rl*64);
    }
    __syncthreads();
    #pragma unroll
    for (int ksub = 0; ksub < 2; ksub++){
      const int kbyte = ksub*64 + kg*16;
      bf16x8 b[4];
      #pragma unroll
      for (int ni=0; ni<4; ni++){
        const int br = wc*64 + ni*16 + fr;
        b[ni] = *(const bf16x8*)(Ws + br*64 + ((kbyte ^ ((br&7)<<4)) >> 1));
      }
      bf16x8 a[2];
      #pragma unroll
      for (int mi=0; mi<2; mi++){
        const int ar = wr*32 + mi*16 + fr;
        a[mi] = *(const bf16x8*)(As + ar*64 + ((kbyte ^ ((ar&7)<<4)) >> 1));
      }
      #pragma unroll
      for (int mi=0; mi<2; mi++)
        #pragma unroll
        for (int ni=0; ni<4; ni++)
          acc[mi][ni] = __builtin_amdgcn_mfma_f32_16x16x32_bf16(a[mi], b[ni], acc[mi][ni], 0, 0, 0);
    }
  }

  const int cL = lane & 15, rL = lane >> 4;
  #pragma unroll
  for (int mi=0; mi<2; mi++){
    #pragma unroll
    for (int ni=0; ni<4; ni++){
      const int col = n0 + wc*64 + ni*16 + cL;
      const int rowb = m0 + wr*32 + mi*16 + rL*4;
      const float bb = bias[col];
      #pragma unroll
      for (int r=0; r<4; r++){
        const int row = rowb + r;
        if (row >= M) continue;
        float v = acc[mi][ni][r] + bb;
        if (EPI == 2){
          v = 0.5f*v*(1.0f + erff(v*0.7071067811865475f));
          ((unsigned short*)outv)[(size_t)row*N + col] = f2bf(v);
        } else {
          v = gamma[col]*v + resid[(size_t)row*N + col];
          ((float*)outv)[(size_t)row*N + col] = v;
        }
      }
    }
  }
}

// ==== proj v2: 3-term split, M64 x N256, 8 waves, 48 KB LDS (3 blocks/CU) ==
__global__ __launch_bounds__(512) void mfma_proj3_kernel(
    const unsigned short* __restrict__ A, const unsigned short* __restrict__ W,
    const float* __restrict__ bias, const float* __restrict__ gamma,
    const float* __restrict__ resid, float* __restrict__ out,
    int M, int N, int K, int gx)
{
  __shared__ __align__(16) unsigned short Ah[64*64], Al[64*64];  // 16 KB
  __shared__ __align__(16) unsigned short Ws[256*64];            // 32 KB
  const int nwg = gridDim.x;
  const int q8 = nwg >> 3, r8 = nwg & 7;
  const int xcd = blockIdx.x & 7, lid = blockIdx.x >> 3;
  const int swz = (xcd < r8) ? (xcd*(q8+1) + lid) : (r8*(q8+1) + (xcd-r8)*q8 + lid);
  const int bx = swz % gx, by = swz / gx;

  const int t = threadIdx.x;
  const int w = t >> 6, lane = t & 63;
  const int m0 = bx * 64, n0 = by * 256;
  const int wr = w >> 2, wc = w & 3;
  const int lda = 2*K;
  f32x4 acc[2][4];
  #pragma unroll
  for (int i=0;i<2;i++)
    #pragma unroll
    for (int j=0;j<4;j++){ acc[i][j][0]=0.f; acc[i][j][1]=0.f; acc[i][j][2]=0.f; acc[i][j][3]=0.f; }

  const int srow = lane >> 3;
  const int slot = lane & 7;
  const int scol = (slot ^ srow) * 8;
  const int aloc = w*8;
  const int wloc = w*32;
  const int fr = lane & 15;
  const int kg = lane >> 4;

  #define PSEG(NA)                                                            \
    _Pragma("unroll")                                                         \
    for (int ksub = 0; ksub < 2; ksub++){                                     \
      const int kbyte = ksub*64 + kg*16;                                      \
      bf16x8 b[4];                                                            \
      _Pragma("unroll")                                                       \
      for (int ni=0; ni<4; ni++){                                             \
        const int br = wc*64 + ni*16 + fr;                                    \
        b[ni] = *(const bf16x8*)(Ws + br*64 + ((kbyte ^ ((br&7)<<4)) >> 1));  \
      }                                                                       \
      _Pragma("unroll")                                                       \
      for (int mi=0; mi<2; mi++){                                             \
        const int ar = wr*32 + mi*16 + fr;                                    \
        const int ao = ar*64 + ((kbyte ^ ((ar&7)<<4)) >> 1);                  \
        bf16x8 ah = *(const bf16x8*)(Ah + ao);                                \
        _Pragma("unroll")                                                     \
        for (int ni=0; ni<4; ni++)                                            \
          acc[mi][ni] = __builtin_amdgcn_mfma_f32_16x16x32_bf16(ah, b[ni], acc[mi][ni], 0, 0, 0); \
        if (NA > 1){                                                          \
          bf16x8 al = *(const bf16x8*)(Al + ao);                              \
          _Pragma("unroll")                                                   \
          for (int ni=0; ni<4; ni++)                                          \
            acc[mi][ni] = __builtin_amdgcn_mfma_f32_16x16x32_bf16(al, b[ni], acc[mi][ni], 0, 0, 0); \
        }                                                                     \
      }                                                                       \
    }

  for (int k0 = 0; k0 < K; k0 += 64){
    __syncthreads();
    {
      const size_t abase = (size_t)(m0+aloc+srow)*lda + k0 + scol;
      GLDS(A + abase,     Ah + aloc*64);
      GLDS(A + abase + K, Al + aloc*64);
    }
    #pragma unroll
    for (int tt=0; tt<4; tt++){
      const int rl = wloc + tt*8;
      GLDS(W + (size_t)(n0+rl+srow)*lda + k0 + scol, Ws + rl*64);
    }
    __syncthreads();
    PSEG(2)
    __syncthreads();
    #pragma unroll
    for (int tt=0; tt<4; tt++){
      const int rl = wloc + tt*8;
      GLDS(W + (size_t)(n0+rl+srow)*lda + K + k0 + scol, Ws + rl*64);
    }
    __syncthreads();
    PSEG(1)
  }
  #undef PSEG

  const int cL = lane & 15, rL = lane >> 4;
  #pragma unroll
  for (int mi=0; mi<2; mi++){
    #pragma unroll
    for (int ni=0; ni<4; ni++){
      const int col = n0 + wc*64 + ni*16 + cL;
      const int rowb = m0 + wr*32 + mi*16 + rL*4;
      const float bb = bias[col];
      const float gg = gamma[col];
      #pragma unroll
      for (int r=0; r<4; r++){
        const int row = rowb + r;
        if (row >= M) continue;
        out[(size_t)row*N + col] = gg*(acc[mi][ni][r] + bb) + resid[(size_t)row*N + col];
      }
    }
  }
}

// ---- flash attention (R12 exact): K in LDS, V broadcast, one pass --------
__global__ __launch_bounds__(256) void attn_flash_kernel(
    const float* __restrict__ qkv, double* __restrict__ mbuf,
    double* __restrict__ lbuf, unsigned short* __restrict__ msa3)
{
  __shared__ float Kt[NTOK][HD];      // 50,432 B
  __shared__ double q0s[HD];
  __shared__ float m0sh;
  __shared__ double red[4];
  __shared__ float l0f;
  const int bh = blockIdx.x;
  const int b = bh / NHEAD, h = bh % NHEAD;
  const float* basep = qkv + (size_t)b*NTOK*2304 + h*HD;
  for (int li=threadIdx.x; li<NTOK*16; li+=256){
    const int r = li >> 4, c4 = (li & 15) << 2;
    *(float4*)&Kt[r][c4] = *(const float4*)(basep + (size_t)r*2304 + 768 + c4);
  }
  if (threadIdx.x < 16){
    const float4 t4 = *(const float4*)(basep + threadIdx.x*4);
    q0s[threadIdx.x*4+0] = (double)t4.x*0.125; q0s[threadIdx.x*4+1] = (double)t4.y*0.125;
    q0s[threadIdx.x*4+2] = (double)t4.z*0.125; q0s[threadIdx.x*4+3] = (double)t4.w*0.125;
  }
  __syncthreads();
  const int i = threadIdx.x;
  float4 q[16];
  float4 o[16];
  float m = -INFINITY, l = 0.f;
  if (i < NTOK){
    #pragma unroll
    for (int dd=0; dd<16; dd++){
      float4 tq = *(const float4*)(basep + (size_t)i*2304 + dd*4);
      q[dd] = make_float4(tq.x*0.125f, tq.y*0.125f, tq.z*0.125f, tq.w*0.125f);
      o[dd] = make_float4(0.f,0.f,0.f,0.f);
    }
    for (int j=0;j<NTOK;j++){
      float s = 0.f;
      #pragma unroll
      for (int dd=0;dd<16;dd++){
        const float4 kk = *(const float4*)&Kt[j][dd*4];
        s = fmaf(q[dd].x,kk.x,s); s = fmaf(q[dd].y,kk.y,s);
        s = fmaf(q[dd].z,kk.z,s); s = fmaf(q[dd].w,kk.w,s);
      }
      const float mn = fmaxf(m, s);
      const float sc = expf(m - mn);     // 1.0f when max unchanged
      const float p  = expf(s - mn);
      l = l*sc + p;                      // same expression as original stats
      if (sc != 1.0f){
        #pragma unroll
        for (int dd=0;dd<16;dd++){
          o[dd].x *= sc; o[dd].y *= sc; o[dd].z *= sc; o[dd].w *= sc;
        }
      }
      m = mn;
      const float* vrow = basep + (size_t)j*2304 + 1536;  // uniform addr: broadcast
      #pragma unroll
      for (int dd=0;dd<16;dd++){
        const float4 vv = *(const float4*)(vrow + dd*4);
        o[dd].x = fmaf(p,vv.x,o[dd].x); o[dd].y = fmaf(p,vv.y,o[dd].y);
        o[dd].z = fmaf(p,vv.z,o[dd].z); o[dd].w = fmaf(p,vv.w,o[dd].w);
      }
    }
    mbuf[bh*NTOK+i] = (double)m;
    if (i > 0) lbuf[bh*NTOK+i] = (double)(1.0f/l);
    if (i == 0) m0sh = m;
  }
  __syncthreads();
  // exact f64 row-0 normalizer (Kt still resident)
  double e = 0.0;
  if (i < NTOK){
    double s64 = 0.0;
    #pragma unroll
    for (int d=0; d<HD; d++) s64 = fma(q0s[d], (double)Kt[i][d], s64);
    e = exp(s64 - (double)m0sh);
  }
  #pragma unroll
  for (int o2=32;o2>0;o2>>=1) e += __shfl_down(e,o2);
  if ((i&63)==0) red[i>>6] = e;
  __syncthreads();
  if (i==0){
    const double l0 = 1.0/(red[0]+red[1]+red[2]+red[3]);
    lbuf[bh*NTOK] = l0;
    l0f = (float)l0;
  }
  __syncthreads();
  if (i >= NTOK) return;
  const float linv = (i == 0) ? l0f : (1.0f/l);
  unsigned short* orow = msa3 + ((size_t)b*NTOK + i)*1536 + h*HD;
  #pragma unroll
  for (int dd=0;dd<16;dd++){
    const float4 v = make_float4(o[dd].x*linv, o[dd].y*linv, o[dd].z*linv, o[dd].w*linv);
    ushort4 hi, lo;
    hi.x = f2bf(v.x); lo.x = f2bf(v.x - bf2f(hi.x));
    hi.y = f2bf(v.y); lo.y = f2bf(v.y - bf2f(hi.y));
    hi.z = f2bf(v.z); lo.z = f2bf(v.z - bf2f(hi.z));
    hi.w = f2bf(v.w); lo.w = f2bf(v.w - bf2f(hi.w));
    *(ushort4*)(orow + dd*4)       = hi;
    *(ushort4*)(orow + 768 + dd*4) = lo;
  }
}

// ---- selector stats (R12 exact): Q in LDS, f32 colsum, f64 row0 ----------
__global__ __launch_bounds__(256) void attn_sel_kernel(
    const float* __restrict__ qkv, const double* __restrict__ mbuf,
    const double* __restrict__ lbuf, double* __restrict__ ta_part)
{
  __shared__ float Qt[NTOK][HD];
  __shared__ double q0s[HD];
  __shared__ float msf[NTOK], lsf[NTOK];
  __shared__ double m0d, l0inv;
  __shared__ double sh_cs0, sh_r00;
  const int bh = blockIdx.x;
  const int b = bh / NHEAD, h = bh % NHEAD;
  const float* basep = qkv + (size_t)b*NTOK*2304 + h*HD;
  for (int li=threadIdx.x; li<NTOK*16; li+=256){
    const int r = li >> 4, c4 = (li & 15) << 2;
    float4 tq = *(const float4*)(basep + (size_t)r*2304 + c4);
    Qt[r][c4+0]=tq.x*0.125f; Qt[r][c4+1]=tq.y*0.125f;
    Qt[r][c4+2]=tq.z*0.125f; Qt[r][c4+3]=tq.w*0.125f;
  }
  if (threadIdx.x < 16){
    const float4 t4 = *(const float4*)(basep + threadIdx.x*4);
    q0s[threadIdx.x*4+0] = (double)t4.x*0.125; q0s[threadIdx.x*4+1] = (double)t4.y*0.125;
    q0s[threadIdx.x*4+2] = (double)t4.z*0.125; q0s[threadIdx.x*4+3] = (double)t4.w*0.125;
  }
  for (int li=threadIdx.x; li<NTOK; li+=256){
    msf[li] = (float)mbuf[bh*NTOK+li];
    lsf[li] = (float)lbuf[bh*NTOK+li];
  }
  if (threadIdx.x == 0){ m0d = mbuf[bh*NTOK]; l0inv = lbuf[bh*NTOK]; }
  __syncthreads();
  const int j = threadIdx.x;
  double colsum = 0.0, row0 = 0.0;
  if (j < NTOK){
    float4 kreg[16];
    #pragma unroll
    for (int dd=0;dd<16;dd++) kreg[dd] = *(const float4*)(basep + (size_t)j*2304 + 768 + dd*4);
    {
      double s64 = 0.0;
      #pragma unroll
      for (int dd=0;dd<16;dd++){
        s64 = fma(q0s[dd*4+0], (double)kreg[dd].x, s64);
        s64 = fma(q0s[dd*4+1], (double)kreg[dd].y, s64);
        s64 = fma(q0s[dd*4+2], (double)kreg[dd].z, s64);
        s64 = fma(q0s[dd*4+3], (double)kreg[dd].w, s64);
      }
      row0 = exp(s64 - m0d) * l0inv;
    }
    for (int i2=1;i2<NTOK;i2++){
      float s = 0.f;
      #pragma unroll
      for (int dd=0;dd<16;dd++){
        const float4 qq = *(const float4*)&Qt[i2][dd*4];
        s = fmaf(qq.x,kreg[dd].x,s); s = fmaf(qq.y,kreg[dd].y,s);
        s = fmaf(qq.z,kreg[dd].z,s); s = fmaf(qq.w,kreg[dd].w,s);
      }
      colsum += (double)(expf(s - msf[i2]) * lsf[i2]);
    }
  }
  if (j == 0){ sh_cs0 = colsum; sh_r00 = row0; }
  __syncthreads();
  if (j >= 1 && j < NTOK){
    ta_part[(size_t)bh*NIMG + (j-1)] = row0 * (sh_cs0 / 196.0) + (colsum / 196.0) * sh_r00;
  }
}

// -------- circulant coefficients, parallel: one block per d ---------------
__global__ __launch_bounds__(256) void circ_kernel(float* __restrict__ circ)
{
  const int d = blockIdx.x;
  const int g = threadIdx.x;
  __shared__ double rs[4], is[4];
  double re = 0.0, im = 0.0;
  if (g < NIMG){
    const double d0   = (196.0 * 0.15 / 2.0);
    const double twod = 2.0 * d0 * d0;
    const double gg = (double)g - 97.5;
    const double kg = 1.0 - exp(-(gg*gg)/twod);
    const int gd = (g*d) % NIMG;
    const double ang = 6.283185307179586476925286766559 * ((double)gd / 196.0);
    re = kg * cos(ang);
    im = kg * sin(ang);
  }
  #pragma unroll
  for (int o=32;o>0;o>>=1){ re += __shfl_down(re,o); im += __shfl_down(im,o); }
  if ((g&63)==0){ rs[g>>6] = re; is[g>>6] = im; }
  __syncthreads();
  if (g == 0){
    circ[d]        = (float)((rs[0]+rs[1]+rs[2]+rs[3]) / 196.0);
    circ[NIMG + d] = (float)((is[0]+is[1]+is[2]+is[3]) / 196.0);
  }
}

// -------- low-frequency-energy: f32 conv, f64 accumulation ----------------
__global__ __launch_bounds__(256) void lfe_kernel(
    const float* __restrict__ x1, const float* __restrict__ circ,
    double* __restrict__ lfe_part, double* __restrict__ den_part)
{
  __shared__ float xs[NIMG][36];
  __shared__ float2 c2[NIMG];
  __shared__ double red[4];
  const int cg = blockIdx.x, b = blockIdx.y;
  const int c0 = cg * 32;
  for (int li=threadIdx.x; li<NIMG*32; li+=256){
    const int m = li >> 5, ch = li & 31;
    xs[m][ch] = x1[((size_t)b*NTOK + 1 + m)*CDIM + c0 + ch];
  }
  for (int li=threadIdx.x; li<NIMG; li+=256) c2[li] = make_float2(circ[li], circ[NIMG+li]);
  __syncthreads();
  const int n = threadIdx.x;
  double lfe_sum = 0.0, den_sum = 0.0;
  if (n < NIMG){
    #pragma unroll 1
    for (int g=0; g<4; g++){
      const int cc0 = g*8;
      float re[8] = {0,0,0,0,0,0,0,0};
      float im[8] = {0,0,0,0,0,0,0,0};
      int d = n;
      for (int mm=0; mm<NIMG; mm++){
        const float2 cc = c2[d];
        const float4 xa = *(const float4*)&xs[mm][cc0];
        const float4 xb = *(const float4*)&xs[mm][cc0+4];
        const float xv[8] = {xa.x,xa.y,xa.z,xa.w,xb.x,xb.y,xb.z,xb.w};
        #pragma unroll
        for (int q=0;q<8;q++){
          re[q] = fmaf(cc.x, xv[q], re[q]);
          im[q] = fmaf(cc.y, xv[q], im[q]);
        }
        d = (d==0) ? (NIMG-1) : (d-1);
      }
      #pragma unroll
      for (int q=0;q<8;q++) lfe_sum += (double)sqrtf(re[q]*re[q] + im[q]*im[q]);
    }
    #pragma unroll
    for (int q=0;q<8;q++){
      const float4 xv = *(const float4*)&xs[n][q*4];
      den_sum += (double)fabsf(xv.x)+(double)fabsf(xv.y)+(double)fabsf(xv.z)+(double)fabsf(xv.w);
    }
    lfe_part[((size_t)b*24 + cg)*NIMG + n] = lfe_sum;
  }
  double s = (n < NIMG) ? den_sum : 0.0;
  #pragma unroll
  for (int o=32;o>0;o>>=1) s += __shfl_down(s,o);
  if ((threadIdx.x & 63) == 0) red[threadIdx.x >> 6] = s;
  __syncthreads();
  if (threadIdx.x == 0) den_part[b*24 + cg] = red[0]+red[1]+red[2]+red[3];
}

// -------- merged head-reduce + scores (per b, bit-identical math) ---------
__global__ __launch_bounds__(256) void reduce_scores_kernel(
    const double* __restrict__ ta_part, const double* __restrict__ lfe_part,
    const double* __restrict__ den_part, double* __restrict__ scores)
{
  const int b = blockIdx.x, j = threadIdx.x;
  if (j < NIMG){
    double s = 0.0;
    for (int h=0; h<NHEAD; h++) s += ta_part[((size_t)b*NHEAD + h)*NIMG + j];
    const double ta = s / 12.0;
    double num = 0.0;
    for (int cg=0; cg<24; cg++) num += lfe_part[((size_t)b*24 + cg)*NIMG + j];
    double den = 0.0;
    for (int cg=0; cg<24; cg++) den += den_part[b*24 + cg];
    const double tl = num / (den / 196.0);
    scores[b*NIMG + j] = tl * ta;
  }
}

// -------- top-118 + gather fused: 1 wave per batch ------------------------
__global__ void topk_gather_kernel(const double* __restrict__ scores,
                                   const float* __restrict__ x1,
                                   float* __restrict__ xsel)
{
  __shared__ double w[NIMG];
  __shared__ int bi_sh;
  const int b = blockIdx.x, lane = threadIdx.x;   // blockDim = 64
  for (int i=lane; i<NIMG; i+=64) w[i] = scores[b*NIMG + i];
  {
    const float4* s0 = (const float4*)(x1 + ((size_t)b*NTOK)*CDIM);
    float4* d0 = (float4*)(xsel + ((size_t)b*(NSEL+1))*CDIM);
    #pragma unroll
    for (int c=0;c<3;c++) d0[lane + c*64] = s0[lane + c*64];
  }
  __syncthreads();
  for (int r=0; r<NSEL; r++){
    double bv = -INFINITY; int bi = NIMG;
    for (int i=lane; i<NIMG; i+=64){
      const double v = w[i];
      if (v > bv){ bv = v; bi = i; }
    }
    #pragma unroll
    for (int o=32;o>0;o>>=1){
      const double ov = __shfl_down(bv,o);
      const int    oi = __shfl_down(bi,o);
      if (ov > bv || (ov == bv && oi < bi)){ bv = ov; bi = oi; }
    }
    if (lane == 0){
      w[bi] = -INFINITY;
      bi_sh = bi;
    }
    __syncthreads();
    const int src = 1 + bi_sh;
    const float4* s = (const float4*)(x1 + ((size_t)b*NTOK + src)*CDIM);
    float4* d = (float4*)(xsel + ((size_t)b*(NSEL+1) + 1 + r)*CDIM);
    #pragma unroll
    for (int c=0;c<3;c++) d[lane + c*64] = s[lane + c*64];
    __syncthreads();
  }
}

// ===========================================================================
extern "C" void kernel_launch(void* const* d_in, const int* in_sizes, int n_in,
                              void* d_out, int out_size, void* d_ws, size_t ws_size,
                              hipStream_t stream)
{
  const float* x      = (const float*)d_in[0];
  const float* ln1_w  = (const float*)d_in[1];
  const float* ln1_b  = (const float*)d_in[2];
  const float* qkv_w  = (const float*)d_in[3];
  const float* proj_w = (const float*)d_in[4];
  const float* proj_b = (const float*)d_in[5];
  const float* gamma1 = (const float*)d_in[6];
  const float* ln2_w  = (const float*)d_in[7];
  const float* ln2_b  = (const float*)d_in[8];
  const float* fc1_w  = (const float*)d_in[9];
  const float* fc1_b  = (const float*)d_in[10];
  const float* fc2_w  = (const float*)d_in[11];
  const float* fc2_b  = (const float*)d_in[12];
  const float* gamma2 = (const float*)d_in[13];
  float* out = (float*)d_out;
  float* ws  = (float*)d_ws;

  float* R1 = ws;                                   // 9,732,096 f
  float* R2 = ws + 9732096;                         // 29,048,832 f
  double* D = (double*)(ws + 9732096 + 29048832);   // f-off 38,780,928
  double* mbuf = D;                   // 151296
  double* lbuf = mbuf + 151296;       // 151296
  double* tap  = lbuf + 151296;       // 150528
  double* ta   = tap  + 150528;       // 12544 (unused)
  double* lfep = ta   + 12544;        // 301056
  double* denp = lfep + 301056;       // 1536
  double* sc   = denp + 1536;         // 12544
  float* circ  = (float*)(sc + 12544);        // 392 f
  unsigned short* W3p = (unsigned short*)(ws + 40350472);   // 768x1536 us
  unsigned short* WQ3 = (unsigned short*)(ws + 40940296);   // 3 x 2304x768 us
  unsigned short* XQ3 = (unsigned short*)(ws + 43594504);   // 3 x 12672x768 us
  const size_t NEED_BYTES = (size_t)58192648 * 4;           // ~233 MB

  float* xln  = R1;
  unsigned short* msa3 = (unsigned short*)R1;
  float* xsel = R1;
  float* qkv  = R2;
  float* x1   = R2;
  unsigned short* ln2o_bf = (unsigned short*)(R2 + 9682944);   // 7680*768
  unsigned short* fc1w_bf = (unsigned short*)(R2 + 12632064);  // 3072*768
  unsigned short* fc2w_bf = (unsigned short*)(R2 + 13811712);  // 768*3072
  unsigned short* h1_bf   = (unsigned short*)(R2 + 14991360);  // 7680*3072

  // 1-2) LN1 + qkv = ln(x) @ qkv_w^T  [12608,2304]
  if (ws_size >= NEED_BYTES){
    ln_split3_kernel<<<ROWS_FULL, 256, 0, stream>>>(x, ln1_w, ln1_b, XQ3, (size_t)9732096);
    cvt_split3_kernel<<<(442368+255)/256, 256, 0, stream>>>(qkv_w, WQ3, 442368, (size_t)1769472);
    mfma_gemm6w_kernel<<<197*9, 512, 0, stream>>>(XQ3, WQ3, qkv, ROWS_FULL, 2304, 768,
                                                  (size_t)9732096, (size_t)1769472, 197);
  } else {
    ln_kernel<0><<<ROWS_FULL, 256, 0, stream>>>(x, ln1_w, ln1_b, xln);
    gemm_f32_kernel<<<dim3(99,18), 256, 0, stream>>>(xln, qkv_w, qkv, ROWS_FULL, 2304, 768);
  }
  // 3-4) flash attention (R12): stats + PV -> msa hi/lo bf16 (over R1)
  attn_flash_kernel<<<BATCH*NHEAD, 256, 0, stream>>>(qkv, mbuf, lbuf, msa3);
  // 5) selector stats (R12)
  attn_sel_kernel<<<BATCH*NHEAD, 256, 0, stream>>>(qkv, mbuf, lbuf, tap);
  // 6) proj via 3-term split MFMA v2: x1 = gamma1*(msa@proj_w^T + b) + x
  cvt3_kernel<<<CDIM, 192, 0, stream>>>(proj_w, W3p, CDIM);
  mfma_proj3_kernel<<<197*3, 512, 0, stream>>>(msa3, W3p, proj_b, gamma1, x,
                                               x1, ROWS_FULL, CDIM, CDIM, 197);
  // 6b) fc weights -> bf16
  cvt_bf16_kernel<<<2304, 256, 0, stream>>>(fc1_w, fc1w_bf, 589824);
  cvt_bf16_kernel<<<2304, 256, 0, stream>>>(fc2_w, fc2w_bf, 589824);
  // 7) selector scores (head-reduce + scores merged)
  circ_kernel<<<NIMG, 256, 0, stream>>>(circ);
  lfe_kernel<<<dim3(24, BATCH), 256, 0, stream>>>(x1, circ, lfep, denp);
  reduce_scores_kernel<<<BATCH, 256, 0, stream>>>(tap, lfep, denp, sc);
  // 8) top-118 + gather fused (xsel over dead msa3)
  topk_gather_kernel<<<BATCH, 64, 0, stream>>>(sc, x1, xsel);
  // 9) MLP: LN2 -> bf16, fc1/fc2 via v5-style M64xN256 MFMA
  ln_kernel<1><<<ROWS_SEL, 256, 0, stream>>>(xsel, ln2_w, ln2_b, ln2o_bf);
  mfma_gemm1w_kernel<2><<<119*12, 512, 0, stream>>>(ln2o_bf, fc1w_bf, fc1_b, nullptr,
                                                    nullptr, h1_bf, ROWS_SEL, 3072, 768, 119);
  mfma_gemm1w_kernel<3><<<119*3, 512, 0, stream>>>(h1_bf, fc2w_bf, fc2_b, gamma2,
                                                   xsel, out, ROWS_SEL, 768, 3072, 119);
}

// Round 17
// 1266.238 us; speedup vs baseline: 1.3993x; 1.0198x over previous
//
#include <hip/hip_runtime.h>
#include <math.h>

#define NTOK 197
#define NIMG 196
#define CDIM 768
#define NHEAD 12
#define HD 64
#define BATCH 64
#define NSEL 118
#define ROWS_FULL (BATCH*NTOK)     // 12608
#define ROWS_SEL  (BATCH*(NSEL+1)) // 7616

typedef short bf16x8 __attribute__((ext_vector_type(8)));
typedef float f32x4  __attribute__((ext_vector_type(4)));

#define GLDS(g, l) __builtin_amdgcn_global_load_lds( \
    (const __attribute__((address_space(1))) void*)(g), \
    (__attribute__((address_space(3))) void*)(l), 16, 0, 0)

__device__ __forceinline__ unsigned short f2bf(float f){
  union { float f; unsigned u; } v; v.f = f;
  unsigned r = v.u + 0x7FFF + ((v.u >> 16) & 1);
  return (unsigned short)(r >> 16);
}
__device__ __forceinline__ float bf2f(unsigned short h){
  union { unsigned u; float f; } v; v.u = ((unsigned)h) << 16; return v.f;
}

// ---------------- LayerNorm (one block per row, C=768). OUT: 0=f32 1=bf16 --
template<int OUT>
__global__ __launch_bounds__(256) void ln_kernel(
    const float* __restrict__ x, const float* __restrict__ w,
    const float* __restrict__ b, void* __restrict__ outv)
{
  const int row = blockIdx.x;
  const int t = threadIdx.x;
  const float* xr = x + (size_t)row * CDIM;
  float v0 = xr[t], v1 = xr[t+256], v2 = xr[t+512];
  float s = v0 + v1 + v2;
  __shared__ float red[4], red2[4];
  #pragma unroll
  for (int o=32;o>0;o>>=1) s += __shfl_down(s,o);
  if ((t&63)==0) red[t>>6] = s;
  __syncthreads();
  const float mean = (red[0]+red[1]+red[2]+red[3]) / 768.0f;
  const float d0=v0-mean, d1=v1-mean, d2=v2-mean;
  float vs = d0*d0 + d1*d1 + d2*d2;
  #pragma unroll
  for (int o=32;o>0;o>>=1) vs += __shfl_down(vs,o);
  if ((t&63)==0) red2[t>>6] = vs;
  __syncthreads();
  const float var = (red2[0]+red2[1]+red2[2]+red2[3]) / 768.0f;
  const float rstd = 1.0f / sqrtf(var + 1e-5f);
  const float o0 = d0*rstd*w[t]     + b[t];
  const float o1 = d1*rstd*w[t+256] + b[t+256];
  const float o2 = d2*rstd*w[t+512] + b[t+512];
  if (OUT == 0){
    float* orow = (float*)outv + (size_t)row * CDIM;
    orow[t] = o0; orow[t+256] = o1; orow[t+512] = o2;
  } else {
    unsigned short* orow = (unsigned short*)outv + (size_t)row * CDIM;
    orow[t] = f2bf(o0); orow[t+256] = f2bf(o1); orow[t+512] = f2bf(o2);
  }
}

// -------- LN1 fused with 3-plane bf16 split (big-ws path) -----------------
__global__ __launch_bounds__(256) void ln_split3_kernel(
    const float* __restrict__ x, const float* __restrict__ w,
    const float* __restrict__ b, unsigned short* __restrict__ dst, size_t plane)
{
  const int row = blockIdx.x;
  const int t = threadIdx.x;
  const float* xr = x + (size_t)row * CDIM;
  float v0 = xr[t], v1 = xr[t+256], v2 = xr[t+512];
  float s = v0 + v1 + v2;
  __shared__ float red[4], red2[4];
  #pragma unroll
  for (int o=32;o>0;o>>=1) s += __shfl_down(s,o);
  if ((t&63)==0) red[t>>6] = s;
  __syncthreads();
  const float mean = (red[0]+red[1]+red[2]+red[3]) / 768.0f;
  const float d0=v0-mean, d1=v1-mean, d2=v2-mean;
  float vs = d0*d0 + d1*d1 + d2*d2;
  #pragma unroll
  for (int o=32;o>0;o>>=1) vs += __shfl_down(vs,o);
  if ((t&63)==0) red2[t>>6] = vs;
  __syncthreads();
  const float var = (red2[0]+red2[1]+red2[2]+red2[3]) / 768.0f;
  const float rstd = 1.0f / sqrtf(var + 1e-5f);
  const float ov[3] = { d0*rstd*w[t]     + b[t],
                        d1*rstd*w[t+256] + b[t+256],
                        d2*rstd*w[t+512] + b[t+512] };
  #pragma unroll
  for (int e=0;e<3;e++){
    const int col = t + e*256;
    const float f = ov[e];
    const unsigned short p0 = f2bf(f);
    const float r1 = f - bf2f(p0);
    const unsigned short p1 = f2bf(r1);
    const unsigned short p2 = f2bf(r1 - bf2f(p1));
    dst[(size_t)row*CDIM + col]             = p0;
    dst[plane + (size_t)row*CDIM + col]     = p1;
    dst[2*plane + (size_t)row*CDIM + col]   = p2;
  }
}

// ---------------- f32 -> bf16 conversion (4 elems/thread) ----------------
__global__ __launch_bounds__(256) void cvt_bf16_kernel(
    const float* __restrict__ src, unsigned short* __restrict__ dst, int n4)
{
  const int i = blockIdx.x*256 + threadIdx.x;
  if (i < n4){
    const float4 v = *(const float4*)(src + (size_t)i*4);
    dst[(size_t)i*4+0] = f2bf(v.x); dst[(size_t)i*4+1] = f2bf(v.y);
    dst[(size_t)i*4+2] = f2bf(v.z); dst[(size_t)i*4+3] = f2bf(v.w);
  }
}

// ---------------- f32 -> hi/lo bf16 split, row layout [n][2K] -------------
__global__ __launch_bounds__(192) void cvt3_kernel(
    const float* __restrict__ w, unsigned short* __restrict__ W3, int K)
{
  const int n = blockIdx.x, t = threadIdx.x;
  const float4 v = *(const float4*)(w + (size_t)n*K + t*4);
  ushort4 hi, lo;
  hi.x = f2bf(v.x); lo.x = f2bf(v.x - bf2f(hi.x));
  hi.y = f2bf(v.y); lo.y = f2bf(v.y - bf2f(hi.y));
  hi.z = f2bf(v.z); lo.z = f2bf(v.z - bf2f(hi.z));
  hi.w = f2bf(v.w); lo.w = f2bf(v.w - bf2f(hi.w));
  *(ushort4*)(W3 + (size_t)n*2*K + t*4)     = hi;
  *(ushort4*)(W3 + (size_t)n*2*K + K + t*4) = lo;
}

// ------- f32 -> 3 bf16 planes (a = p0 + p1 + p2, 24 mantissa bits) --------
__global__ __launch_bounds__(256) void cvt_split3_kernel(
    const float* __restrict__ src, unsigned short* __restrict__ dst,
    int n4, size_t plane)
{
  const int i = blockIdx.x*256 + threadIdx.x;
  if (i >= n4) return;
  const float4 v = *(const float4*)(src + (size_t)i*4);
  const float f[4] = {v.x, v.y, v.z, v.w};
  unsigned short p0[4], p1[4], p2[4];
  #pragma unroll
  for (int q=0;q<4;q++){
    p0[q] = f2bf(f[q]);
    const float r1 = f[q] - bf2f(p0[q]);
    p1[q] = f2bf(r1);
    const float r2 = r1 - bf2f(p1[q]);
    p2[q] = f2bf(r2);
  }
  *(ushort4*)(dst + (size_t)i*4)           = make_ushort4(p0[0],p0[1],p0[2],p0[3]);
  *(ushort4*)(dst + plane + (size_t)i*4)   = make_ushort4(p1[0],p1[1],p1[2],p1[3]);
  *(ushort4*)(dst + 2*plane + (size_t)i*4) = make_ushort4(p2[0],p2[1],p2[2],p2[3]);
}

// -------- f32 GEMM fallback (round-3 proven): out = A[M,K] @ W[N,K]^T -----
__global__ __launch_bounds__(256) void gemm_f32_kernel(
    const float* __restrict__ A, const float* __restrict__ W,
    float* __restrict__ out, int M, int N, int K)
{
  __shared__ float As[16][132];
  __shared__ float Bs[16][132];
  const int t  = threadIdx.x;
  const int tx = t & 15, ty = t >> 4;
  const int m0 = blockIdx.x * 128, n0 = blockIdx.y * 128;
  const int lr = t >> 2, lc = (t & 3) << 2;
  float acc[2][2][4][4] = {{{{0.f}}}};
  const float4 z4 = make_float4(0.f,0.f,0.f,0.f);
  const int rowA0 = m0 + lr, rowA1 = m0 + 64 + lr;
  const size_t strA0 = (size_t)rowA0 * K, strA1 = (size_t)rowA1 * K;
  const size_t strW0 = (size_t)(n0+lr) * K, strW1 = (size_t)(n0+64+lr) * K;
  for (int k0=0; k0<K; k0+=16){
    float4 a0 = (rowA0 < M) ? *(const float4*)(A + strA0 + k0 + lc) : z4;
    float4 a1 = (rowA1 < M) ? *(const float4*)(A + strA1 + k0 + lc) : z4;
    float4 w0 = *(const float4*)(W + strW0 + k0 + lc);
    float4 w1 = *(const float4*)(W + strW1 + k0 + lc);
    __syncthreads();
    As[lc+0][lr]=a0.x; As[lc+1][lr]=a0.y; As[lc+2][lr]=a0.z; As[lc+3][lr]=a0.w;
    As[lc+0][64+lr]=a1.x; As[lc+1][64+lr]=a1.y; As[lc+2][64+lr]=a1.z; As[lc+3][64+lr]=a1.w;
    Bs[lc+0][lr]=w0.x; Bs[lc+1][lr]=w0.y; Bs[lc+2][lr]=w0.z; Bs[lc+3][lr]=w0.w;
    Bs[lc+0][64+lr]=w1.x; Bs[lc+1][64+lr]=w1.y; Bs[lc+2][64+lr]=w1.z; Bs[lc+3][64+lr]=w1.w;
    __syncthreads();
    #pragma unroll
    for (int k=0;k<16;k++){
      const float4 av0 = *(const float4*)&As[k][ty*4];
      const float4 av1 = *(const float4*)&As[k][64+ty*4];
      const float4 bv0 = *(const float4*)&Bs[k][tx*4];
      const float4 bv1 = *(const float4*)&Bs[k][64+tx*4];
      const float ar[2][4] = {{av0.x,av0.y,av0.z,av0.w},{av1.x,av1.y,av1.z,av1.w}};
      const float br[2][4] = {{bv0.x,bv0.y,bv0.z,bv0.w},{bv1.x,bv1.y,bv1.z,bv1.w}};
      #pragma unroll
      for (int ri=0;ri<2;ri++)
        #pragma unroll
        for (int i=0;i<4;i++)
          #pragma unroll
          for (int ci=0;ci<2;ci++)
            #pragma unroll
            for (int j=0;j<4;j++)
              acc[ri][ci][i][j] = fmaf(ar[ri][i], br[ci][j], acc[ri][ci][i][j]);
    }
  }
  #pragma unroll
  for (int ri=0;ri<2;ri++){
    #pragma unroll
    for (int i=0;i<4;i++){
      const int row = m0 + ri*64 + ty*4 + i;
      if (row >= M) continue;
      #pragma unroll
      for (int ci=0;ci<2;ci++){
        const int col = n0 + ci*64 + tx*4;
        *(float4*)(out + (size_t)row*N + col) =
          make_float4(acc[ri][ci][i][0],acc[ri][ci][i][1],acc[ri][ci][i][2],acc[ri][ci][i][3]);
      }
    }
  }
}

// ==== 6-term qkv GEMM v5: M64 x N256, 8 waves (2Mx4N), 56 KB LDS ==========
__global__ __launch_bounds__(512) void mfma_gemm6w_kernel(
    const unsigned short* __restrict__ A3, const unsigned short* __restrict__ W3,
    float* __restrict__ out, int M, int N, int K, size_t planeA, size_t planeW,
    int gx)
{
  __shared__ __align__(16) unsigned short As[3][64*64];   // 24 KB
  __shared__ __align__(16) unsigned short Ws[256*64];     // 32 KB
  const int nwg = gridDim.x;
  const int q8 = nwg >> 3, r8 = nwg & 7;
  const int xcd = blockIdx.x & 7, lid = blockIdx.x >> 3;
  const int swz = (xcd < r8) ? (xcd*(q8+1) + lid) : (r8*(q8+1) + (xcd-r8)*q8 + lid);
  const int bx = swz % gx, by = swz / gx;

  const int t = threadIdx.x;
  const int w = t >> 6, lane = t & 63;
  const int m0 = bx * 64, n0 = by * 256;
  const int wr = w >> 2, wc = w & 3;
  f32x4 acc[2][4];
  #pragma unroll
  for (int i=0;i<2;i++)
    #pragma unroll
    for (int j=0;j<4;j++){ acc[i][j][0]=0.f; acc[i][j][1]=0.f; acc[i][j][2]=0.f; acc[i][j][3]=0.f; }

  const int srow = lane >> 3;
  const int slot = lane & 7;
  const int scol = (slot ^ srow) * 8;
  const int aloc = w*8;
  const int wloc = w*32;
  const int fr = lane & 15;
  const int kg = lane >> 4;

  #define SEGW(NA)                                                            \
    _Pragma("unroll")                                                         \
    for (int ksub = 0; ksub < 2; ksub++){                                     \
      const int kbyte = ksub*64 + kg*16;                                      \
      bf16x8 b[4];                                                            \
      _Pragma("unroll")                                                       \
      for (int ni=0; ni<4; ni++){                                             \
        const int br = wc*64 + ni*16 + fr;                                    \
        b[ni] = *(const bf16x8*)(Ws + br*64 + ((kbyte ^ ((br&7)<<4)) >> 1));  \
      }                                                                       \
      _Pragma("unroll")                                                       \
      for (int p=0; p<NA; p++){                                               \
        bf16x8 a[2];                                                          \
        _Pragma("unroll")                                                     \
        for (int mi=0; mi<2; mi++){                                           \
          const int ar = wr*32 + mi*16 + fr;                                  \
          a[mi] = *(const bf16x8*)(As[p] + ar*64 + ((kbyte ^ ((ar&7)<<4)) >> 1)); \
        }                                                                     \
        _Pragma("unroll")                                                     \
        for (int mi=0; mi<2; mi++)                                            \
          _Pragma("unroll")                                                   \
          for (int ni=0; ni<4; ni++)                                          \
            acc[mi][ni] = __builtin_amdgcn_mfma_f32_16x16x32_bf16(a[mi], b[ni], acc[mi][ni], 0, 0, 0); \
      }                                                                       \
    }

  #define STAGE_W(P)                                                          \
    _Pragma("unroll")                                                         \
    for (int tt=0; tt<4; tt++){                                               \
      const int rl = wloc + tt*8;                                             \
      GLDS(W3 + (size_t)(P)*planeW + (size_t)(n0+rl+srow)*K + k0 + scol, Ws + rl*64); \
    }

  for (int k0 = 0; k0 < K; k0 += 64){
    __syncthreads();
    #pragma unroll
    for (int p=0; p<3; p++)
      GLDS(A3 + (size_t)p*planeA + (size_t)(m0+aloc+srow)*K + k0 + scol, As[p] + aloc*64);
    STAGE_W(0)
    __syncthreads();
    SEGW(3)
    __syncthreads();
    STAGE_W(1)
    __syncthreads();
    SEGW(2)
    __syncthreads();
    STAGE_W(2)
    __syncthreads();
    SEGW(1)
  }
  #undef SEGW
  #undef STAGE_W

  const int cL = lane & 15, rL = lane >> 4;
  #pragma unroll
  for (int mi=0; mi<2; mi++){
    #pragma unroll
    for (int ni=0; ni<4; ni++){
      const int col = n0 + wc*64 + ni*16 + cL;
      const int rowb = m0 + wr*32 + mi*16 + rL*4;
      #pragma unroll
      for (int r=0; r<4; r++){
        const int row = rowb + r;
        if (row >= M) continue;
        out[(size_t)row*N + col] = acc[mi][ni][r];
      }
    }
  }
}

// ==== plain bf16 GEMM v5: M64 x N256, 8 waves, 40 KB LDS (4 blocks/CU) ====
template<int EPI>
__global__ __launch_bounds__(512) void mfma_gemm1w_kernel(
    const unsigned short* __restrict__ A, const unsigned short* __restrict__ W,
    const float* __restrict__ bias, const float* __restrict__ gamma,
    const float* __restrict__ resid, void* __restrict__ outv,
    int M, int N, int K, int gx)
{
  __shared__ __align__(16) unsigned short As[64*64];      // 8 KB
  __shared__ __align__(16) unsigned short Ws[256*64];     // 32 KB
  const int nwg = gridDim.x;
  const int q8 = nwg >> 3, r8 = nwg & 7;
  const int xcd = blockIdx.x & 7, lid = blockIdx.x >> 3;
  const int swz = (xcd < r8) ? (xcd*(q8+1) + lid) : (r8*(q8+1) + (xcd-r8)*q8 + lid);
  const int bx = swz % gx, by = swz / gx;

  const int t = threadIdx.x;
  const int w = t >> 6, lane = t & 63;
  const int m0 = bx * 64, n0 = by * 256;
  const int wr = w >> 2, wc = w & 3;
  f32x4 acc[2][4];
  #pragma unroll
  for (int i=0;i<2;i++)
    #pragma unroll
    for (int j=0;j<4;j++){ acc[i][j][0]=0.f; acc[i][j][1]=0.f; acc[i][j][2]=0.f; acc[i][j][3]=0.f; }

  const int srow = lane >> 3;
  const int slot = lane & 7;
  const int scol = (slot ^ srow) * 8;
  const int aloc = w*8;
  const int wloc = w*32;
  const int fr = lane & 15;
  const int kg = lane >> 4;

  for (int k0 = 0; k0 < K; k0 += 64){
    __syncthreads();
    GLDS(A + (size_t)(m0+aloc+srow)*K + k0 + scol, As + aloc*64);
    #pragma unroll
    for (int tt=0; tt<4; tt++){
      const int rl = wloc + tt*8;
      GLDS(W + (size_t)(n0+rl+srow)*K + k0 + scol, Ws + rl*64);
    }
    __syncthreads();
    #pragma unroll
    for (int ksub = 0; ksub < 2; ksub++){
      const int kbyte = ksub*64 + kg*16;
      bf16x8 b[4];
      #pragma unroll
      for (int ni=0; ni<4; ni++){
        const int br = wc*64 + ni*16 + fr;
        b[ni] = *(const bf16x8*)(Ws + br*64 + ((kbyte ^ ((br&7)<<4)) >> 1));
      }
      bf16x8 a[2];
      #pragma unroll
      for (int mi=0; mi<2; mi++){
        const int ar = wr*32 + mi*16 + fr;
        a[mi] = *(const bf16x8*)(As + ar*64 + ((kbyte ^ ((ar&7)<<4)) >> 1));
      }
      #pragma unroll
      for (int mi=0; mi<2; mi++)
        #pragma unroll
        for (int ni=0; ni<4; ni++)
          acc[mi][ni] = __builtin_amdgcn_mfma_f32_16x16x32_bf16(a[mi], b[ni], acc[mi][ni], 0, 0, 0);
    }
  }

  const int cL = lane & 15, rL = lane >> 4;
  #pragma unroll
  for (int mi=0; mi<2; mi++){
    #pragma unroll
    for (int ni=0; ni<4; ni++){
      const int col = n0 + wc*64 + ni*16 + cL;
      const int rowb = m0 + wr*32 + mi*16 + rL*4;
      const float bb = bias[col];
      #pragma unroll
      for (int r=0; r<4; r++){
        const int row = rowb + r;
        if (row >= M) continue;
        float v = acc[mi][ni][r] + bb;
        if (EPI == 2){
          v = 0.5f*v*(1.0f + erff(v*0.7071067811865475f));
          ((unsigned short*)outv)[(size_t)row*N + col] = f2bf(v);
        } else {
          v = gamma[col]*v + resid[(size_t)row*N + col];
          ((float*)outv)[(size_t)row*N + col] = v;
        }
      }
    }
  }
}

// ==== proj v2: 3-term split, M64 x N256, 8 waves, 48 KB LDS (3 blocks/CU) ==
__global__ __launch_bounds__(512) void mfma_proj3_kernel(
    const unsigned short* __restrict__ A, const unsigned short* __restrict__ W,
    const float* __restrict__ bias, const float* __restrict__ gamma,
    const float* __restrict__ resid, float* __restrict__ out,
    int M, int N, int K, int gx)
{
  __shared__ __align__(16) unsigned short Ah[64*64], Al[64*64];  // 16 KB
  __shared__ __align__(16) unsigned short Ws[256*64];            // 32 KB
  const int nwg = gridDim.x;
  const int q8 = nwg >> 3, r8 = nwg & 7;
  const int xcd = blockIdx.x & 7, lid = blockIdx.x >> 3;
  const int swz = (xcd < r8) ? (xcd*(q8+1) + lid) : (r8*(q8+1) + (xcd-r8)*q8 + lid);
  const int bx = swz % gx, by = swz / gx;

  const int t = threadIdx.x;
  const int w = t >> 6, lane = t & 63;
  const int m0 = bx * 64, n0 = by * 256;
  const int wr = w >> 2, wc = w & 3;
  const int lda = 2*K;
  f32x4 acc[2][4];
  #pragma unroll
  for (int i=0;i<2;i++)
    #pragma unroll
    for (int j=0;j<4;j++){ acc[i][j][0]=0.f; acc[i][j][1]=0.f; acc[i][j][2]=0.f; acc[i][j][3]=0.f; }

  const int srow = lane >> 3;
  const int slot = lane & 7;
  const int scol = (slot ^ srow) * 8;
  const int aloc = w*8;
  const int wloc = w*32;
  const int fr = lane & 15;
  const int kg = lane >> 4;

  #define PSEG(NA)                                                            \
    _Pragma("unroll")                                                         \
    for (int ksub = 0; ksub < 2; ksub++){                                     \
      const int kbyte = ksub*64 + kg*16;                                      \
      bf16x8 b[4];                                                            \
      _Pragma("unroll")                                                       \
      for (int ni=0; ni<4; ni++){                                             \
        const int br = wc*64 + ni*16 + fr;                                    \
        b[ni] = *(const bf16x8*)(Ws + br*64 + ((kbyte ^ ((br&7)<<4)) >> 1));  \
      }                                                                       \
      _Pragma("unroll")                                                       \
      for (int mi=0; mi<2; mi++){                                             \
        const int ar = wr*32 + mi*16 + fr;                                    \
        const int ao = ar*64 + ((kbyte ^ ((ar&7)<<4)) >> 1);                  \
        bf16x8 ah = *(const bf16x8*)(Ah + ao);                                \
        _Pragma("unroll")                                                     \
        for (int ni=0; ni<4; ni++)                                            \
          acc[mi][ni] = __builtin_amdgcn_mfma_f32_16x16x32_bf16(ah, b[ni], acc[mi][ni], 0, 0, 0); \
        if (NA > 1){                                                          \
          bf16x8 al = *(const bf16x8*)(Al + ao);                              \
          _Pragma("unroll")                                                   \
          for (int ni=0; ni<4; ni++)                                          \
            acc[mi][ni] = __builtin_amdgcn_mfma_f32_16x16x32_bf16(al, b[ni], acc[mi][ni], 0, 0, 0); \
        }                                                                     \
      }                                                                       \
    }

  for (int k0 = 0; k0 < K; k0 += 64){
    __syncthreads();
    {
      const size_t abase = (size_t)(m0+aloc+srow)*lda + k0 + scol;
      GLDS(A + abase,     Ah + aloc*64);
      GLDS(A + abase + K, Al + aloc*64);
    }
    #pragma unroll
    for (int tt=0; tt<4; tt++){
      const int rl = wloc + tt*8;
      GLDS(W + (size_t)(n0+rl+srow)*lda + k0 + scol, Ws + rl*64);
    }
    __syncthreads();
    PSEG(2)
    __syncthreads();
    #pragma unroll
    for (int tt=0; tt<4; tt++){
      const int rl = wloc + tt*8;
      GLDS(W + (size_t)(n0+rl+srow)*lda + K + k0 + scol, Ws + rl*64);
    }
    __syncthreads();
    PSEG(1)
  }
  #undef PSEG

  const int cL = lane & 15, rL = lane >> 4;
  #pragma unroll
  for (int mi=0; mi<2; mi++){
    #pragma unroll
    for (int ni=0; ni<4; ni++){
      const int col = n0 + wc*64 + ni*16 + cL;
      const int rowb = m0 + wr*32 + mi*16 + rL*4;
      const float bb = bias[col];
      const float gg = gamma[col];
      #pragma unroll
      for (int r=0; r<4; r++){
        const int row = rowb + r;
        if (row >= M) continue;
        out[(size_t)row*N + col] = gg*(acc[mi][ni][r] + bb) + resid[(size_t)row*N + col];
      }
    }
  }
}

// ---- flash attention: one pass, K in LDS (51 KB), V broadcast from global --
// l/m computed with the SAME expression as before -> mbuf/lbuf bit-identical.
__global__ __launch_bounds__(256) void attn_flash_kernel(
    const float* __restrict__ qkv, double* __restrict__ mbuf,
    double* __restrict__ lbuf, unsigned short* __restrict__ msa3)
{
  __shared__ float Kt[NTOK][HD];      // 50,432 B
  __shared__ double q0s[HD];
  __shared__ float m0sh;
  __shared__ double red[4];
  __shared__ float l0f;
  const int bh = blockIdx.x;
  const int b = bh / NHEAD, h = bh % NHEAD;
  const float* basep = qkv + (size_t)b*NTOK*2304 + h*HD;
  for (int li=threadIdx.x; li<NTOK*16; li+=256){
    const int r = li >> 4, c4 = (li & 15) << 2;
    *(float4*)&Kt[r][c4] = *(const float4*)(basep + (size_t)r*2304 + 768 + c4);
  }
  if (threadIdx.x < 16){
    const float4 t4 = *(const float4*)(basep + threadIdx.x*4);
    q0s[threadIdx.x*4+0] = (double)t4.x*0.125; q0s[threadIdx.x*4+1] = (double)t4.y*0.125;
    q0s[threadIdx.x*4+2] = (double)t4.z*0.125; q0s[threadIdx.x*4+3] = (double)t4.w*0.125;
  }
  __syncthreads();
  const int i = threadIdx.x;
  float4 q[16];
  float4 o[16];
  float m = -INFINITY, l = 0.f;
  if (i < NTOK){
    #pragma unroll
    for (int dd=0; dd<16; dd++){
      float4 tq = *(const float4*)(basep + (size_t)i*2304 + dd*4);
      q[dd] = make_float4(tq.x*0.125f, tq.y*0.125f, tq.z*0.125f, tq.w*0.125f);
      o[dd] = make_float4(0.f,0.f,0.f,0.f);
    }
    for (int j=0;j<NTOK;j++){
      float s = 0.f;
      #pragma unroll
      for (int dd=0;dd<16;dd++){
        const float4 kk = *(const float4*)&Kt[j][dd*4];
        s = fmaf(q[dd].x,kk.x,s); s = fmaf(q[dd].y,kk.y,s);
        s = fmaf(q[dd].z,kk.z,s); s = fmaf(q[dd].w,kk.w,s);
      }
      const float mn = fmaxf(m, s);
      const float sc = expf(m - mn);     // 1.0f when max unchanged
      const float p  = expf(s - mn);
      l = l*sc + p;                      // same expression as original stats
      if (sc != 1.0f){
        #pragma unroll
        for (int dd=0;dd<16;dd++){
          o[dd].x *= sc; o[dd].y *= sc; o[dd].z *= sc; o[dd].w *= sc;
        }
      }
      m = mn;
      const float* vrow = basep + (size_t)j*2304 + 1536;  // uniform addr: broadcast
      #pragma unroll
      for (int dd=0;dd<16;dd++){
        const float4 vv = *(const float4*)(vrow + dd*4);
        o[dd].x = fmaf(p,vv.x,o[dd].x); o[dd].y = fmaf(p,vv.y,o[dd].y);
        o[dd].z = fmaf(p,vv.z,o[dd].z); o[dd].w = fmaf(p,vv.w,o[dd].w);
      }
    }
    mbuf[bh*NTOK+i] = (double)m;
    if (i > 0) lbuf[bh*NTOK+i] = (double)(1.0f/l);
    if (i == 0) m0sh = m;
  }
  __syncthreads();
  // exact f64 row-0 normalizer (Kt still resident)
  double e = 0.0;
  if (i < NTOK){
    double s64 = 0.0;
    #pragma unroll
    for (int d=0; d<HD; d++) s64 = fma(q0s[d], (double)Kt[i][d], s64);
    e = exp(s64 - (double)m0sh);
  }
  #pragma unroll
  for (int o2=32;o2>0;o2>>=1) e += __shfl_down(e,o2);
  if ((i&63)==0) red[i>>6] = e;
  __syncthreads();
  if (i==0){
    const double l0 = 1.0/(red[0]+red[1]+red[2]+red[3]);
    lbuf[bh*NTOK] = l0;
    l0f = (float)l0;
  }
  __syncthreads();
  if (i >= NTOK) return;
  const float linv = (i == 0) ? l0f : (1.0f/l);
  unsigned short* orow = msa3 + ((size_t)b*NTOK + i)*1536 + h*HD;
  #pragma unroll
  for (int dd=0;dd<16;dd++){
    const float4 v = make_float4(o[dd].x*linv, o[dd].y*linv, o[dd].z*linv, o[dd].w*linv);
    ushort4 hi, lo;
    hi.x = f2bf(v.x); lo.x = f2bf(v.x - bf2f(hi.x));
    hi.y = f2bf(v.y); lo.y = f2bf(v.y - bf2f(hi.y));
    hi.z = f2bf(v.z); lo.z = f2bf(v.z - bf2f(hi.z));
    hi.w = f2bf(v.w); lo.w = f2bf(v.w - bf2f(hi.w));
    *(ushort4*)(orow + dd*4)       = hi;
    *(ushort4*)(orow + 768 + dd*4) = lo;
  }
}

// ---- selector stats: Q in LDS, f32 colsum (i>=1), f64 row0 ---------------
__global__ __launch_bounds__(256) void attn_sel_kernel(
    const float* __restrict__ qkv, const double* __restrict__ mbuf,
    const double* __restrict__ lbuf, double* __restrict__ ta_part)
{
  __shared__ float Qt[NTOK][HD];
  __shared__ double q0s[HD];
  __shared__ float msf[NTOK], lsf[NTOK];
  __shared__ double m0d, l0inv;
  __shared__ double sh_cs0, sh_r00;
  const int bh = blockIdx.x;
  const int b = bh / NHEAD, h = bh % NHEAD;
  const float* basep = qkv + (size_t)b*NTOK*2304 + h*HD;
  for (int li=threadIdx.x; li<NTOK*16; li+=256){
    const int r = li >> 4, c4 = (li & 15) << 2;
    float4 tq = *(const float4*)(basep + (size_t)r*2304 + c4);
    Qt[r][c4+0]=tq.x*0.125f; Qt[r][c4+1]=tq.y*0.125f;
    Qt[r][c4+2]=tq.z*0.125f; Qt[r][c4+3]=tq.w*0.125f;
  }
  if (threadIdx.x < 16){
    const float4 t4 = *(const float4*)(basep + threadIdx.x*4);
    q0s[threadIdx.x*4+0] = (double)t4.x*0.125; q0s[threadIdx.x*4+1] = (double)t4.y*0.125;
    q0s[threadIdx.x*4+2] = (double)t4.z*0.125; q0s[threadIdx.x*4+3] = (double)t4.w*0.125;
  }
  for (int li=threadIdx.x; li<NTOK; li+=256){
    msf[li] = (float)mbuf[bh*NTOK+li];
    lsf[li] = (float)lbuf[bh*NTOK+li];
  }
  if (threadIdx.x == 0){ m0d = mbuf[bh*NTOK]; l0inv = lbuf[bh*NTOK]; }
  __syncthreads();
  const int j = threadIdx.x;
  double colsum = 0.0, row0 = 0.0;
  if (j < NTOK){
    float4 kreg[16];
    #pragma unroll
    for (int dd=0;dd<16;dd++) kreg[dd] = *(const float4*)(basep + (size_t)j*2304 + 768 + dd*4);
    {
      double s64 = 0.0;
      #pragma unroll
      for (int dd=0;dd<16;dd++){
        s64 = fma(q0s[dd*4+0], (double)kreg[dd].x, s64);
        s64 = fma(q0s[dd*4+1], (double)kreg[dd].y, s64);
        s64 = fma(q0s[dd*4+2], (double)kreg[dd].z, s64);
        s64 = fma(q0s[dd*4+3], (double)kreg[dd].w, s64);
      }
      row0 = exp(s64 - m0d) * l0inv;
    }
    for (int i2=1;i2<NTOK;i2++){
      float s = 0.f;
      #pragma unroll
      for (int dd=0;dd<16;dd++){
        const float4 qq = *(const float4*)&Qt[i2][dd*4];
        s = fmaf(qq.x,kreg[dd].x,s); s = fmaf(qq.y,kreg[dd].y,s);
        s = fmaf(qq.z,kreg[dd].z,s); s = fmaf(qq.w,kreg[dd].w,s);
      }
      colsum += (double)(expf(s - msf[i2]) * lsf[i2]);
    }
  }
  if (j == 0){ sh_cs0 = colsum; sh_r00 = row0; }
  __syncthreads();
  if (j >= 1 && j < NTOK){
    ta_part[(size_t)bh*NIMG + (j-1)] = row0 * (sh_cs0 / 196.0) + (colsum / 196.0) * sh_r00;
  }
}

// -------- deterministic reduce over heads: token_attn[b,j] (f64) ---------
__global__ __launch_bounds__(256) void reduce_ta_kernel(
    const double* __restrict__ ta_part, double* __restrict__ token_attn)
{
  const int b = blockIdx.x, j = threadIdx.x;
  if (j < NIMG){
    double s = 0.0;
    for (int h=0; h<NHEAD; h++) s += ta_part[((size_t)b*NHEAD + h)*NIMG + j];
    token_attn[b*NIMG + j] = s / 12.0;
  }
}

// -------- circulant coefficients, parallel: one block per d ---------------
__global__ __launch_bounds__(256) void circ_kernel(float* __restrict__ circ)
{
  const int d = blockIdx.x;
  const int g = threadIdx.x;
  __shared__ double rs[4], is[4];
  double re = 0.0, im = 0.0;
  if (g < NIMG){
    const double d0   = (196.0 * 0.15 / 2.0);
    const double twod = 2.0 * d0 * d0;
    const double gg = (double)g - 97.5;
    const double kg = 1.0 - exp(-(gg*gg)/twod);
    const int gd = (g*d) % NIMG;
    const double ang = 6.283185307179586476925286766559 * ((double)gd / 196.0);
    re = kg * cos(ang);
    im = kg * sin(ang);
  }
  #pragma unroll
  for (int o=32;o>0;o>>=1){ re += __shfl_down(re,o); im += __shfl_down(im,o); }
  if ((g&63)==0){ rs[g>>6] = re; is[g>>6] = im; }
  __syncthreads();
  if (g == 0){
    circ[d]        = (float)((rs[0]+rs[1]+rs[2]+rs[3]) / 196.0);
    circ[NIMG + d] = (float)((is[0]+is[1]+is[2]+is[3]) / 196.0);
  }
}

// -------- low-frequency-energy: f32 conv, f64 accumulation ----------------
__global__ __launch_bounds__(256) void lfe_kernel(
    const float* __restrict__ x1, const float* __restrict__ circ,
    double* __restrict__ lfe_part, double* __restrict__ den_part)
{
  __shared__ float xs[NIMG][36];
  __shared__ float2 c2[NIMG];
  __shared__ double red[4];
  const int cg = blockIdx.x, b = blockIdx.y;
  const int c0 = cg * 32;
  for (int li=threadIdx.x; li<NIMG*32; li+=256){
    const int m = li >> 5, ch = li & 31;
    xs[m][ch] = x1[((size_t)b*NTOK + 1 + m)*CDIM + c0 + ch];
  }
  for (int li=threadIdx.x; li<NIMG; li+=256) c2[li] = make_float2(circ[li], circ[NIMG+li]);
  __syncthreads();
  const int n = threadIdx.x;
  double lfe_sum = 0.0, den_sum = 0.0;
  if (n < NIMG){
    #pragma unroll 1
    for (int g=0; g<4; g++){
      const int cc0 = g*8;
      float re[8] = {0,0,0,0,0,0,0,0};
      float im[8] = {0,0,0,0,0,0,0,0};
      int d = n;
      for (int mm=0; mm<NIMG; mm++){
        const float2 cc = c2[d];
        const float4 xa = *(const float4*)&xs[mm][cc0];
        const float4 xb = *(const float4*)&xs[mm][cc0+4];
        const float xv[8] = {xa.x,xa.y,xa.z,xa.w,xb.x,xb.y,xb.z,xb.w};
        #pragma unroll
        for (int q=0;q<8;q++){
          re[q] = fmaf(cc.x, xv[q], re[q]);
          im[q] = fmaf(cc.y, xv[q], im[q]);
        }
        d = (d==0) ? (NIMG-1) : (d-1);
      }
      #pragma unroll
      for (int q=0;q<8;q++) lfe_sum += (double)sqrtf(re[q]*re[q] + im[q]*im[q]);
    }
    #pragma unroll
    for (int q=0;q<8;q++){
      const float4 xv = *(const float4*)&xs[n][q*4];
      den_sum += (double)fabsf(xv.x)+(double)fabsf(xv.y)+(double)fabsf(xv.z)+(double)fabsf(xv.w);
    }
    lfe_part[((size_t)b*24 + cg)*NIMG + n] = lfe_sum;
  }
  double s = (n < NIMG) ? den_sum : 0.0;
  #pragma unroll
  for (int o=32;o>0;o>>=1) s += __shfl_down(s,o);
  if ((threadIdx.x & 63) == 0) red[threadIdx.x >> 6] = s;
  __syncthreads();
  if (threadIdx.x == 0) den_part[b*24 + cg] = red[0]+red[1]+red[2]+red[3];
}

// -------- scores[b,n] = (lfe_num / (den/196)) * token_attn (f64) ----------
__global__ __launch_bounds__(256) void scores_kernel(
    const double* __restrict__ lfe_part, const double* __restrict__ den_part,
    const double* __restrict__ token_attn, double* __restrict__ scores)
{
  const int b = blockIdx.x, n = threadIdx.x;
  if (n < NIMG){
    double num = 0.0;
    for (int cg=0; cg<24; cg++) num += lfe_part[((size_t)b*24 + cg)*NIMG + n];
    double den = 0.0;
    for (int cg=0; cg<24; cg++) den += den_part[b*24 + cg];
    const double tl = num / (den / 196.0);
    scores[b*NIMG + n] = tl * token_attn[b*NIMG + n];
  }
}

// -------- top-118, descending, stable (ties -> lower index); 1 wave -------
__global__ void topk_kernel(const double* __restrict__ scores, int* __restrict__ idx)
{
  __shared__ double w[NIMG];
  const int b = blockIdx.x, lane = threadIdx.x;   // blockDim = 64
  for (int i=lane; i<NIMG; i+=64) w[i] = scores[b*NIMG + i];
  __syncthreads();
  for (int r=0; r<NSEL; r++){
    double bv = -INFINITY; int bi = NIMG;
    for (int i=lane; i<NIMG; i+=64){
      const double v = w[i];
      if (v > bv){ bv = v; bi = i; }
    }
    #pragma unroll
    for (int o=32;o>0;o>>=1){
      const double ov = __shfl_down(bv,o);
      const int    oi = __shfl_down(bi,o);
      if (ov > bv || (ov == bv && oi < bi)){ bv = ov; bi = oi; }
    }
    if (lane == 0){
      idx[b*NSEL + r] = bi;
      w[bi] = -INFINITY;
    }
    __syncthreads();
  }
}

// -------- gather selected tokens -----------------------------------------
__global__ void gather_kernel(const float* __restrict__ x1, const int* __restrict__ idx,
                              float* __restrict__ xsel)
{
  const int row = blockIdx.x;
  const int b = row / (NSEL+1), r = row % (NSEL+1);
  const int src = (r == 0) ? 0 : (1 + idx[b*NSEL + (r-1)]);
  const float4* s = (const float4*)(x1 + ((size_t)b*NTOK + src)*CDIM);
  float4* d = (float4*)(xsel + (size_t)row*CDIM);
  d[threadIdx.x] = s[threadIdx.x];
}

// ===========================================================================
extern "C" void kernel_launch(void* const* d_in, const int* in_sizes, int n_in,
                              void* d_out, int out_size, void* d_ws, size_t ws_size,
                              hipStream_t stream)
{
  const float* x      = (const float*)d_in[0];
  const float* ln1_w  = (const float*)d_in[1];
  const float* ln1_b  = (const float*)d_in[2];
  const float* qkv_w  = (const float*)d_in[3];
  const float* proj_w = (const float*)d_in[4];
  const float* proj_b = (const float*)d_in[5];
  const float* gamma1 = (const float*)d_in[6];
  const float* ln2_w  = (const float*)d_in[7];
  const float* ln2_b  = (const float*)d_in[8];
  const float* fc1_w  = (const float*)d_in[9];
  const float* fc1_b  = (const float*)d_in[10];
  const float* fc2_w  = (const float*)d_in[11];
  const float* fc2_b  = (const float*)d_in[12];
  const float* gamma2 = (const float*)d_in[13];
  float* out = (float*)d_out;
  float* ws  = (float*)d_ws;

  float* R1 = ws;                                   // 9,732,096 f
  float* R2 = ws + 9732096;                         // 29,048,832 f
  double* D = (double*)(ws + 9732096 + 29048832);   // f-off 38,780,928
  double* mbuf = D;                   // 151296
  double* lbuf = mbuf + 151296;       // 151296
  double* tap  = lbuf + 151296;       // 150528
  double* ta   = tap  + 150528;       // 12544
  double* lfep = ta   + 12544;        // 301056
  double* denp = lfep + 301056;       // 1536
  double* sc   = denp + 1536;         // 12544
  float* circ  = (float*)(sc + 12544);        // 392 f
  int*   idxb  = (int*)(circ + 392);          // 7552 i
  unsigned short* W3p = (unsigned short*)(ws + 40350472);   // 768x1536 us
  unsigned short* WQ3 = (unsigned short*)(ws + 40940296);   // 3 x 2304x768 us
  unsigned short* XQ3 = (unsigned short*)(ws + 43594504);   // 3 x 12672x768 us
  const size_t NEED_BYTES = (size_t)58192648 * 4;           // ~233 MB

  float* xln  = R1;
  unsigned short* msa3 = (unsigned short*)R1;
  float* xsel = R1;
  float* qkv  = R2;
  float* x1   = R2;
  unsigned short* ln2o_bf = (unsigned short*)(R2 + 9682944);   // 7680*768
  unsigned short* fc1w_bf = (unsigned short*)(R2 + 12632064);  // 3072*768
  unsigned short* fc2w_bf = (unsigned short*)(R2 + 13811712);  // 768*3072
  unsigned short* h1_bf   = (unsigned short*)(R2 + 14991360);  // 7680*3072

  // 1-2) LN1 + qkv = ln(x) @ qkv_w^T  [12608,2304]
  if (ws_size >= NEED_BYTES){
    ln_split3_kernel<<<ROWS_FULL, 256, 0, stream>>>(x, ln1_w, ln1_b, XQ3, (size_t)9732096);
    cvt_split3_kernel<<<(442368+255)/256, 256, 0, stream>>>(qkv_w, WQ3, 442368, (size_t)1769472);
    mfma_gemm6w_kernel<<<197*9, 512, 0, stream>>>(XQ3, WQ3, qkv, ROWS_FULL, 2304, 768,
                                                  (size_t)9732096, (size_t)1769472, 197);
  } else {
    ln_kernel<0><<<ROWS_FULL, 256, 0, stream>>>(x, ln1_w, ln1_b, xln);
    gemm_f32_kernel<<<dim3(99,18), 256, 0, stream>>>(xln, qkv_w, qkv, ROWS_FULL, 2304, 768);
  }
  // 3-4) flash attention: one-pass stats + PV -> msa hi/lo bf16 (over R1)
  attn_flash_kernel<<<BATCH*NHEAD, 256, 0, stream>>>(qkv, mbuf, lbuf, msa3);
  // 5) selector stats + head reduce
  attn_sel_kernel<<<BATCH*NHEAD, 256, 0, stream>>>(qkv, mbuf, lbuf, tap);
  reduce_ta_kernel<<<BATCH, 256, 0, stream>>>(tap, ta);
  // 6) proj via 3-term split MFMA v2: x1 = gamma1*(msa@proj_w^T + b) + x
  cvt3_kernel<<<CDIM, 192, 0, stream>>>(proj_w, W3p, CDIM);
  mfma_proj3_kernel<<<197*3, 512, 0, stream>>>(msa3, W3p, proj_b, gamma1, x,
                                               x1, ROWS_FULL, CDIM, CDIM, 197);
  // 6b) fc weights -> bf16
  cvt_bf16_kernel<<<2304, 256, 0, stream>>>(fc1_w, fc1w_bf, 589824);
  cvt_bf16_kernel<<<2304, 256, 0, stream>>>(fc2_w, fc2w_bf, 589824);
  // 7) selector scores
  circ_kernel<<<NIMG, 256, 0, stream>>>(circ);
  lfe_kernel<<<dim3(24, BATCH), 256, 0, stream>>>(x1, circ, lfep, denp);
  scores_kernel<<<BATCH, 256, 0, stream>>>(lfep, denp, ta, sc);
  // 8) top-118 + gather (xsel over dead msa3)
  topk_kernel<<<BATCH, 64, 0, stream>>>(sc, idxb);
  gather_kernel<<<ROWS_SEL, 192, 0, stream>>>(x1, idxb, xsel);
  // 9) MLP: LN2 -> bf16, fc1/fc2 via v5-style M64xN256 MFMA
  ln_kernel<1><<<ROWS_SEL, 256, 0, stream>>>(xsel, ln2_w, ln2_b, ln2o_bf);
  mfma_gemm1w_kernel<2><<<119*12, 512, 0, stream>>>(ln2o_bf, fc1w_bf, fc1_b, nullptr,
                                                    nullptr, h1_bf, ROWS_SEL, 3072, 768, 119);
  mfma_gemm1w_kernel<3><<<119*3, 512, 0, stream>>>(h1_bf, fc2w_bf, fc2_b, gamma2,
                                                   xsel, out, ROWS_SEL, 768, 3072, 119);
}

// Round 18
// 1128.098 us; speedup vs baseline: 1.5706x; 1.1225x over previous
//
#include <hip/hip_runtime.h>
#include <math.h>

#define NTOK 197
#define NIMG 196
#define CDIM 768
#define NHEAD 12
#define HD 64
#define BATCH 64
#define NSEL 118
#define ROWS_FULL (BATCH*NTOK)     // 12608
#define ROWS_SEL  (BATCH*(NSEL+1)) // 7616

typedef short bf16x8 __attribute__((ext_vector_type(8)));
typedef float f32x4  __attribute__((ext_vector_type(4)));

#define GLDS(g, l) __builtin_amdgcn_global_load_lds( \
    (const __attribute__((address_space(1))) void*)(g), \
    (__attribute__((address_space(3))) void*)(l), 16, 0, 0)

__device__ __forceinline__ unsigned short f2bf(float f){
  union { float f; unsigned u; } v; v.f = f;
  unsigned r = v.u + 0x7FFF + ((v.u >> 16) & 1);
  return (unsigned short)(r >> 16);
}
__device__ __forceinline__ float bf2f(unsigned short h){
  union { unsigned u; float f; } v; v.u = ((unsigned)h) << 16; return v.f;
}

// ---------------- LayerNorm (one block per row, C=768). OUT: 0=f32 1=bf16 --
template<int OUT>
__global__ __launch_bounds__(256) void ln_kernel(
    const float* __restrict__ x, const float* __restrict__ w,
    const float* __restrict__ b, void* __restrict__ outv)
{
  const int row = blockIdx.x;
  const int t = threadIdx.x;
  const float* xr = x + (size_t)row * CDIM;
  float v0 = xr[t], v1 = xr[t+256], v2 = xr[t+512];
  float s = v0 + v1 + v2;
  __shared__ float red[4], red2[4];
  #pragma unroll
  for (int o=32;o>0;o>>=1) s += __shfl_down(s,o);
  if ((t&63)==0) red[t>>6] = s;
  __syncthreads();
  const float mean = (red[0]+red[1]+red[2]+red[3]) / 768.0f;
  const float d0=v0-mean, d1=v1-mean, d2=v2-mean;
  float vs = d0*d0 + d1*d1 + d2*d2;
  #pragma unroll
  for (int o=32;o>0;o>>=1) vs += __shfl_down(vs,o);
  if ((t&63)==0) red2[t>>6] = vs;
  __syncthreads();
  const float var = (red2[0]+red2[1]+red2[2]+red2[3]) / 768.0f;
  const float rstd = 1.0f / sqrtf(var + 1e-5f);
  const float o0 = d0*rstd*w[t]     + b[t];
  const float o1 = d1*rstd*w[t+256] + b[t+256];
  const float o2 = d2*rstd*w[t+512] + b[t+512];
  if (OUT == 0){
    float* orow = (float*)outv + (size_t)row * CDIM;
    orow[t] = o0; orow[t+256] = o1; orow[t+512] = o2;
  } else {
    unsigned short* orow = (unsigned short*)outv + (size_t)row * CDIM;
    orow[t] = f2bf(o0); orow[t+256] = f2bf(o1); orow[t+512] = f2bf(o2);
  }
}

// -------- LN1 fused with 3-plane bf16 split (big-ws path) -----------------
__global__ __launch_bounds__(256) void ln_split3_kernel(
    const float* __restrict__ x, const float* __restrict__ w,
    const float* __restrict__ b, unsigned short* __restrict__ dst, size_t plane)
{
  const int row = blockIdx.x;
  const int t = threadIdx.x;
  const float* xr = x + (size_t)row * CDIM;
  float v0 = xr[t], v1 = xr[t+256], v2 = xr[t+512];
  float s = v0 + v1 + v2;
  __shared__ float red[4], red2[4];
  #pragma unroll
  for (int o=32;o>0;o>>=1) s += __shfl_down(s,o);
  if ((t&63)==0) red[t>>6] = s;
  __syncthreads();
  const float mean = (red[0]+red[1]+red[2]+red[3]) / 768.0f;
  const float d0=v0-mean, d1=v1-mean, d2=v2-mean;
  float vs = d0*d0 + d1*d1 + d2*d2;
  #pragma unroll
  for (int o=32;o>0;o>>=1) vs += __shfl_down(vs,o);
  if ((t&63)==0) red2[t>>6] = vs;
  __syncthreads();
  const float var = (red2[0]+red2[1]+red2[2]+red2[3]) / 768.0f;
  const float rstd = 1.0f / sqrtf(var + 1e-5f);
  const float ov[3] = { d0*rstd*w[t]     + b[t],
                        d1*rstd*w[t+256] + b[t+256],
                        d2*rstd*w[t+512] + b[t+512] };
  #pragma unroll
  for (int e=0;e<3;e++){
    const int col = t + e*256;
    const float f = ov[e];
    const unsigned short p0 = f2bf(f);
    const float r1 = f - bf2f(p0);
    const unsigned short p1 = f2bf(r1);
    const unsigned short p2 = f2bf(r1 - bf2f(p1));
    dst[(size_t)row*CDIM + col]             = p0;
    dst[plane + (size_t)row*CDIM + col]     = p1;
    dst[2*plane + (size_t)row*CDIM + col]   = p2;
  }
}

// ---------------- f32 -> bf16 conversion (4 elems/thread) ----------------
__global__ __launch_bounds__(256) void cvt_bf16_kernel(
    const float* __restrict__ src, unsigned short* __restrict__ dst, int n4)
{
  const int i = blockIdx.x*256 + threadIdx.x;
  if (i < n4){
    const float4 v = *(const float4*)(src + (size_t)i*4);
    dst[(size_t)i*4+0] = f2bf(v.x); dst[(size_t)i*4+1] = f2bf(v.y);
    dst[(size_t)i*4+2] = f2bf(v.z); dst[(size_t)i*4+3] = f2bf(v.w);
  }
}

// ---------------- f32 -> hi/lo bf16 split, row layout [n][2K] -------------
__global__ __launch_bounds__(192) void cvt3_kernel(
    const float* __restrict__ w, unsigned short* __restrict__ W3, int K)
{
  const int n = blockIdx.x, t = threadIdx.x;
  const float4 v = *(const float4*)(w + (size_t)n*K + t*4);
  ushort4 hi, lo;
  hi.x = f2bf(v.x); lo.x = f2bf(v.x - bf2f(hi.x));
  hi.y = f2bf(v.y); lo.y = f2bf(v.y - bf2f(hi.y));
  hi.z = f2bf(v.z); lo.z = f2bf(v.z - bf2f(hi.z));
  hi.w = f2bf(v.w); lo.w = f2bf(v.w - bf2f(hi.w));
  *(ushort4*)(W3 + (size_t)n*2*K + t*4)     = hi;
  *(ushort4*)(W3 + (size_t)n*2*K + K + t*4) = lo;
}

// ------- f32 -> 3 bf16 planes (a = p0 + p1 + p2, 24 mantissa bits) --------
__global__ __launch_bounds__(256) void cvt_split3_kernel(
    const float* __restrict__ src, unsigned short* __restrict__ dst,
    int n4, size_t plane)
{
  const int i = blockIdx.x*256 + threadIdx.x;
  if (i >= n4) return;
  const float4 v = *(const float4*)(src + (size_t)i*4);
  const float f[4] = {v.x, v.y, v.z, v.w};
  unsigned short p0[4], p1[4], p2[4];
  #pragma unroll
  for (int q=0;q<4;q++){
    p0[q] = f2bf(f[q]);
    const float r1 = f[q] - bf2f(p0[q]);
    p1[q] = f2bf(r1);
    const float r2 = r1 - bf2f(p1[q]);
    p2[q] = f2bf(r2);
  }
  *(ushort4*)(dst + (size_t)i*4)           = make_ushort4(p0[0],p0[1],p0[2],p0[3]);
  *(ushort4*)(dst + plane + (size_t)i*4)   = make_ushort4(p1[0],p1[1],p1[2],p1[3]);
  *(ushort4*)(dst + 2*plane + (size_t)i*4) = make_ushort4(p2[0],p2[1],p2[2],p2[3]);
}

// -------- f32 GEMM fallback (round-3 proven): out = A[M,K] @ W[N,K]^T -----
__global__ __launch_bounds__(256) void gemm_f32_kernel(
    const float* __restrict__ A, const float* __restrict__ W,
    float* __restrict__ out, int M, int N, int K)
{
  __shared__ float As[16][132];
  __shared__ float Bs[16][132];
  const int t  = threadIdx.x;
  const int tx = t & 15, ty = t >> 4;
  const int m0 = blockIdx.x * 128, n0 = blockIdx.y * 128;
  const int lr = t >> 2, lc = (t & 3) << 2;
  float acc[2][2][4][4] = {{{{0.f}}}};
  const float4 z4 = make_float4(0.f,0.f,0.f,0.f);
  const int rowA0 = m0 + lr, rowA1 = m0 + 64 + lr;
  const size_t strA0 = (size_t)rowA0 * K, strA1 = (size_t)rowA1 * K;
  const size_t strW0 = (size_t)(n0+lr) * K, strW1 = (size_t)(n0+64+lr) * K;
  for (int k0=0; k0<K; k0+=16){
    float4 a0 = (rowA0 < M) ? *(const float4*)(A + strA0 + k0 + lc) : z4;
    float4 a1 = (rowA1 < M) ? *(const float4*)(A + strA1 + k0 + lc) : z4;
    float4 w0 = *(const float4*)(W + strW0 + k0 + lc);
    float4 w1 = *(const float4*)(W + strW1 + k0 + lc);
    __syncthreads();
    As[lc+0][lr]=a0.x; As[lc+1][lr]=a0.y; As[lc+2][lr]=a0.z; As[lc+3][lr]=a0.w;
    As[lc+0][64+lr]=a1.x; As[lc+1][64+lr]=a1.y; As[lc+2][64+lr]=a1.z; As[lc+3][64+lr]=a1.w;
    Bs[lc+0][lr]=w0.x; Bs[lc+1][lr]=w0.y; Bs[lc+2][lr]=w0.z; Bs[lc+3][lr]=w0.w;
    Bs[lc+0][64+lr]=w1.x; Bs[lc+1][64+lr]=w1.y; Bs[lc+2][64+lr]=w1.z; Bs[lc+3][64+lr]=w1.w;
    __syncthreads();
    #pragma unroll
    for (int k=0;k<16;k++){
      const float4 av0 = *(const float4*)&As[k][ty*4];
      const float4 av1 = *(const float4*)&As[k][64+ty*4];
      const float4 bv0 = *(const float4*)&Bs[k][tx*4];
      const float4 bv1 = *(const float4*)&Bs[k][64+tx*4];
      const float ar[2][4] = {{av0.x,av0.y,av0.z,av0.w},{av1.x,av1.y,av1.z,av1.w}};
      const float br[2][4] = {{bv0.x,bv0.y,bv0.z,bv0.w},{bv1.x,bv1.y,bv1.z,bv1.w}};
      #pragma unroll
      for (int ri=0;ri<2;ri++)
        #pragma unroll
        for (int i=0;i<4;i++)
          #pragma unroll
          for (int ci=0;ci<2;ci++)
            #pragma unroll
            for (int j=0;j<4;j++)
              acc[ri][ci][i][j] = fmaf(ar[ri][i], br[ci][j], acc[ri][ci][i][j]);
    }
  }
  #pragma unroll
  for (int ri=0;ri<2;ri++){
    #pragma unroll
    for (int i=0;i<4;i++){
      const int row = m0 + ri*64 + ty*4 + i;
      if (row >= M) continue;
      #pragma unroll
      for (int ci=0;ci<2;ci++){
        const int col = n0 + ci*64 + tx*4;
        *(float4*)(out + (size_t)row*N + col) =
          make_float4(acc[ri][ci][i][0],acc[ri][ci][i][1],acc[ri][ci][i][2],acc[ri][ci][i][3]);
      }
    }
  }
}

// ==== 6-term qkv GEMM v5: M64 x N256, 8 waves (2Mx4N), 56 KB LDS ==========
__global__ __launch_bounds__(512) void mfma_gemm6w_kernel(
    const unsigned short* __restrict__ A3, const unsigned short* __restrict__ W3,
    float* __restrict__ out, int M, int N, int K, size_t planeA, size_t planeW,
    int gx)
{
  __shared__ __align__(16) unsigned short As[3][64*64];   // 24 KB
  __shared__ __align__(16) unsigned short Ws[256*64];     // 32 KB
  const int nwg = gridDim.x;
  const int q8 = nwg >> 3, r8 = nwg & 7;
  const int xcd = blockIdx.x & 7, lid = blockIdx.x >> 3;
  const int swz = (xcd < r8) ? (xcd*(q8+1) + lid) : (r8*(q8+1) + (xcd-r8)*q8 + lid);
  const int bx = swz % gx, by = swz / gx;

  const int t = threadIdx.x;
  const int w = t >> 6, lane = t & 63;
  const int m0 = bx * 64, n0 = by * 256;
  const int wr = w >> 2, wc = w & 3;
  f32x4 acc[2][4];
  #pragma unroll
  for (int i=0;i<2;i++)
    #pragma unroll
    for (int j=0;j<4;j++){ acc[i][j][0]=0.f; acc[i][j][1]=0.f; acc[i][j][2]=0.f; acc[i][j][3]=0.f; }

  const int srow = lane >> 3;
  const int slot = lane & 7;
  const int scol = (slot ^ srow) * 8;
  const int aloc = w*8;
  const int wloc = w*32;
  const int fr = lane & 15;
  const int kg = lane >> 4;

  #define SEGW(NA)                                                            \
    _Pragma("unroll")                                                         \
    for (int ksub = 0; ksub < 2; ksub++){                                     \
      const int kbyte = ksub*64 + kg*16;                                      \
      bf16x8 b[4];                                                            \
      _Pragma("unroll")                                                       \
      for (int ni=0; ni<4; ni++){                                             \
        const int br = wc*64 + ni*16 + fr;                                    \
        b[ni] = *(const bf16x8*)(Ws + br*64 + ((kbyte ^ ((br&7)<<4)) >> 1));  \
      }                                                                       \
      _Pragma("unroll")                                                       \
      for (int p=0; p<NA; p++){                                               \
        bf16x8 a[2];                                                          \
        _Pragma("unroll")                                                     \
        for (int mi=0; mi<2; mi++){                                           \
          const int ar = wr*32 + mi*16 + fr;                                  \
          a[mi] = *(const bf16x8*)(As[p] + ar*64 + ((kbyte ^ ((ar&7)<<4)) >> 1)); \
        }                                                                     \
        _Pragma("unroll")                                                     \
        for (int mi=0; mi<2; mi++)                                            \
          _Pragma("unroll")                                                   \
          for (int ni=0; ni<4; ni++)                                          \
            acc[mi][ni] = __builtin_amdgcn_mfma_f32_16x16x32_bf16(a[mi], b[ni], acc[mi][ni], 0, 0, 0); \
      }                                                                       \
    }

  #define STAGE_W(P)                                                          \
    _Pragma("unroll")                                                         \
    for (int tt=0; tt<4; tt++){                                               \
      const int rl = wloc + tt*8;                                             \
      GLDS(W3 + (size_t)(P)*planeW + (size_t)(n0+rl+srow)*K + k0 + scol, Ws + rl*64); \
    }

  for (int k0 = 0; k0 < K; k0 += 64){
    __syncthreads();
    #pragma unroll
    for (int p=0; p<3; p++)
      GLDS(A3 + (size_t)p*planeA + (size_t)(m0+aloc+srow)*K + k0 + scol, As[p] + aloc*64);
    STAGE_W(0)
    __syncthreads();
    SEGW(3)
    __syncthreads();
    STAGE_W(1)
    __syncthreads();
    SEGW(2)
    __syncthreads();
    STAGE_W(2)
    __syncthreads();
    SEGW(1)
  }
  #undef SEGW
  #undef STAGE_W

  const int cL = lane & 15, rL = lane >> 4;
  #pragma unroll
  for (int mi=0; mi<2; mi++){
    #pragma unroll
    for (int ni=0; ni<4; ni++){
      const int col = n0 + wc*64 + ni*16 + cL;
      const int rowb = m0 + wr*32 + mi*16 + rL*4;
      #pragma unroll
      for (int r=0; r<4; r++){
        const int row = rowb + r;
        if (row >= M) continue;
        out[(size_t)row*N + col] = acc[mi][ni][r];
      }
    }
  }
}

// ==== plain bf16 GEMM v5: M64 x N256, 8 waves, 40 KB LDS (4 blocks/CU) ====
template<int EPI>
__global__ __launch_bounds__(512) void mfma_gemm1w_kernel(
    const unsigned short* __restrict__ A, const unsigned short* __restrict__ W,
    const float* __restrict__ bias, const float* __restrict__ gamma,
    const float* __restrict__ resid, void* __restrict__ outv,
    int M, int N, int K, int gx)
{
  __shared__ __align__(16) unsigned short As[64*64];      // 8 KB
  __shared__ __align__(16) unsigned short Ws[256*64];     // 32 KB
  const int nwg = gridDim.x;
  const int q8 = nwg >> 3, r8 = nwg & 7;
  const int xcd = blockIdx.x & 7, lid = blockIdx.x >> 3;
  const int swz = (xcd < r8) ? (xcd*(q8+1) + lid) : (r8*(q8+1) + (xcd-r8)*q8 + lid);
  const int bx = swz % gx, by = swz / gx;

  const int t = threadIdx.x;
  const int w = t >> 6, lane = t & 63;
  const int m0 = bx * 64, n0 = by * 256;
  const int wr = w >> 2, wc = w & 3;
  f32x4 acc[2][4];
  #pragma unroll
  for (int i=0;i<2;i++)
    #pragma unroll
    for (int j=0;j<4;j++){ acc[i][j][0]=0.f; acc[i][j][1]=0.f; acc[i][j][2]=0.f; acc[i][j][3]=0.f; }

  const int srow = lane >> 3;
  const int slot = lane & 7;
  const int scol = (slot ^ srow) * 8;
  const int aloc = w*8;
  const int wloc = w*32;
  const int fr = lane & 15;
  const int kg = lane >> 4;

  for (int k0 = 0; k0 < K; k0 += 64){
    __syncthreads();
    GLDS(A + (size_t)(m0+aloc+srow)*K + k0 + scol, As + aloc*64);
    #pragma unroll
    for (int tt=0; tt<4; tt++){
      const int rl = wloc + tt*8;
      GLDS(W + (size_t)(n0+rl+srow)*K + k0 + scol, Ws + rl*64);
    }
    __syncthreads();
    #pragma unroll
    for (int ksub = 0; ksub < 2; ksub++){
      const int kbyte = ksub*64 + kg*16;
      bf16x8 b[4];
      #pragma unroll
      for (int ni=0; ni<4; ni++){
        const int br = wc*64 + ni*16 + fr;
        b[ni] = *(const bf16x8*)(Ws + br*64 + ((kbyte ^ ((br&7)<<4)) >> 1));
      }
      bf16x8 a[2];
      #pragma unroll
      for (int mi=0; mi<2; mi++){
        const int ar = wr*32 + mi*16 + fr;
        a[mi] = *(const bf16x8*)(As + ar*64 + ((kbyte ^ ((ar&7)<<4)) >> 1));
      }
      #pragma unroll
      for (int mi=0; mi<2; mi++)
        #pragma unroll
        for (int ni=0; ni<4; ni++)
          acc[mi][ni] = __builtin_amdgcn_mfma_f32_16x16x32_bf16(a[mi], b[ni], acc[mi][ni], 0, 0, 0);
    }
  }

  const int cL = lane & 15, rL = lane >> 4;
  #pragma unroll
  for (int mi=0; mi<2; mi++){
    #pragma unroll
    for (int ni=0; ni<4; ni++){
      const int col = n0 + wc*64 + ni*16 + cL;
      const int rowb = m0 + wr*32 + mi*16 + rL*4;
      const float bb = bias[col];
      #pragma unroll
      for (int r=0; r<4; r++){
        const int row = rowb + r;
        if (row >= M) continue;
        float v = acc[mi][ni][r] + bb;
        if (EPI == 2){
          v = 0.5f*v*(1.0f + erff(v*0.7071067811865475f));
          ((unsigned short*)outv)[(size_t)row*N + col] = f2bf(v);
        } else {
          v = gamma[col]*v + resid[(size_t)row*N + col];
          ((float*)outv)[(size_t)row*N + col] = v;
        }
      }
    }
  }
}

// ==== proj v2: 3-term split, M64 x N256, 8 waves, 48 KB LDS (3 blocks/CU) ==
__global__ __launch_bounds__(512) void mfma_proj3_kernel(
    const unsigned short* __restrict__ A, const unsigned short* __restrict__ W,
    const float* __restrict__ bias, const float* __restrict__ gamma,
    const float* __restrict__ resid, float* __restrict__ out,
    int M, int N, int K, int gx)
{
  __shared__ __align__(16) unsigned short Ah[64*64], Al[64*64];  // 16 KB
  __shared__ __align__(16) unsigned short Ws[256*64];            // 32 KB
  const int nwg = gridDim.x;
  const int q8 = nwg >> 3, r8 = nwg & 7;
  const int xcd = blockIdx.x & 7, lid = blockIdx.x >> 3;
  const int swz = (xcd < r8) ? (xcd*(q8+1) + lid) : (r8*(q8+1) + (xcd-r8)*q8 + lid);
  const int bx = swz % gx, by = swz / gx;

  const int t = threadIdx.x;
  const int w = t >> 6, lane = t & 63;
  const int m0 = bx * 64, n0 = by * 256;
  const int wr = w >> 2, wc = w & 3;
  const int lda = 2*K;
  f32x4 acc[2][4];
  #pragma unroll
  for (int i=0;i<2;i++)
    #pragma unroll
    for (int j=0;j<4;j++){ acc[i][j][0]=0.f; acc[i][j][1]=0.f; acc[i][j][2]=0.f; acc[i][j][3]=0.f; }

  const int srow = lane >> 3;
  const int slot = lane & 7;
  const int scol = (slot ^ srow) * 8;
  const int aloc = w*8;
  const int wloc = w*32;
  const int fr = lane & 15;
  const int kg = lane >> 4;

  #define PSEG(NA)                                                            \
    _Pragma("unroll")                                                         \
    for (int ksub = 0; ksub < 2; ksub++){                                     \
      const int kbyte = ksub*64 + kg*16;                                      \
      bf16x8 b[4];                                                            \
      _Pragma("unroll")                                                       \
      for (int ni=0; ni<4; ni++){                                             \
        const int br = wc*64 + ni*16 + fr;                                    \
        b[ni] = *(const bf16x8*)(Ws + br*64 + ((kbyte ^ ((br&7)<<4)) >> 1));  \
      }                                                                       \
      _Pragma("unroll")                                                       \
      for (int mi=0; mi<2; mi++){                                             \
        const int ar = wr*32 + mi*16 + fr;                                    \
        const int ao = ar*64 + ((kbyte ^ ((ar&7)<<4)) >> 1);                  \
        bf16x8 ah = *(const bf16x8*)(Ah + ao);                                \
        _Pragma("unroll")                                                     \
        for (int ni=0; ni<4; ni++)                                            \
          acc[mi][ni] = __builtin_amdgcn_mfma_f32_16x16x32_bf16(ah, b[ni], acc[mi][ni], 0, 0, 0); \
        if (NA > 1){                                                          \
          bf16x8 al = *(const bf16x8*)(Al + ao);                              \
          _Pragma("unroll")                                                   \
          for (int ni=0; ni<4; ni++)                                          \
            acc[mi][ni] = __builtin_amdgcn_mfma_f32_16x16x32_bf16(al, b[ni], acc[mi][ni], 0, 0, 0); \
        }                                                                     \
      }                                                                       \
    }

  for (int k0 = 0; k0 < K; k0 += 64){
    __syncthreads();
    {
      const size_t abase = (size_t)(m0+aloc+srow)*lda + k0 + scol;
      GLDS(A + abase,     Ah + aloc*64);
      GLDS(A + abase + K, Al + aloc*64);
    }
    #pragma unroll
    for (int tt=0; tt<4; tt++){
      const int rl = wloc + tt*8;
      GLDS(W + (size_t)(n0+rl+srow)*lda + k0 + scol, Ws + rl*64);
    }
    __syncthreads();
    PSEG(2)
    __syncthreads();
    #pragma unroll
    for (int tt=0; tt<4; tt++){
      const int rl = wloc + tt*8;
      GLDS(W + (size_t)(n0+rl+srow)*lda + K + k0 + scol, Ws + rl*64);
    }
    __syncthreads();
    PSEG(1)
  }
  #undef PSEG

  const int cL = lane & 15, rL = lane >> 4;
  #pragma unroll
  for (int mi=0; mi<2; mi++){
    #pragma unroll
    for (int ni=0; ni<4; ni++){
      const int col = n0 + wc*64 + ni*16 + cL;
      const int rowb = m0 + wr*32 + mi*16 + rL*4;
      const float bb = bias[col];
      const float gg = gamma[col];
      #pragma unroll
      for (int r=0; r<4; r++){
        const int row = rowb + r;
        if (row >= M) continue;
        out[(size_t)row*N + col] = gg*(acc[mi][ni][r] + bb) + resid[(size_t)row*N + col];
      }
    }
  }
}

// ---- flash attention: one pass, K in LDS (51 KB), V broadcast from global --
__global__ __launch_bounds__(256) void attn_flash_kernel(
    const float* __restrict__ qkv, double* __restrict__ mbuf,
    double* __restrict__ lbuf, unsigned short* __restrict__ msa3)
{
  __shared__ float Kt[NTOK][HD];      // 50,432 B
  __shared__ double q0s[HD];
  __shared__ float m0sh;
  __shared__ double red[4];
  __shared__ float l0f;
  const int bh = blockIdx.x;
  const int b = bh / NHEAD, h = bh % NHEAD;
  const float* basep = qkv + (size_t)b*NTOK*2304 + h*HD;
  for (int li=threadIdx.x; li<NTOK*16; li+=256){
    const int r = li >> 4, c4 = (li & 15) << 2;
    *(float4*)&Kt[r][c4] = *(const float4*)(basep + (size_t)r*2304 + 768 + c4);
  }
  if (threadIdx.x < 16){
    const float4 t4 = *(const float4*)(basep + threadIdx.x*4);
    q0s[threadIdx.x*4+0] = (double)t4.x*0.125; q0s[threadIdx.x*4+1] = (double)t4.y*0.125;
    q0s[threadIdx.x*4+2] = (double)t4.z*0.125; q0s[threadIdx.x*4+3] = (double)t4.w*0.125;
  }
  __syncthreads();
  const int i = threadIdx.x;
  float4 q[16];
  float4 o[16];
  float m = -INFINITY, l = 0.f;
  if (i < NTOK){
    #pragma unroll
    for (int dd=0; dd<16; dd++){
      float4 tq = *(const float4*)(basep + (size_t)i*2304 + dd*4);
      q[dd] = make_float4(tq.x*0.125f, tq.y*0.125f, tq.z*0.125f, tq.w*0.125f);
      o[dd] = make_float4(0.f,0.f,0.f,0.f);
    }
    for (int j=0;j<NTOK;j++){
      float s = 0.f;
      #pragma unroll
      for (int dd=0;dd<16;dd++){
        const float4 kk = *(const float4*)&Kt[j][dd*4];
        s = fmaf(q[dd].x,kk.x,s); s = fmaf(q[dd].y,kk.y,s);
        s = fmaf(q[dd].z,kk.z,s); s = fmaf(q[dd].w,kk.w,s);
      }
      const float mn = fmaxf(m, s);
      const float sc = expf(m - mn);     // 1.0f when max unchanged
      const float p  = expf(s - mn);
      l = l*sc + p;                      // same expression as original stats
      if (sc != 1.0f){
        #pragma unroll
        for (int dd=0;dd<16;dd++){
          o[dd].x *= sc; o[dd].y *= sc; o[dd].z *= sc; o[dd].w *= sc;
        }
      }
      m = mn;
      const float* vrow = basep + (size_t)j*2304 + 1536;  // uniform addr: broadcast
      #pragma unroll
      for (int dd=0;dd<16;dd++){
        const float4 vv = *(const float4*)(vrow + dd*4);
        o[dd].x = fmaf(p,vv.x,o[dd].x); o[dd].y = fmaf(p,vv.y,o[dd].y);
        o[dd].z = fmaf(p,vv.z,o[dd].z); o[dd].w = fmaf(p,vv.w,o[dd].w);
      }
    }
    mbuf[bh*NTOK+i] = (double)m;
    if (i > 0) lbuf[bh*NTOK+i] = (double)(1.0f/l);
    if (i == 0) m0sh = m;
  }
  __syncthreads();
  // exact f64 row-0 normalizer (Kt still resident)
  double e = 0.0;
  if (i < NTOK){
    double s64 = 0.0;
    #pragma unroll
    for (int d=0; d<HD; d++) s64 = fma(q0s[d], (double)Kt[i][d], s64);
    e = exp(s64 - (double)m0sh);
  }
  #pragma unroll
  for (int o2=32;o2>0;o2>>=1) e += __shfl_down(e,o2);
  if ((i&63)==0) red[i>>6] = e;
  __syncthreads();
  if (i==0){
    const double l0 = 1.0/(red[0]+red[1]+red[2]+red[3]);
    lbuf[bh*NTOK] = l0;
    l0f = (float)l0;
  }
  __syncthreads();
  if (i >= NTOK) return;
  const float linv = (i == 0) ? l0f : (1.0f/l);
  unsigned short* orow = msa3 + ((size_t)b*NTOK + i)*1536 + h*HD;
  #pragma unroll
  for (int dd=0;dd<16;dd++){
    const float4 v = make_float4(o[dd].x*linv, o[dd].y*linv, o[dd].z*linv, o[dd].w*linv);
    ushort4 hi, lo;
    hi.x = f2bf(v.x); lo.x = f2bf(v.x - bf2f(hi.x));
    hi.y = f2bf(v.y); lo.y = f2bf(v.y - bf2f(hi.y));
    hi.z = f2bf(v.z); lo.z = f2bf(v.z - bf2f(hi.z));
    hi.w = f2bf(v.w); lo.w = f2bf(v.w - bf2f(hi.w));
    *(ushort4*)(orow + dd*4)       = hi;
    *(ushort4*)(orow + 768 + dd*4) = lo;
  }
}

// ---- selector stats PART: half the i2 range per block (25 KB Qt, 6/CU) ---
// blockIdx = bh*2 + half; half 0 also writes e0_j = exp(f64 q0.k_j - m0).
__global__ __launch_bounds__(256) void attn_selp_kernel(
    const float* __restrict__ qkv, const double* __restrict__ mbuf,
    const double* __restrict__ lbuf, double* __restrict__ csp,
    double* __restrict__ e0buf)
{
  __shared__ float Qt[98][HD];        // 25,088 B
  __shared__ double q0s[HD];
  __shared__ float msf[98], lsf[98];
  const int bh   = blockIdx.x >> 1;
  const int half = blockIdx.x & 1;
  const int i2base = 1 + half*98;     // rows [i2base, i2base+98)
  const int b = bh / NHEAD, h = bh % NHEAD;
  const float* basep = qkv + (size_t)b*NTOK*2304 + h*HD;
  for (int li=threadIdx.x; li<98*16; li+=256){
    const int r = li >> 4, c4 = (li & 15) << 2;
    float4 tq = *(const float4*)(basep + (size_t)(i2base + r)*2304 + c4);
    Qt[r][c4+0]=tq.x*0.125f; Qt[r][c4+1]=tq.y*0.125f;
    Qt[r][c4+2]=tq.z*0.125f; Qt[r][c4+3]=tq.w*0.125f;
  }
  if (half == 0 && threadIdx.x < 16){
    const float4 t4 = *(const float4*)(basep + threadIdx.x*4);
    q0s[threadIdx.x*4+0] = (double)t4.x*0.125; q0s[threadIdx.x*4+1] = (double)t4.y*0.125;
    q0s[threadIdx.x*4+2] = (double)t4.z*0.125; q0s[threadIdx.x*4+3] = (double)t4.w*0.125;
  }
  for (int li=threadIdx.x; li<98; li+=256){
    msf[li] = (float)mbuf[bh*NTOK + i2base + li];
    lsf[li] = (float)lbuf[bh*NTOK + i2base + li];
  }
  __syncthreads();
  const int j = threadIdx.x;
  if (j < NTOK){
    float4 kreg[16];
    #pragma unroll
    for (int dd=0;dd<16;dd++) kreg[dd] = *(const float4*)(basep + (size_t)j*2304 + 768 + dd*4);
    if (half == 0){
      const double m0d = mbuf[bh*NTOK];
      double s64 = 0.0;
      #pragma unroll
      for (int dd=0;dd<16;dd++){
        s64 = fma(q0s[dd*4+0], (double)kreg[dd].x, s64);
        s64 = fma(q0s[dd*4+1], (double)kreg[dd].y, s64);
        s64 = fma(q0s[dd*4+2], (double)kreg[dd].z, s64);
        s64 = fma(q0s[dd*4+3], (double)kreg[dd].w, s64);
      }
      e0buf[(size_t)bh*NTOK + j] = exp(s64 - m0d);
    }
    double colsum = 0.0;
    for (int r=0;r<98;r++){
      float s = 0.f;
      #pragma unroll
      for (int dd=0;dd<16;dd++){
        const float4 qq = *(const float4*)&Qt[r][dd*4];
        s = fmaf(qq.x,kreg[dd].x,s); s = fmaf(qq.y,kreg[dd].y,s);
        s = fmaf(qq.z,kreg[dd].z,s); s = fmaf(qq.w,kreg[dd].w,s);
      }
      colsum += (double)(expf(s - msf[r]) * lsf[r]);
    }
    csp[(size_t)blockIdx.x*NTOK + j] = colsum;
  }
}

// ---- selector stats COMBINE: colsum = part0+part1; l0 reduce; ta_part ----
__global__ __launch_bounds__(256) void attn_selc_kernel(
    const double* __restrict__ csp, const double* __restrict__ e0buf,
    double* __restrict__ ta_part)
{
  __shared__ double red[4];
  __shared__ double sh_cs0, sh_e00, sh_l0inv;
  const int bh = blockIdx.x;
  const int j = threadIdx.x;
  double colsum = 0.0, e0 = 0.0;
  if (j < NTOK){
    colsum = csp[(size_t)(bh*2)*NTOK + j] + csp[(size_t)(bh*2+1)*NTOK + j];
    e0 = e0buf[(size_t)bh*NTOK + j];
  }
  double e = e0;
  #pragma unroll
  for (int o=32;o>0;o>>=1) e += __shfl_down(e,o);
  if ((threadIdx.x&63)==0) red[threadIdx.x>>6] = e;
  __syncthreads();
  if (threadIdx.x == 0){
    sh_l0inv = 1.0/(red[0]+red[1]+red[2]+red[3]);
    sh_cs0 = colsum;        // thread 0 holds colsum at j=0
    sh_e00 = e0;
  }
  __syncthreads();
  if (j >= 1 && j < NTOK){
    const double row0 = e0 * sh_l0inv;
    const double r00  = sh_e00 * sh_l0inv;
    ta_part[(size_t)bh*NIMG + (j-1)] = row0 * (sh_cs0 / 196.0) + (colsum / 196.0) * r00;
  }
}

// -------- deterministic reduce over heads: token_attn[b,j] (f64) ---------
__global__ __launch_bounds__(256) void reduce_ta_kernel(
    const double* __restrict__ ta_part, double* __restrict__ token_attn)
{
  const int b = blockIdx.x, j = threadIdx.x;
  if (j < NIMG){
    double s = 0.0;
    for (int h=0; h<NHEAD; h++) s += ta_part[((size_t)b*NHEAD + h)*NIMG + j];
    token_attn[b*NIMG + j] = s / 12.0;
  }
}

// -------- circulant coefficients, parallel: one block per d ---------------
__global__ __launch_bounds__(256) void circ_kernel(float* __restrict__ circ)
{
  const int d = blockIdx.x;
  const int g = threadIdx.x;
  __shared__ double rs[4], is[4];
  double re = 0.0, im = 0.0;
  if (g < NIMG){
    const double d0   = (196.0 * 0.15 / 2.0);
    const double twod = 2.0 * d0 * d0;
    const double gg = (double)g - 97.5;
    const double kg = 1.0 - exp(-(gg*gg)/twod);
    const int gd = (g*d) % NIMG;
    const double ang = 6.283185307179586476925286766559 * ((double)gd / 196.0);
    re = kg * cos(ang);
    im = kg * sin(ang);
  }
  #pragma unroll
  for (int o=32;o>0;o>>=1){ re += __shfl_down(re,o); im += __shfl_down(im,o); }
  if ((g&63)==0){ rs[g>>6] = re; is[g>>6] = im; }
  __syncthreads();
  if (g == 0){
    circ[d]        = (float)((rs[0]+rs[1]+rs[2]+rs[3]) / 196.0);
    circ[NIMG + d] = (float)((is[0]+is[1]+is[2]+is[3]) / 196.0);
  }
}

// -------- low-frequency-energy: f32 conv, f64 accumulation ----------------
__global__ __launch_bounds__(256) void lfe_kernel(
    const float* __restrict__ x1, const float* __restrict__ circ,
    double* __restrict__ lfe_part, double* __restrict__ den_part)
{
  __shared__ float xs[NIMG][36];
  __shared__ float2 c2[NIMG];
  __shared__ double red[4];
  const int cg = blockIdx.x, b = blockIdx.y;
  const int c0 = cg * 32;
  for (int li=threadIdx.x; li<NIMG*32; li+=256){
    const int m = li >> 5, ch = li & 31;
    xs[m][ch] = x1[((size_t)b*NTOK + 1 + m)*CDIM + c0 + ch];
  }
  for (int li=threadIdx.x; li<NIMG; li+=256) c2[li] = make_float2(circ[li], circ[NIMG+li]);
  __syncthreads();
  const int n = threadIdx.x;
  double lfe_sum = 0.0, den_sum = 0.0;
  if (n < NIMG){
    #pragma unroll 1
    for (int g=0; g<4; g++){
      const int cc0 = g*8;
      float re[8] = {0,0,0,0,0,0,0,0};
      float im[8] = {0,0,0,0,0,0,0,0};
      int d = n;
      for (int mm=0; mm<NIMG; mm++){
        const float2 cc = c2[d];
        const float4 xa = *(const float4*)&xs[mm][cc0];
        const float4 xb = *(const float4*)&xs[mm][cc0+4];
        const float xv[8] = {xa.x,xa.y,xa.z,xa.w,xb.x,xb.y,xb.z,xb.w};
        #pragma unroll
        for (int q=0;q<8;q++){
          re[q] = fmaf(cc.x, xv[q], re[q]);
          im[q] = fmaf(cc.y, xv[q], im[q]);
        }
        d = (d==0) ? (NIMG-1) : (d-1);
      }
      #pragma unroll
      for (int q=0;q<8;q++) lfe_sum += (double)sqrtf(re[q]*re[q] + im[q]*im[q]);
    }
    #pragma unroll
    for (int q=0;q<8;q++){
      const float4 xv = *(const float4*)&xs[n][q*4];
      den_sum += (double)fabsf(xv.x)+(double)fabsf(xv.y)+(double)fabsf(xv.z)+(double)fabsf(xv.w);
    }
    lfe_part[((size_t)b*24 + cg)*NIMG + n] = lfe_sum;
  }
  double s = (n < NIMG) ? den_sum : 0.0;
  #pragma unroll
  for (int o=32;o>0;o>>=1) s += __shfl_down(s,o);
  if ((threadIdx.x & 63) == 0) red[threadIdx.x >> 6] = s;
  __syncthreads();
  if (threadIdx.x == 0) den_part[b*24 + cg] = red[0]+red[1]+red[2]+red[3];
}

// -------- scores[b,n] = (lfe_num / (den/196)) * token_attn (f64) ----------
__global__ __launch_bounds__(256) void scores_kernel(
    const double* __restrict__ lfe_part, const double* __restrict__ den_part,
    const double* __restrict__ token_attn, double* __restrict__ scores)
{
  const int b = blockIdx.x, n = threadIdx.x;
  if (n < NIMG){
    double num = 0.0;
    for (int cg=0; cg<24; cg++) num += lfe_part[((size_t)b*24 + cg)*NIMG + n];
    double den = 0.0;
    for (int cg=0; cg<24; cg++) den += den_part[b*24 + cg];
    const double tl = num / (den / 196.0);
    scores[b*NIMG + n] = tl * token_attn[b*NIMG + n];
  }
}

// -------- top-118, descending, stable (ties -> lower index); 1 wave -------
__global__ void topk_kernel(const double* __restrict__ scores, int* __restrict__ idx)
{
  __shared__ double w[NIMG];
  const int b = blockIdx.x, lane = threadIdx.x;   // blockDim = 64
  for (int i=lane; i<NIMG; i+=64) w[i] = scores[b*NIMG + i];
  __syncthreads();
  for (int r=0; r<NSEL; r++){
    double bv = -INFINITY; int bi = NIMG;
    for (int i=lane; i<NIMG; i+=64){
      const double v = w[i];
      if (v > bv){ bv = v; bi = i; }
    }
    #pragma unroll
    for (int o=32;o>0;o>>=1){
      const double ov = __shfl_down(bv,o);
      const int    oi = __shfl_down(bi,o);
      if (ov > bv || (ov == bv && oi < bi)){ bv = ov; bi = oi; }
    }
    if (lane == 0){
      idx[b*NSEL + r] = bi;
      w[bi] = -INFINITY;
    }
    __syncthreads();
  }
}

// -------- gather selected tokens -----------------------------------------
__global__ void gather_kernel(const float* __restrict__ x1, const int* __restrict__ idx,
                              float* __restrict__ xsel)
{
  const int row = blockIdx.x;
  const int b = row / (NSEL+1), r = row % (NSEL+1);
  const int src = (r == 0) ? 0 : (1 + idx[b*NSEL + (r-1)]);
  const float4* s = (const float4*)(x1 + ((size_t)b*NTOK + src)*CDIM);
  float4* d = (float4*)(xsel + (size_t)row*CDIM);
  d[threadIdx.x] = s[threadIdx.x];
}

// ===========================================================================
extern "C" void kernel_launch(void* const* d_in, const int* in_sizes, int n_in,
                              void* d_out, int out_size, void* d_ws, size_t ws_size,
                              hipStream_t stream)
{
  const float* x      = (const float*)d_in[0];
  const float* ln1_w  = (const float*)d_in[1];
  const float* ln1_b  = (const float*)d_in[2];
  const float* qkv_w  = (const float*)d_in[3];
  const float* proj_w = (const float*)d_in[4];
  const float* proj_b = (const float*)d_in[5];
  const float* gamma1 = (const float*)d_in[6];
  const float* ln2_w  = (const float*)d_in[7];
  const float* ln2_b  = (const float*)d_in[8];
  const float* fc1_w  = (const float*)d_in[9];
  const float* fc1_b  = (const float*)d_in[10];
  const float* fc2_w  = (const float*)d_in[11];
  const float* fc2_b  = (const float*)d_in[12];
  const float* gamma2 = (const float*)d_in[13];
  float* out = (float*)d_out;
  float* ws  = (float*)d_ws;

  float* R1 = ws;                                   // 9,732,096 f
  float* R2 = ws + 9732096;                         // 29,048,832 f
  double* D = (double*)(ws + 9732096 + 29048832);   // f-off 38,780,928
  double* mbuf = D;                   // 151296
  double* lbuf = mbuf + 151296;       // 151296
  double* tap  = lbuf + 151296;       // 150528
  double* ta   = tap  + 150528;       // 12544
  double* lfep = ta   + 12544;        // 301056
  double* denp = lfep + 301056;       // 1536
  double* sc   = denp + 1536;         // 12544
  float* circ  = (float*)(sc + 12544);        // 392 f
  int*   idxb  = (int*)(circ + 392);          // 7552 i
  unsigned short* W3p = (unsigned short*)(ws + 40350472);   // 768x1536 us
  unsigned short* WQ3 = (unsigned short*)(ws + 40940296);   // 3 x 2304x768 us
  unsigned short* XQ3 = (unsigned short*)(ws + 43594504);   // 3 x 12672x768 us
  const size_t NEED_BYTES = (size_t)58192648 * 4;           // ~233 MB

  // sel split scratch (region reuse; both dead at selp/selc time):
  double* csp   = lfep;                          // 302,592 doubles (lfep+denp)
  double* e0buf = (double*)(ws + 40940296);      // 151,296 doubles (dead WQ3)

  float* xln  = R1;
  unsigned short* msa3 = (unsigned short*)R1;
  float* xsel = R1;
  float* qkv  = R2;
  float* x1   = R2;
  unsigned short* ln2o_bf = (unsigned short*)(R2 + 9682944);   // 7680*768
  unsigned short* fc1w_bf = (unsigned short*)(R2 + 12632064);  // 3072*768
  unsigned short* fc2w_bf = (unsigned short*)(R2 + 13811712);  // 768*3072
  unsigned short* h1_bf   = (unsigned short*)(R2 + 14991360);  // 7680*3072

  // 1-2) LN1 + qkv = ln(x) @ qkv_w^T  [12608,2304]
  if (ws_size >= NEED_BYTES){
    ln_split3_kernel<<<ROWS_FULL, 256, 0, stream>>>(x, ln1_w, ln1_b, XQ3, (size_t)9732096);
    cvt_split3_kernel<<<(442368+255)/256, 256, 0, stream>>>(qkv_w, WQ3, 442368, (size_t)1769472);
    mfma_gemm6w_kernel<<<197*9, 512, 0, stream>>>(XQ3, WQ3, qkv, ROWS_FULL, 2304, 768,
                                                  (size_t)9732096, (size_t)1769472, 197);
  } else {
    ln_kernel<0><<<ROWS_FULL, 256, 0, stream>>>(x, ln1_w, ln1_b, xln);
    gemm_f32_kernel<<<dim3(99,18), 256, 0, stream>>>(xln, qkv_w, qkv, ROWS_FULL, 2304, 768);
  }
  // 3-4) flash attention: one-pass stats + PV -> msa hi/lo bf16 (over R1)
  attn_flash_kernel<<<BATCH*NHEAD, 256, 0, stream>>>(qkv, mbuf, lbuf, msa3);
  // 5) selector stats: split i2 range (2 blocks/bh, 25 KB Qt -> 6/CU), combine
  attn_selp_kernel<<<BATCH*NHEAD*2, 256, 0, stream>>>(qkv, mbuf, lbuf, csp, e0buf);
  attn_selc_kernel<<<BATCH*NHEAD, 256, 0, stream>>>(csp, e0buf, tap);
  reduce_ta_kernel<<<BATCH, 256, 0, stream>>>(tap, ta);
  // 6) proj via 3-term split MFMA v2: x1 = gamma1*(msa@proj_w^T + b) + x
  cvt3_kernel<<<CDIM, 192, 0, stream>>>(proj_w, W3p, CDIM);
  mfma_proj3_kernel<<<197*3, 512, 0, stream>>>(msa3, W3p, proj_b, gamma1, x,
                                               x1, ROWS_FULL, CDIM, CDIM, 197);
  // 6b) fc weights -> bf16
  cvt_bf16_kernel<<<2304, 256, 0, stream>>>(fc1_w, fc1w_bf, 589824);
  cvt_bf16_kernel<<<2304, 256, 0, stream>>>(fc2_w, fc2w_bf, 589824);
  // 7) selector scores
  circ_kernel<<<NIMG, 256, 0, stream>>>(circ);
  lfe_kernel<<<dim3(24, BATCH), 256, 0, stream>>>(x1, circ, lfep, denp);
  scores_kernel<<<BATCH, 256, 0, stream>>>(lfep, denp, ta, sc);
  // 8) top-118 + gather (xsel over dead msa3)
  topk_kernel<<<BATCH, 64, 0, stream>>>(sc, idxb);
  gather_kernel<<<ROWS_SEL, 192, 0, stream>>>(x1, idxb, xsel);
  // 9) MLP: LN2 -> bf16, fc1/fc2 via v5-style M64xN256 MFMA
  ln_kernel<1><<<ROWS_SEL, 256, 0, stream>>>(xsel, ln2_w, ln2_b, ln2o_bf);
  mfma_gemm1w_kernel<2><<<119*12, 512, 0, stream>>>(ln2o_bf, fc1w_bf, fc1_b, nullptr,
                                                    nullptr, h1_bf, ROWS_SEL, 3072, 768, 119);
  mfma_gemm1w_kernel<3><<<119*3, 512, 0, stream>>>(h1_bf, fc2w_bf, fc2_b, gamma2,
                                                   xsel, out, ROWS_SEL, 768, 3072, 119);
}

// Round 19
// 1125.834 us; speedup vs baseline: 1.5738x; 1.0020x over previous
//
#include <hip/hip_runtime.h>
#include <math.h>

#define NTOK 197
#define NIMG 196
#define CDIM 768
#define NHEAD 12
#define HD 64
#define BATCH 64
#define NSEL 118
#define ROWS_FULL (BATCH*NTOK)     // 12608
#define ROWS_SEL  (BATCH*(NSEL+1)) // 7616

typedef short bf16x8 __attribute__((ext_vector_type(8)));
typedef float f32x4  __attribute__((ext_vector_type(4)));

#define GLDS(g, l) __builtin_amdgcn_global_load_lds( \
    (const __attribute__((address_space(1))) void*)(g), \
    (__attribute__((address_space(3))) void*)(l), 16, 0, 0)

__device__ __forceinline__ unsigned short f2bf(float f){
  union { float f; unsigned u; } v; v.f = f;
  unsigned r = v.u + 0x7FFF + ((v.u >> 16) & 1);
  return (unsigned short)(r >> 16);
}
__device__ __forceinline__ float bf2f(unsigned short h){
  union { unsigned u; float f; } v; v.u = ((unsigned)h) << 16; return v.f;
}

// ---------------- LayerNorm (one block per row, C=768). OUT: 0=f32 1=bf16 --
template<int OUT>
__global__ __launch_bounds__(256) void ln_kernel(
    const float* __restrict__ x, const float* __restrict__ w,
    const float* __restrict__ b, void* __restrict__ outv)
{
  const int row = blockIdx.x;
  const int t = threadIdx.x;
  const float* xr = x + (size_t)row * CDIM;
  float v0 = xr[t], v1 = xr[t+256], v2 = xr[t+512];
  float s = v0 + v1 + v2;
  __shared__ float red[4], red2[4];
  #pragma unroll
  for (int o=32;o>0;o>>=1) s += __shfl_down(s,o);
  if ((t&63)==0) red[t>>6] = s;
  __syncthreads();
  const float mean = (red[0]+red[1]+red[2]+red[3]) / 768.0f;
  const float d0=v0-mean, d1=v1-mean, d2=v2-mean;
  float vs = d0*d0 + d1*d1 + d2*d2;
  #pragma unroll
  for (int o=32;o>0;o>>=1) vs += __shfl_down(vs,o);
  if ((t&63)==0) red2[t>>6] = vs;
  __syncthreads();
  const float var = (red2[0]+red2[1]+red2[2]+red2[3]) / 768.0f;
  const float rstd = 1.0f / sqrtf(var + 1e-5f);
  const float o0 = d0*rstd*w[t]     + b[t];
  const float o1 = d1*rstd*w[t+256] + b[t+256];
  const float o2 = d2*rstd*w[t+512] + b[t+512];
  if (OUT == 0){
    float* orow = (float*)outv + (size_t)row * CDIM;
    orow[t] = o0; orow[t+256] = o1; orow[t+512] = o2;
  } else {
    unsigned short* orow = (unsigned short*)outv + (size_t)row * CDIM;
    orow[t] = f2bf(o0); orow[t+256] = f2bf(o1); orow[t+512] = f2bf(o2);
  }
}

// -------- LN1 fused with 3-plane bf16 split (big-ws path) -----------------
__global__ __launch_bounds__(256) void ln_split3_kernel(
    const float* __restrict__ x, const float* __restrict__ w,
    const float* __restrict__ b, unsigned short* __restrict__ dst, size_t plane)
{
  const int row = blockIdx.x;
  const int t = threadIdx.x;
  const float* xr = x + (size_t)row * CDIM;
  float v0 = xr[t], v1 = xr[t+256], v2 = xr[t+512];
  float s = v0 + v1 + v2;
  __shared__ float red[4], red2[4];
  #pragma unroll
  for (int o=32;o>0;o>>=1) s += __shfl_down(s,o);
  if ((t&63)==0) red[t>>6] = s;
  __syncthreads();
  const float mean = (red[0]+red[1]+red[2]+red[3]) / 768.0f;
  const float d0=v0-mean, d1=v1-mean, d2=v2-mean;
  float vs = d0*d0 + d1*d1 + d2*d2;
  #pragma unroll
  for (int o=32;o>0;o>>=1) vs += __shfl_down(vs,o);
  if ((t&63)==0) red2[t>>6] = vs;
  __syncthreads();
  const float var = (red2[0]+red2[1]+red2[2]+red2[3]) / 768.0f;
  const float rstd = 1.0f / sqrtf(var + 1e-5f);
  const float ov[3] = { d0*rstd*w[t]     + b[t],
                        d1*rstd*w[t+256] + b[t+256],
                        d2*rstd*w[t+512] + b[t+512] };
  #pragma unroll
  for (int e=0;e<3;e++){
    const int col = t + e*256;
    const float f = ov[e];
    const unsigned short p0 = f2bf(f);
    const float r1 = f - bf2f(p0);
    const unsigned short p1 = f2bf(r1);
    const unsigned short p2 = f2bf(r1 - bf2f(p1));
    dst[(size_t)row*CDIM + col]             = p0;
    dst[plane + (size_t)row*CDIM + col]     = p1;
    dst[2*plane + (size_t)row*CDIM + col]   = p2;
  }
}

// ---------------- f32 -> bf16 conversion (4 elems/thread) ----------------
__global__ __launch_bounds__(256) void cvt_bf16_kernel(
    const float* __restrict__ src, unsigned short* __restrict__ dst, int n4)
{
  const int i = blockIdx.x*256 + threadIdx.x;
  if (i < n4){
    const float4 v = *(const float4*)(src + (size_t)i*4);
    dst[(size_t)i*4+0] = f2bf(v.x); dst[(size_t)i*4+1] = f2bf(v.y);
    dst[(size_t)i*4+2] = f2bf(v.z); dst[(size_t)i*4+3] = f2bf(v.w);
  }
}

// ---------------- f32 -> hi/lo bf16 split, row layout [n][2K] -------------
__global__ __launch_bounds__(192) void cvt3_kernel(
    const float* __restrict__ w, unsigned short* __restrict__ W3, int K)
{
  const int n = blockIdx.x, t = threadIdx.x;
  const float4 v = *(const float4*)(w + (size_t)n*K + t*4);
  ushort4 hi, lo;
  hi.x = f2bf(v.x); lo.x = f2bf(v.x - bf2f(hi.x));
  hi.y = f2bf(v.y); lo.y = f2bf(v.y - bf2f(hi.y));
  hi.z = f2bf(v.z); lo.z = f2bf(v.z - bf2f(hi.z));
  hi.w = f2bf(v.w); lo.w = f2bf(v.w - bf2f(hi.w));
  *(ushort4*)(W3 + (size_t)n*2*K + t*4)     = hi;
  *(ushort4*)(W3 + (size_t)n*2*K + K + t*4) = lo;
}

// ------- f32 -> 3 bf16 planes (a = p0 + p1 + p2, 24 mantissa bits) --------
__global__ __launch_bounds__(256) void cvt_split3_kernel(
    const float* __restrict__ src, unsigned short* __restrict__ dst,
    int n4, size_t plane)
{
  const int i = blockIdx.x*256 + threadIdx.x;
  if (i >= n4) return;
  const float4 v = *(const float4*)(src + (size_t)i*4);
  const float f[4] = {v.x, v.y, v.z, v.w};
  unsigned short p0[4], p1[4], p2[4];
  #pragma unroll
  for (int q=0;q<4;q++){
    p0[q] = f2bf(f[q]);
    const float r1 = f[q] - bf2f(p0[q]);
    p1[q] = f2bf(r1);
    const float r2 = r1 - bf2f(p1[q]);
    p2[q] = f2bf(r2);
  }
  *(ushort4*)(dst + (size_t)i*4)           = make_ushort4(p0[0],p0[1],p0[2],p0[3]);
  *(ushort4*)(dst + plane + (size_t)i*4)   = make_ushort4(p1[0],p1[1],p1[2],p1[3]);
  *(ushort4*)(dst + 2*plane + (size_t)i*4) = make_ushort4(p2[0],p2[1],p2[2],p2[3]);
}

// -------- f32 GEMM fallback (round-3 proven): out = A[M,K] @ W[N,K]^T -----
__global__ __launch_bounds__(256) void gemm_f32_kernel(
    const float* __restrict__ A, const float* __restrict__ W,
    float* __restrict__ out, int M, int N, int K)
{
  __shared__ float As[16][132];
  __shared__ float Bs[16][132];
  const int t  = threadIdx.x;
  const int tx = t & 15, ty = t >> 4;
  const int m0 = blockIdx.x * 128, n0 = blockIdx.y * 128;
  const int lr = t >> 2, lc = (t & 3) << 2;
  float acc[2][2][4][4] = {{{{0.f}}}};
  const float4 z4 = make_float4(0.f,0.f,0.f,0.f);
  const int rowA0 = m0 + lr, rowA1 = m0 + 64 + lr;
  const size_t strA0 = (size_t)rowA0 * K, strA1 = (size_t)rowA1 * K;
  const size_t strW0 = (size_t)(n0+lr) * K, strW1 = (size_t)(n0+64+lr) * K;
  for (int k0=0; k0<K; k0+=16){
    float4 a0 = (rowA0 < M) ? *(const float4*)(A + strA0 + k0 + lc) : z4;
    float4 a1 = (rowA1 < M) ? *(const float4*)(A + strA1 + k0 + lc) : z4;
    float4 w0 = *(const float4*)(W + strW0 + k0 + lc);
    float4 w1 = *(const float4*)(W + strW1 + k0 + lc);
    __syncthreads();
    As[lc+0][lr]=a0.x; As[lc+1][lr]=a0.y; As[lc+2][lr]=a0.z; As[lc+3][lr]=a0.w;
    As[lc+0][64+lr]=a1.x; As[lc+1][64+lr]=a1.y; As[lc+2][64+lr]=a1.z; As[lc+3][64+lr]=a1.w;
    Bs[lc+0][lr]=w0.x; Bs[lc+1][lr]=w0.y; Bs[lc+2][lr]=w0.z; Bs[lc+3][lr]=w0.w;
    Bs[lc+0][64+lr]=w1.x; Bs[lc+1][64+lr]=w1.y; Bs[lc+2][64+lr]=w1.z; Bs[lc+3][64+lr]=w1.w;
    __syncthreads();
    #pragma unroll
    for (int k=0;k<16;k++){
      const float4 av0 = *(const float4*)&As[k][ty*4];
      const float4 av1 = *(const float4*)&As[k][64+ty*4];
      const float4 bv0 = *(const float4*)&Bs[k][tx*4];
      const float4 bv1 = *(const float4*)&Bs[k][64+tx*4];
      const float ar[2][4] = {{av0.x,av0.y,av0.z,av0.w},{av1.x,av1.y,av1.z,av1.w}};
      const float br[2][4] = {{bv0.x,bv0.y,bv0.z,bv0.w},{bv1.x,bv1.y,bv1.z,bv1.w}};
      #pragma unroll
      for (int ri=0;ri<2;ri++)
        #pragma unroll
        for (int i=0;i<4;i++)
          #pragma unroll
          for (int ci=0;ci<2;ci++)
            #pragma unroll
            for (int j=0;j<4;j++)
              acc[ri][ci][i][j] = fmaf(ar[ri][i], br[ci][j], acc[ri][ci][i][j]);
    }
  }
  #pragma unroll
  for (int ri=0;ri<2;ri++){
    #pragma unroll
    for (int i=0;i<4;i++){
      const int row = m0 + ri*64 + ty*4 + i;
      if (row >= M) continue;
      #pragma unroll
      for (int ci=0;ci<2;ci++){
        const int col = n0 + ci*64 + tx*4;
        *(float4*)(out + (size_t)row*N + col) =
          make_float4(acc[ri][ci][i][0],acc[ri][ci][i][1],acc[ri][ci][i][2],acc[ri][ci][i][3]);
      }
    }
  }
}

// ==== 6-term qkv GEMM v5: M64 x N256, 8 waves (2Mx4N), 56 KB LDS ==========
__global__ __launch_bounds__(512) void mfma_gemm6w_kernel(
    const unsigned short* __restrict__ A3, const unsigned short* __restrict__ W3,
    float* __restrict__ out, int M, int N, int K, size_t planeA, size_t planeW,
    int gx)
{
  __shared__ __align__(16) unsigned short As[3][64*64];   // 24 KB
  __shared__ __align__(16) unsigned short Ws[256*64];     // 32 KB
  const int nwg = gridDim.x;
  const int q8 = nwg >> 3, r8 = nwg & 7;
  const int xcd = blockIdx.x & 7, lid = blockIdx.x >> 3;
  const int swz = (xcd < r8) ? (xcd*(q8+1) + lid) : (r8*(q8+1) + (xcd-r8)*q8 + lid);
  const int bx = swz % gx, by = swz / gx;

  const int t = threadIdx.x;
  const int w = t >> 6, lane = t & 63;
  const int m0 = bx * 64, n0 = by * 256;
  const int wr = w >> 2, wc = w & 3;
  f32x4 acc[2][4];
  #pragma unroll
  for (int i=0;i<2;i++)
    #pragma unroll
    for (int j=0;j<4;j++){ acc[i][j][0]=0.f; acc[i][j][1]=0.f; acc[i][j][2]=0.f; acc[i][j][3]=0.f; }

  const int srow = lane >> 3;
  const int slot = lane & 7;
  const int scol = (slot ^ srow) * 8;
  const int aloc = w*8;
  const int wloc = w*32;
  const int fr = lane & 15;
  const int kg = lane >> 4;

  #define SEGW(NA)                                                            \
    _Pragma("unroll")                                                         \
    for (int ksub = 0; ksub < 2; ksub++){                                     \
      const int kbyte = ksub*64 + kg*16;                                      \
      bf16x8 b[4];                                                            \
      _Pragma("unroll")                                                       \
      for (int ni=0; ni<4; ni++){                                             \
        const int br = wc*64 + ni*16 + fr;                                    \
        b[ni] = *(const bf16x8*)(Ws + br*64 + ((kbyte ^ ((br&7)<<4)) >> 1));  \
      }                                                                       \
      _Pragma("unroll")                                                       \
      for (int p=0; p<NA; p++){                                               \
        bf16x8 a[2];                                                          \
        _Pragma("unroll")                                                     \
        for (int mi=0; mi<2; mi++){                                           \
          const int ar = wr*32 + mi*16 + fr;                                  \
          a[mi] = *(const bf16x8*)(As[p] + ar*64 + ((kbyte ^ ((ar&7)<<4)) >> 1)); \
        }                                                                     \
        _Pragma("unroll")                                                     \
        for (int mi=0; mi<2; mi++)                                            \
          _Pragma("unroll")                                                   \
          for (int ni=0; ni<4; ni++)                                          \
            acc[mi][ni] = __builtin_amdgcn_mfma_f32_16x16x32_bf16(a[mi], b[ni], acc[mi][ni], 0, 0, 0); \
      }                                                                       \
    }

  #define STAGE_W(P)                                                          \
    _Pragma("unroll")                                                         \
    for (int tt=0; tt<4; tt++){                                               \
      const int rl = wloc + tt*8;                                             \
      GLDS(W3 + (size_t)(P)*planeW + (size_t)(n0+rl+srow)*K + k0 + scol, Ws + rl*64); \
    }

  for (int k0 = 0; k0 < K; k0 += 64){
    __syncthreads();
    #pragma unroll
    for (int p=0; p<3; p++)
      GLDS(A3 + (size_t)p*planeA + (size_t)(m0+aloc+srow)*K + k0 + scol, As[p] + aloc*64);
    STAGE_W(0)
    __syncthreads();
    SEGW(3)
    __syncthreads();
    STAGE_W(1)
    __syncthreads();
    SEGW(2)
    __syncthreads();
    STAGE_W(2)
    __syncthreads();
    SEGW(1)
  }
  #undef SEGW
  #undef STAGE_W

  const int cL = lane & 15, rL = lane >> 4;
  #pragma unroll
  for (int mi=0; mi<2; mi++){
    #pragma unroll
    for (int ni=0; ni<4; ni++){
      const int col = n0 + wc*64 + ni*16 + cL;
      const int rowb = m0 + wr*32 + mi*16 + rL*4;
      #pragma unroll
      for (int r=0; r<4; r++){
        const int row = rowb + r;
        if (row >= M) continue;
        out[(size_t)row*N + col] = acc[mi][ni][r];
      }
    }
  }
}

// ==== plain bf16 GEMM v5: M64 x N256, 8 waves, 40 KB LDS (4 blocks/CU) ====
template<int EPI>
__global__ __launch_bounds__(512) void mfma_gemm1w_kernel(
    const unsigned short* __restrict__ A, const unsigned short* __restrict__ W,
    const float* __restrict__ bias, const float* __restrict__ gamma,
    const float* __restrict__ resid, void* __restrict__ outv,
    int M, int N, int K, int gx)
{
  __shared__ __align__(16) unsigned short As[64*64];      // 8 KB
  __shared__ __align__(16) unsigned short Ws[256*64];     // 32 KB
  const int nwg = gridDim.x;
  const int q8 = nwg >> 3, r8 = nwg & 7;
  const int xcd = blockIdx.x & 7, lid = blockIdx.x >> 3;
  const int swz = (xcd < r8) ? (xcd*(q8+1) + lid) : (r8*(q8+1) + (xcd-r8)*q8 + lid);
  const int bx = swz % gx, by = swz / gx;

  const int t = threadIdx.x;
  const int w = t >> 6, lane = t & 63;
  const int m0 = bx * 64, n0 = by * 256;
  const int wr = w >> 2, wc = w & 3;
  f32x4 acc[2][4];
  #pragma unroll
  for (int i=0;i<2;i++)
    #pragma unroll
    for (int j=0;j<4;j++){ acc[i][j][0]=0.f; acc[i][j][1]=0.f; acc[i][j][2]=0.f; acc[i][j][3]=0.f; }

  const int srow = lane >> 3;
  const int slot = lane & 7;
  const int scol = (slot ^ srow) * 8;
  const int aloc = w*8;
  const int wloc = w*32;
  const int fr = lane & 15;
  const int kg = lane >> 4;

  for (int k0 = 0; k0 < K; k0 += 64){
    __syncthreads();
    GLDS(A + (size_t)(m0+aloc+srow)*K + k0 + scol, As + aloc*64);
    #pragma unroll
    for (int tt=0; tt<4; tt++){
      const int rl = wloc + tt*8;
      GLDS(W + (size_t)(n0+rl+srow)*K + k0 + scol, Ws + rl*64);
    }
    __syncthreads();
    #pragma unroll
    for (int ksub = 0; ksub < 2; ksub++){
      const int kbyte = ksub*64 + kg*16;
      bf16x8 b[4];
      #pragma unroll
      for (int ni=0; ni<4; ni++){
        const int br = wc*64 + ni*16 + fr;
        b[ni] = *(const bf16x8*)(Ws + br*64 + ((kbyte ^ ((br&7)<<4)) >> 1));
      }
      bf16x8 a[2];
      #pragma unroll
      for (int mi=0; mi<2; mi++){
        const int ar = wr*32 + mi*16 + fr;
        a[mi] = *(const bf16x8*)(As + ar*64 + ((kbyte ^ ((ar&7)<<4)) >> 1));
      }
      #pragma unroll
      for (int mi=0; mi<2; mi++)
        #pragma unroll
        for (int ni=0; ni<4; ni++)
          acc[mi][ni] = __builtin_amdgcn_mfma_f32_16x16x32_bf16(a[mi], b[ni], acc[mi][ni], 0, 0, 0);
    }
  }

  const int cL = lane & 15, rL = lane >> 4;
  #pragma unroll
  for (int mi=0; mi<2; mi++){
    #pragma unroll
    for (int ni=0; ni<4; ni++){
      const int col = n0 + wc*64 + ni*16 + cL;
      const int rowb = m0 + wr*32 + mi*16 + rL*4;
      const float bb = bias[col];
      #pragma unroll
      for (int r=0; r<4; r++){
        const int row = rowb + r;
        if (row >= M) continue;
        float v = acc[mi][ni][r] + bb;
        if (EPI == 2){
          v = 0.5f*v*(1.0f + erff(v*0.7071067811865475f));
          ((unsigned short*)outv)[(size_t)row*N + col] = f2bf(v);
        } else {
          v = gamma[col]*v + resid[(size_t)row*N + col];
          ((float*)outv)[(size_t)row*N + col] = v;
        }
      }
    }
  }
}

// ==== proj v2: 3-term split, M64 x N256, 8 waves, 48 KB LDS (3 blocks/CU) ==
__global__ __launch_bounds__(512) void mfma_proj3_kernel(
    const unsigned short* __restrict__ A, const unsigned short* __restrict__ W,
    const float* __restrict__ bias, const float* __restrict__ gamma,
    const float* __restrict__ resid, float* __restrict__ out,
    int M, int N, int K, int gx)
{
  __shared__ __align__(16) unsigned short Ah[64*64], Al[64*64];  // 16 KB
  __shared__ __align__(16) unsigned short Ws[256*64];            // 32 KB
  const int nwg = gridDim.x;
  const int q8 = nwg >> 3, r8 = nwg & 7;
  const int xcd = blockIdx.x & 7, lid = blockIdx.x >> 3;
  const int swz = (xcd < r8) ? (xcd*(q8+1) + lid) : (r8*(q8+1) + (xcd-r8)*q8 + lid);
  const int bx = swz % gx, by = swz / gx;

  const int t = threadIdx.x;
  const int w = t >> 6, lane = t & 63;
  const int m0 = bx * 64, n0 = by * 256;
  const int wr = w >> 2, wc = w & 3;
  const int lda = 2*K;
  f32x4 acc[2][4];
  #pragma unroll
  for (int i=0;i<2;i++)
    #pragma unroll
    for (int j=0;j<4;j++){ acc[i][j][0]=0.f; acc[i][j][1]=0.f; acc[i][j][2]=0.f; acc[i][j][3]=0.f; }

  const int srow = lane >> 3;
  const int slot = lane & 7;
  const int scol = (slot ^ srow) * 8;
  const int aloc = w*8;
  const int wloc = w*32;
  const int fr = lane & 15;
  const int kg = lane >> 4;

  #define PSEG(NA)                                                            \
    _Pragma("unroll")                                                         \
    for (int ksub = 0; ksub < 2; ksub++){                                     \
      const int kbyte = ksub*64 + kg*16;                                      \
      bf16x8 b[4];                                                            \
      _Pragma("unroll")                                                       \
      for (int ni=0; ni<4; ni++){                                             \
        const int br = wc*64 + ni*16 + fr;                                    \
        b[ni] = *(const bf16x8*)(Ws + br*64 + ((kbyte ^ ((br&7)<<4)) >> 1));  \
      }                                                                       \
      _Pragma("unroll")                                                       \
      for (int mi=0; mi<2; mi++){                                             \
        const int ar = wr*32 + mi*16 + fr;                                    \
        const int ao = ar*64 + ((kbyte ^ ((ar&7)<<4)) >> 1);                  \
        bf16x8 ah = *(const bf16x8*)(Ah + ao);                                \
        _Pragma("unroll")                                                     \
        for (int ni=0; ni<4; ni++)                                            \
          acc[mi][ni] = __builtin_amdgcn_mfma_f32_16x16x32_bf16(ah, b[ni], acc[mi][ni], 0, 0, 0); \
        if (NA > 1){                                                          \
          bf16x8 al = *(const bf16x8*)(Al + ao);                              \
          _Pragma("unroll")                                                   \
          for (int ni=0; ni<4; ni++)                                          \
            acc[mi][ni] = __builtin_amdgcn_mfma_f32_16x16x32_bf16(al, b[ni], acc[mi][ni], 0, 0, 0); \
        }                                                                     \
      }                                                                       \
    }

  for (int k0 = 0; k0 < K; k0 += 64){
    __syncthreads();
    {
      const size_t abase = (size_t)(m0+aloc+srow)*lda + k0 + scol;
      GLDS(A + abase,     Ah + aloc*64);
      GLDS(A + abase + K, Al + aloc*64);
    }
    #pragma unroll
    for (int tt=0; tt<4; tt++){
      const int rl = wloc + tt*8;
      GLDS(W + (size_t)(n0+rl+srow)*lda + k0 + scol, Ws + rl*64);
    }
    __syncthreads();
    PSEG(2)
    __syncthreads();
    #pragma unroll
    for (int tt=0; tt<4; tt++){
      const int rl = wloc + tt*8;
      GLDS(W + (size_t)(n0+rl+srow)*lda + K + k0 + scol, Ws + rl*64);
    }
    __syncthreads();
    PSEG(1)
  }
  #undef PSEG

  const int cL = lane & 15, rL = lane >> 4;
  #pragma unroll
  for (int mi=0; mi<2; mi++){
    #pragma unroll
    for (int ni=0; ni<4; ni++){
      const int col = n0 + wc*64 + ni*16 + cL;
      const int rowb = m0 + wr*32 + mi*16 + rL*4;
      const float bb = bias[col];
      const float gg = gamma[col];
      #pragma unroll
      for (int r=0; r<4; r++){
        const int row = rowb + r;
        if (row >= M) continue;
        out[(size_t)row*N + col] = gg*(acc[mi][ni][r] + bb) + resid[(size_t)row*N + col];
      }
    }
  }
}

// ---- flash attention FALLBACK (R17, proven): single block per bh ---------
__global__ __launch_bounds__(256) void attn_flash_kernel(
    const float* __restrict__ qkv, double* __restrict__ mbuf,
    double* __restrict__ lbuf, unsigned short* __restrict__ msa3)
{
  __shared__ float Kt[NTOK][HD];      // 50,432 B
  __shared__ double q0s[HD];
  __shared__ float m0sh;
  __shared__ double red[4];
  __shared__ float l0f;
  const int bh = blockIdx.x;
  const int b = bh / NHEAD, h = bh % NHEAD;
  const float* basep = qkv + (size_t)b*NTOK*2304 + h*HD;
  for (int li=threadIdx.x; li<NTOK*16; li+=256){
    const int r = li >> 4, c4 = (li & 15) << 2;
    *(float4*)&Kt[r][c4] = *(const float4*)(basep + (size_t)r*2304 + 768 + c4);
  }
  if (threadIdx.x < 16){
    const float4 t4 = *(const float4*)(basep + threadIdx.x*4);
    q0s[threadIdx.x*4+0] = (double)t4.x*0.125; q0s[threadIdx.x*4+1] = (double)t4.y*0.125;
    q0s[threadIdx.x*4+2] = (double)t4.z*0.125; q0s[threadIdx.x*4+3] = (double)t4.w*0.125;
  }
  __syncthreads();
  const int i = threadIdx.x;
  float4 q[16];
  float4 o[16];
  float m = -INFINITY, l = 0.f;
  if (i < NTOK){
    #pragma unroll
    for (int dd=0; dd<16; dd++){
      float4 tq = *(const float4*)(basep + (size_t)i*2304 + dd*4);
      q[dd] = make_float4(tq.x*0.125f, tq.y*0.125f, tq.z*0.125f, tq.w*0.125f);
      o[dd] = make_float4(0.f,0.f,0.f,0.f);
    }
    for (int j=0;j<NTOK;j++){
      float s = 0.f;
      #pragma unroll
      for (int dd=0;dd<16;dd++){
        const float4 kk = *(const float4*)&Kt[j][dd*4];
        s = fmaf(q[dd].x,kk.x,s); s = fmaf(q[dd].y,kk.y,s);
        s = fmaf(q[dd].z,kk.z,s); s = fmaf(q[dd].w,kk.w,s);
      }
      const float mn = fmaxf(m, s);
      const float sc = expf(m - mn);
      const float p  = expf(s - mn);
      l = l*sc + p;
      if (sc != 1.0f){
        #pragma unroll
        for (int dd=0;dd<16;dd++){
          o[dd].x *= sc; o[dd].y *= sc; o[dd].z *= sc; o[dd].w *= sc;
        }
      }
      m = mn;
      const float* vrow = basep + (size_t)j*2304 + 1536;
      #pragma unroll
      for (int dd=0;dd<16;dd++){
        const float4 vv = *(const float4*)(vrow + dd*4);
        o[dd].x = fmaf(p,vv.x,o[dd].x); o[dd].y = fmaf(p,vv.y,o[dd].y);
        o[dd].z = fmaf(p,vv.z,o[dd].z); o[dd].w = fmaf(p,vv.w,o[dd].w);
      }
    }
    mbuf[bh*NTOK+i] = (double)m;
    if (i > 0) lbuf[bh*NTOK+i] = (double)(1.0f/l);
    if (i == 0) m0sh = m;
  }
  __syncthreads();
  double e = 0.0;
  if (i < NTOK){
    double s64 = 0.0;
    #pragma unroll
    for (int d=0; d<HD; d++) s64 = fma(q0s[d], (double)Kt[i][d], s64);
    e = exp(s64 - (double)m0sh);
  }
  #pragma unroll
  for (int o2=32;o2>0;o2>>=1) e += __shfl_down(e,o2);
  if ((i&63)==0) red[i>>6] = e;
  __syncthreads();
  if (i==0){
    const double l0 = 1.0/(red[0]+red[1]+red[2]+red[3]);
    lbuf[bh*NTOK] = l0;
    l0f = (float)l0;
  }
  __syncthreads();
  if (i >= NTOK) return;
  const float linv = (i == 0) ? l0f : (1.0f/l);
  unsigned short* orow = msa3 + ((size_t)b*NTOK + i)*1536 + h*HD;
  #pragma unroll
  for (int dd=0;dd<16;dd++){
    const float4 v = make_float4(o[dd].x*linv, o[dd].y*linv, o[dd].z*linv, o[dd].w*linv);
    ushort4 hi, lo;
    hi.x = f2bf(v.x); lo.x = f2bf(v.x - bf2f(hi.x));
    hi.y = f2bf(v.y); lo.y = f2bf(v.y - bf2f(hi.y));
    hi.z = f2bf(v.z); lo.z = f2bf(v.z - bf2f(hi.z));
    hi.w = f2bf(v.w); lo.w = f2bf(v.w - bf2f(hi.w));
    *(ushort4*)(orow + dd*4)       = hi;
    *(ushort4*)(orow + 768 + dd*4) = lo;
  }
}

// ---- flash PART: half the j range per block (25 KB Kt) -------------------
// blockIdx = bh*2 + half. half 0: j in [0,99); half 1: j in [99,197).
// Writes partial m,l (f32) and unnormalized o (f32, 64/row).
__global__ __launch_bounds__(256) void attn_flashp_kernel(
    const float* __restrict__ qkv, float* __restrict__ opart,
    float* __restrict__ mpart, float* __restrict__ lpart)
{
  __shared__ float Kt[99][HD];        // 25,344 B
  const int bh   = blockIdx.x >> 1;
  const int half = blockIdx.x & 1;
  const int jbase = half ? 99 : 0;
  const int jcnt  = half ? 98 : 99;
  const int b = bh / NHEAD, h = bh % NHEAD;
  const float* basep = qkv + (size_t)b*NTOK*2304 + h*HD;
  for (int li=threadIdx.x; li<jcnt*16; li+=256){
    const int r = li >> 4, c4 = (li & 15) << 2;
    *(float4*)&Kt[r][c4] = *(const float4*)(basep + (size_t)(jbase+r)*2304 + 768 + c4);
  }
  __syncthreads();
  const int i = threadIdx.x;
  if (i >= NTOK) return;
  float4 q[16], o[16];
  #pragma unroll
  for (int dd=0; dd<16; dd++){
    float4 tq = *(const float4*)(basep + (size_t)i*2304 + dd*4);
    q[dd] = make_float4(tq.x*0.125f, tq.y*0.125f, tq.z*0.125f, tq.w*0.125f);
    o[dd] = make_float4(0.f,0.f,0.f,0.f);
  }
  float m = -INFINITY, l = 0.f;
  for (int jj=0; jj<jcnt; jj++){
    float s = 0.f;
    #pragma unroll
    for (int dd=0;dd<16;dd++){
      const float4 kk = *(const float4*)&Kt[jj][dd*4];
      s = fmaf(q[dd].x,kk.x,s); s = fmaf(q[dd].y,kk.y,s);
      s = fmaf(q[dd].z,kk.z,s); s = fmaf(q[dd].w,kk.w,s);
    }
    const float mn = fmaxf(m, s);
    const float sc = expf(m - mn);
    const float p  = expf(s - mn);
    l = l*sc + p;
    if (sc != 1.0f){
      #pragma unroll
      for (int dd=0;dd<16;dd++){
        o[dd].x *= sc; o[dd].y *= sc; o[dd].z *= sc; o[dd].w *= sc;
      }
    }
    m = mn;
    const float* vrow = basep + (size_t)(jbase+jj)*2304 + 1536;  // broadcast
    #pragma unroll
    for (int dd=0;dd<16;dd++){
      const float4 vv = *(const float4*)(vrow + dd*4);
      o[dd].x = fmaf(p,vv.x,o[dd].x); o[dd].y = fmaf(p,vv.y,o[dd].y);
      o[dd].z = fmaf(p,vv.z,o[dd].z); o[dd].w = fmaf(p,vv.w,o[dd].w);
    }
  }
  const size_t row = (size_t)blockIdx.x*NTOK + i;
  mpart[row] = m;
  lpart[row] = l;
  float* orow = opart + row*64;
  #pragma unroll
  for (int dd=0;dd<16;dd++) *(float4*)(orow + dd*4) = o[dd];
}

// ---- flash COMBINE: merge two halves; write mbuf/lbuf/msa3 ---------------
// m = max (exact, bit-identical to serial); l reordered (~1e-7 rel, accepted).
__global__ __launch_bounds__(256) void attn_flashc_kernel(
    const float* __restrict__ opart, const float* __restrict__ mpart,
    const float* __restrict__ lpart, double* __restrict__ mbuf,
    double* __restrict__ lbuf, unsigned short* __restrict__ msa3)
{
  const int bh = blockIdx.x;
  const int b = bh / NHEAD, h = bh % NHEAD;
  const int i = threadIdx.x;
  if (i >= NTOK) return;
  const size_t r0 = (size_t)(bh*2)*NTOK + i;
  const size_t r1 = (size_t)(bh*2+1)*NTOK + i;
  const float m0 = mpart[r0], m1 = mpart[r1];
  const float l0 = lpart[r0], l1 = lpart[r1];
  const float m = fmaxf(m0, m1);
  const float sc0 = expf(m0 - m);
  const float sc1 = expf(m1 - m);
  const float l = l0*sc0 + l1*sc1;
  const float linv = 1.0f / l;
  mbuf[bh*NTOK+i] = (double)m;
  lbuf[bh*NTOK+i] = (double)linv;
  const float* o0 = opart + r0*64;
  const float* o1 = opart + r1*64;
  unsigned short* orow = msa3 + ((size_t)b*NTOK + i)*1536 + h*HD;
  #pragma unroll
  for (int dd=0;dd<16;dd++){
    const float4 a = *(const float4*)(o0 + dd*4);
    const float4 c = *(const float4*)(o1 + dd*4);
    const float4 v = make_float4((a.x*sc0 + c.x*sc1)*linv,
                                 (a.y*sc0 + c.y*sc1)*linv,
                                 (a.z*sc0 + c.z*sc1)*linv,
                                 (a.w*sc0 + c.w*sc1)*linv);
    ushort4 hi, lo;
    hi.x = f2bf(v.x); lo.x = f2bf(v.x - bf2f(hi.x));
    hi.y = f2bf(v.y); lo.y = f2bf(v.y - bf2f(hi.y));
    hi.z = f2bf(v.z); lo.z = f2bf(v.z - bf2f(hi.z));
    hi.w = f2bf(v.w); lo.w = f2bf(v.w - bf2f(hi.w));
    *(ushort4*)(orow + dd*4)       = hi;
    *(ushort4*)(orow + 768 + dd*4) = lo;
  }
}

// ---- selector stats PART: half the i2 range per block (25 KB Qt) ---------
__global__ __launch_bounds__(256) void attn_selp_kernel(
    const float* __restrict__ qkv, const double* __restrict__ mbuf,
    const double* __restrict__ lbuf, double* __restrict__ csp,
    double* __restrict__ e0buf)
{
  __shared__ float Qt[98][HD];        // 25,088 B
  __shared__ double q0s[HD];
  __shared__ float msf[98], lsf[98];
  const int bh   = blockIdx.x >> 1;
  const int half = blockIdx.x & 1;
  const int i2base = 1 + half*98;
  const int b = bh / NHEAD, h = bh % NHEAD;
  const float* basep = qkv + (size_t)b*NTOK*2304 + h*HD;
  for (int li=threadIdx.x; li<98*16; li+=256){
    const int r = li >> 4, c4 = (li & 15) << 2;
    float4 tq = *(const float4*)(basep + (size_t)(i2base + r)*2304 + c4);
    Qt[r][c4+0]=tq.x*0.125f; Qt[r][c4+1]=tq.y*0.125f;
    Qt[r][c4+2]=tq.z*0.125f; Qt[r][c4+3]=tq.w*0.125f;
  }
  if (half == 0 && threadIdx.x < 16){
    const float4 t4 = *(const float4*)(basep + threadIdx.x*4);
    q0s[threadIdx.x*4+0] = (double)t4.x*0.125; q0s[threadIdx.x*4+1] = (double)t4.y*0.125;
    q0s[threadIdx.x*4+2] = (double)t4.z*0.125; q0s[threadIdx.x*4+3] = (double)t4.w*0.125;
  }
  for (int li=threadIdx.x; li<98; li+=256){
    msf[li] = (float)mbuf[bh*NTOK + i2base + li];
    lsf[li] = (float)lbuf[bh*NTOK + i2base + li];
  }
  __syncthreads();
  const int j = threadIdx.x;
  if (j < NTOK){
    float4 kreg[16];
    #pragma unroll
    for (int dd=0;dd<16;dd++) kreg[dd] = *(const float4*)(basep + (size_t)j*2304 + 768 + dd*4);
    if (half == 0){
      const double m0d = mbuf[bh*NTOK];
      double s64 = 0.0;
      #pragma unroll
      for (int dd=0;dd<16;dd++){
        s64 = fma(q0s[dd*4+0], (double)kreg[dd].x, s64);
        s64 = fma(q0s[dd*4+1], (double)kreg[dd].y, s64);
        s64 = fma(q0s[dd*4+2], (double)kreg[dd].z, s64);
        s64 = fma(q0s[dd*4+3], (double)kreg[dd].w, s64);
      }
      e0buf[(size_t)bh*NTOK + j] = exp(s64 - m0d);
    }
    double colsum = 0.0;
    for (int r=0;r<98;r++){
      float s = 0.f;
      #pragma unroll
      for (int dd=0;dd<16;dd++){
        const float4 qq = *(const float4*)&Qt[r][dd*4];
        s = fmaf(qq.x,kreg[dd].x,s); s = fmaf(qq.y,kreg[dd].y,s);
        s = fmaf(qq.z,kreg[dd].z,s); s = fmaf(qq.w,kreg[dd].w,s);
      }
      colsum += (double)(expf(s - msf[r]) * lsf[r]);
    }
    csp[(size_t)blockIdx.x*NTOK + j] = colsum;
  }
}

// ---- selector stats COMBINE ----------------------------------------------
__global__ __launch_bounds__(256) void attn_selc_kernel(
    const double* __restrict__ csp, const double* __restrict__ e0buf,
    double* __restrict__ ta_part)
{
  __shared__ double red[4];
  __shared__ double sh_cs0, sh_e00, sh_l0inv;
  const int bh = blockIdx.x;
  const int j = threadIdx.x;
  double colsum = 0.0, e0 = 0.0;
  if (j < NTOK){
    colsum = csp[(size_t)(bh*2)*NTOK + j] + csp[(size_t)(bh*2+1)*NTOK + j];
    e0 = e0buf[(size_t)bh*NTOK + j];
  }
  double e = e0;
  #pragma unroll
  for (int o=32;o>0;o>>=1) e += __shfl_down(e,o);
  if ((threadIdx.x&63)==0) red[threadIdx.x>>6] = e;
  __syncthreads();
  if (threadIdx.x == 0){
    sh_l0inv = 1.0/(red[0]+red[1]+red[2]+red[3]);
    sh_cs0 = colsum;
    sh_e00 = e0;
  }
  __syncthreads();
  if (j >= 1 && j < NTOK){
    const double row0 = e0 * sh_l0inv;
    const double r00  = sh_e00 * sh_l0inv;
    ta_part[(size_t)bh*NIMG + (j-1)] = row0 * (sh_cs0 / 196.0) + (colsum / 196.0) * r00;
  }
}

// -------- deterministic reduce over heads: token_attn[b,j] (f64) ---------
__global__ __launch_bounds__(256) void reduce_ta_kernel(
    const double* __restrict__ ta_part, double* __restrict__ token_attn)
{
  const int b = blockIdx.x, j = threadIdx.x;
  if (j < NIMG){
    double s = 0.0;
    for (int h=0; h<NHEAD; h++) s += ta_part[((size_t)b*NHEAD + h)*NIMG + j];
    token_attn[b*NIMG + j] = s / 12.0;
  }
}

// -------- circulant coefficients, parallel: one block per d ---------------
__global__ __launch_bounds__(256) void circ_kernel(float* __restrict__ circ)
{
  const int d = blockIdx.x;
  const int g = threadIdx.x;
  __shared__ double rs[4], is[4];
  double re = 0.0, im = 0.0;
  if (g < NIMG){
    const double d0   = (196.0 * 0.15 / 2.0);
    const double twod = 2.0 * d0 * d0;
    const double gg = (double)g - 97.5;
    const double kg = 1.0 - exp(-(gg*gg)/twod);
    const int gd = (g*d) % NIMG;
    const double ang = 6.283185307179586476925286766559 * ((double)gd / 196.0);
    re = kg * cos(ang);
    im = kg * sin(ang);
  }
  #pragma unroll
  for (int o=32;o>0;o>>=1){ re += __shfl_down(re,o); im += __shfl_down(im,o); }
  if ((g&63)==0){ rs[g>>6] = re; is[g>>6] = im; }
  __syncthreads();
  if (g == 0){
    circ[d]        = (float)((rs[0]+rs[1]+rs[2]+rs[3]) / 196.0);
    circ[NIMG + d] = (float)((is[0]+is[1]+is[2]+is[3]) / 196.0);
  }
}

// -------- low-frequency-energy: f32 conv, f64 accumulation ----------------
__global__ __launch_bounds__(256) void lfe_kernel(
    const float* __restrict__ x1, const float* __restrict__ circ,
    double* __restrict__ lfe_part, double* __restrict__ den_part)
{
  __shared__ float xs[NIMG][36];
  __shared__ float2 c2[NIMG];
  __shared__ double red[4];
  const int cg = blockIdx.x, b = blockIdx.y;
  const int c0 = cg * 32;
  for (int li=threadIdx.x; li<NIMG*32; li+=256){
    const int m = li >> 5, ch = li & 31;
    xs[m][ch] = x1[((size_t)b*NTOK + 1 + m)*CDIM + c0 + ch];
  }
  for (int li=threadIdx.x; li<NIMG; li+=256) c2[li] = make_float2(circ[li], circ[NIMG+li]);
  __syncthreads();
  const int n = threadIdx.x;
  double lfe_sum = 0.0, den_sum = 0.0;
  if (n < NIMG){
    #pragma unroll 1
    for (int g=0; g<4; g++){
      const int cc0 = g*8;
      float re[8] = {0,0,0,0,0,0,0,0};
      float im[8] = {0,0,0,0,0,0,0,0};
      int d = n;
      for (int mm=0; mm<NIMG; mm++){
        const float2 cc = c2[d];
        const float4 xa = *(const float4*)&xs[mm][cc0];
        const float4 xb = *(const float4*)&xs[mm][cc0+4];
        const float xv[8] = {xa.x,xa.y,xa.z,xa.w,xb.x,xb.y,xb.z,xb.w};
        #pragma unroll
        for (int q=0;q<8;q++){
          re[q] = fmaf(cc.x, xv[q], re[q]);
          im[q] = fmaf(cc.y, xv[q], im[q]);
        }
        d = (d==0) ? (NIMG-1) : (d-1);
      }
      #pragma unroll
      for (int q=0;q<8;q++) lfe_sum += (double)sqrtf(re[q]*re[q] + im[q]*im[q]);
    }
    #pragma unroll
    for (int q=0;q<8;q++){
      const float4 xv = *(const float4*)&xs[n][q*4];
      den_sum += (double)fabsf(xv.x)+(double)fabsf(xv.y)+(double)fabsf(xv.z)+(double)fabsf(xv.w);
    }
    lfe_part[((size_t)b*24 + cg)*NIMG + n] = lfe_sum;
  }
  double s = (n < NIMG) ? den_sum : 0.0;
  #pragma unroll
  for (int o=32;o>0;o>>=1) s += __shfl_down(s,o);
  if ((threadIdx.x & 63) == 0) red[threadIdx.x >> 6] = s;
  __syncthreads();
  if (threadIdx.x == 0) den_part[b*24 + cg] = red[0]+red[1]+red[2]+red[3];
}

// -------- scores[b,n] = (lfe_num / (den/196)) * token_attn (f64) ----------
__global__ __launch_bounds__(256) void scores_kernel(
    const double* __restrict__ lfe_part, const double* __restrict__ den_part,
    const double* __restrict__ token_attn, double* __restrict__ scores)
{
  const int b = blockIdx.x, n = threadIdx.x;
  if (n < NIMG){
    double num = 0.0;
    for (int cg=0; cg<24; cg++) num += lfe_part[((size_t)b*24 + cg)*NIMG + n];
    double den = 0.0;
    for (int cg=0; cg<24; cg++) den += den_part[b*24 + cg];
    const double tl = num / (den / 196.0);
    scores[b*NIMG + n] = tl * token_attn[b*NIMG + n];
  }
}

// -------- top-118, descending, stable (ties -> lower index); 1 wave -------
__global__ void topk_kernel(const double* __restrict__ scores, int* __restrict__ idx)
{
  __shared__ double w[NIMG];
  const int b = blockIdx.x, lane = threadIdx.x;   // blockDim = 64
  for (int i=lane; i<NIMG; i+=64) w[i] = scores[b*NIMG + i];
  __syncthreads();
  for (int r=0; r<NSEL; r++){
    double bv = -INFINITY; int bi = NIMG;
    for (int i=lane; i<NIMG; i+=64){
      const double v = w[i];
      if (v > bv){ bv = v; bi = i; }
    }
    #pragma unroll
    for (int o=32;o>0;o>>=1){
      const double ov = __shfl_down(bv,o);
      const int    oi = __shfl_down(bi,o);
      if (ov > bv || (ov == bv && oi < bi)){ bv = ov; bi = oi; }
    }
    if (lane == 0){
      idx[b*NSEL + r] = bi;
      w[bi] = -INFINITY;
    }
    __syncthreads();
  }
}

// -------- gather selected tokens -----------------------------------------
__global__ void gather_kernel(const float* __restrict__ x1, const int* __restrict__ idx,
                              float* __restrict__ xsel)
{
  const int row = blockIdx.x;
  const int b = row / (NSEL+1), r = row % (NSEL+1);
  const int src = (r == 0) ? 0 : (1 + idx[b*NSEL + (r-1)]);
  const float4* s = (const float4*)(x1 + ((size_t)b*NTOK + src)*CDIM);
  float4* d = (float4*)(xsel + (size_t)row*CDIM);
  d[threadIdx.x] = s[threadIdx.x];
}

// ===========================================================================
extern "C" void kernel_launch(void* const* d_in, const int* in_sizes, int n_in,
                              void* d_out, int out_size, void* d_ws, size_t ws_size,
                              hipStream_t stream)
{
  const float* x      = (const float*)d_in[0];
  const float* ln1_w  = (const float*)d_in[1];
  const float* ln1_b  = (const float*)d_in[2];
  const float* qkv_w  = (const float*)d_in[3];
  const float* proj_w = (const float*)d_in[4];
  const float* proj_b = (const float*)d_in[5];
  const float* gamma1 = (const float*)d_in[6];
  const float* ln2_w  = (const float*)d_in[7];
  const float* ln2_b  = (const float*)d_in[8];
  const float* fc1_w  = (const float*)d_in[9];
  const float* fc1_b  = (const float*)d_in[10];
  const float* fc2_w  = (const float*)d_in[11];
  const float* fc2_b  = (const float*)d_in[12];
  const float* gamma2 = (const float*)d_in[13];
  float* out = (float*)d_out;
  float* ws  = (float*)d_ws;

  float* R1 = ws;                                   // 9,732,096 f
  float* R2 = ws + 9732096;                         // 29,048,832 f
  double* D = (double*)(ws + 9732096 + 29048832);   // f-off 38,780,928
  double* mbuf = D;                   // 151296
  double* lbuf = mbuf + 151296;       // 151296
  double* tap  = lbuf + 151296;       // 150528
  double* ta   = tap  + 150528;       // 12544
  double* lfep = ta   + 12544;        // 301056
  double* denp = lfep + 301056;       // 1536
  double* sc   = denp + 1536;         // 12544
  float* circ  = (float*)(sc + 12544);        // 392 f
  int*   idxb  = (int*)(circ + 392);          // 7552 i
  unsigned short* W3p = (unsigned short*)(ws + 40350472);   // 768x1536 us
  unsigned short* WQ3 = (unsigned short*)(ws + 40940296);   // 3 x 2304x768 us
  unsigned short* XQ3 = (unsigned short*)(ws + 43594504);   // 3 x 12672x768 us
  const size_t NEED_BYTES  = (size_t)58192648 * 4;          // ~233 MB
  // flash-split partials (new region beyond base layout)
  float* opart = ws + 58192648;                             // 19,365,888 f
  float* mpart = opart + 19365888;                          // 302,592 f
  float* lpart = mpart + 302592;                            // 302,592 f
  const size_t NEED2_BYTES = (size_t)78163720 * 4;          // ~313 MB

  // sel split scratch (region reuse; both dead at selp/selc time):
  double* csp   = lfep;                          // 302,592 doubles (lfep+denp)
  double* e0buf = (double*)(ws + 40940296);      // 151,296 doubles (dead WQ3)

  float* xln  = R1;
  unsigned short* msa3 = (unsigned short*)R1;
  float* xsel = R1;
  float* qkv  = R2;
  float* x1   = R2;
  unsigned short* ln2o_bf = (unsigned short*)(R2 + 9682944);   // 7680*768
  unsigned short* fc1w_bf = (unsigned short*)(R2 + 12632064);  // 3072*768
  unsigned short* fc2w_bf = (unsigned short*)(R2 + 13811712);  // 768*3072
  unsigned short* h1_bf   = (unsigned short*)(R2 + 14991360);  // 7680*3072

  // 1-2) LN1 + qkv = ln(x) @ qkv_w^T  [12608,2304]
  if (ws_size >= NEED_BYTES){
    ln_split3_kernel<<<ROWS_FULL, 256, 0, stream>>>(x, ln1_w, ln1_b, XQ3, (size_t)9732096);
    cvt_split3_kernel<<<(442368+255)/256, 256, 0, stream>>>(qkv_w, WQ3, 442368, (size_t)1769472);
    mfma_gemm6w_kernel<<<197*9, 512, 0, stream>>>(XQ3, WQ3, qkv, ROWS_FULL, 2304, 768,
                                                  (size_t)9732096, (size_t)1769472, 197);
  } else {
    ln_kernel<0><<<ROWS_FULL, 256, 0, stream>>>(x, ln1_w, ln1_b, xln);
    gemm_f32_kernel<<<dim3(99,18), 256, 0, stream>>>(xln, qkv_w, qkv, ROWS_FULL, 2304, 768);
  }
  // 3-4) flash attention: split j-range if ws permits, else proven fallback
  if (ws_size >= NEED2_BYTES){
    attn_flashp_kernel<<<BATCH*NHEAD*2, 256, 0, stream>>>(qkv, opart, mpart, lpart);
    attn_flashc_kernel<<<BATCH*NHEAD, 256, 0, stream>>>(opart, mpart, lpart, mbuf, lbuf, msa3);
  } else {
    attn_flash_kernel<<<BATCH*NHEAD, 256, 0, stream>>>(qkv, mbuf, lbuf, msa3);
  }
  // 5) selector stats: split i2 range (2 blocks/bh), combine, head reduce
  attn_selp_kernel<<<BATCH*NHEAD*2, 256, 0, stream>>>(qkv, mbuf, lbuf, csp, e0buf);
  attn_selc_kernel<<<BATCH*NHEAD, 256, 0, stream>>>(csp, e0buf, tap);
  reduce_ta_kernel<<<BATCH, 256, 0, stream>>>(tap, ta);
  // 6) proj via 3-term split MFMA v2: x1 = gamma1*(msa@proj_w^T + b) + x
  cvt3_kernel<<<CDIM, 192, 0, stream>>>(proj_w, W3p, CDIM);
  mfma_proj3_kernel<<<197*3, 512, 0, stream>>>(msa3, W3p, proj_b, gamma1, x,
                                               x1, ROWS_FULL, CDIM, CDIM, 197);
  // 6b) fc weights -> bf16
  cvt_bf16_kernel<<<2304, 256, 0, stream>>>(fc1_w, fc1w_bf, 589824);
  cvt_bf16_kernel<<<2304, 256, 0, stream>>>(fc2_w, fc2w_bf, 589824);
  // 7) selector scores
  circ_kernel<<<NIMG, 256, 0, stream>>>(circ);
  lfe_kernel<<<dim3(24, BATCH), 256, 0, stream>>>(x1, circ, lfep, denp);
  scores_kernel<<<BATCH, 256, 0, stream>>>(lfep, denp, ta, sc);
  // 8) top-118 + gather (xsel over dead msa3)
  topk_kernel<<<BATCH, 64, 0, stream>>>(sc, idxb);
  gather_kernel<<<ROWS_SEL, 192, 0, stream>>>(x1, idxb, xsel);
  // 9) MLP: LN2 -> bf16, fc1/fc2 via v5-style M64xN256 MFMA
  ln_kernel<1><<<ROWS_SEL, 256, 0, stream>>>(xsel, ln2_w, ln2_b, ln2o_bf);
  mfma_gemm1w_kernel<2><<<119*12, 512, 0, stream>>>(ln2o_bf, fc1w_bf, fc1_b, nullptr,
                                                    nullptr, h1_bf, ROWS_SEL, 3072, 768, 119);
  mfma_gemm1w_kernel<3><<<119*3, 512, 0, stream>>>(h1_bf, fc2w_bf, fc2_b, gamma2,
                                                   xsel, out, ROWS_SEL, 768, 3072, 119);
}